// Round 1
// baseline (1133.580 us; speedup 1.0000x reference)
//
#include <hip/hip_runtime.h>

#define NN 65536
#define NE 524288
#define SLOPE 0.01f

__device__ __forceinline__ float leaky(float v) { return v >= 0.f ? v : SLOPE * v; }

// ---------------- utility kernels ----------------
__global__ void zero_ints(int* __restrict__ p, int n) {
  int i = blockIdx.x * blockDim.x + threadIdx.x;
  if (i < n) p[i] = 0;
}

__global__ void deg_count(const int* __restrict__ src, const int* __restrict__ dst,
                          int* __restrict__ cout, int* __restrict__ cin) {
  int e = blockIdx.x * blockDim.x + threadIdx.x;
  if (e < NE) {
    atomicAdd(&cout[src[e]], 1);
    atomicAdd(&cin[dst[e]], 1);
  }
}

__global__ void rs_kernel(const int* __restrict__ cout, const int* __restrict__ cin,
                          float* __restrict__ rs_out, float* __restrict__ rs_in) {
  int n = blockIdx.x * blockDim.x + threadIdx.x;
  if (n < NN) {
    rs_out[n] = rsqrtf((float)(cout[n] > 0 ? cout[n] : 1));
    rs_in[n]  = rsqrtf((float)(cin[n]  > 0 ? cin[n]  : 1));
  }
}

// single-block exclusive scan of 65536 ints -> row_ptr[NN+1]
__global__ __launch_bounds__(1024) void scan_kernel(const int* __restrict__ cnt,
                                                    int* __restrict__ row_ptr) {
  __shared__ int part[1024];
  int t = threadIdx.x;
  int base = t * 64;
  int s = 0;
  for (int i = 0; i < 64; ++i) s += cnt[base + i];
  part[t] = s;
  __syncthreads();
  for (int d = 1; d < 1024; d <<= 1) {
    int v = (t >= d) ? part[t - d] : 0;
    __syncthreads();
    part[t] += v;
    __syncthreads();
  }
  int run = part[t] - s;  // exclusive prefix of this thread's chunk
  for (int i = 0; i < 64; ++i) { row_ptr[base + i] = run; run += cnt[base + i]; }
  if (t == 1023) row_ptr[NN] = run;
}

__global__ void csr_fill(const int* __restrict__ src, const int* __restrict__ dst,
                         const int* __restrict__ row_ptr, int* __restrict__ cursor,
                         int* __restrict__ csr) {
  int e = blockIdx.x * blockDim.x + threadIdx.x;
  if (e < NE) {
    int d = dst[e];
    int pos = atomicAdd(&cursor[d], 1);
    csr[row_ptr[d] + pos] = src[e];
  }
}

// x [512][128c][128v] -> h0 [65536 node][128 c]; one block per (slice, v-half)
__global__ __launch_bounds__(256) void transpose_x(const float* __restrict__ x,
                                                   float* __restrict__ h0) {
  __shared__ float tile[128][68];
  int s  = blockIdx.x >> 1;
  int vh = (blockIdx.x & 1) * 64;
  const float* xs = x + (size_t)s * 16384;
  int t = threadIdx.x;
  int v4 = t & 15, c0 = t >> 4;
  for (int p = 0; p < 8; ++p) {
    int c = c0 + p * 16;
    float4 val = *(const float4*)(xs + (size_t)c * 128 + vh + v4 * 4);
    *(float4*)&tile[c][v4 * 4] = val;
  }
  __syncthreads();
  int c4 = t & 31, v0 = t >> 5;
  for (int p = 0; p < 8; ++p) {
    int v = v0 + p * 8;
    float4 o;
    o.x = tile[c4 * 4 + 0][v];
    o.y = tile[c4 * 4 + 1][v];
    o.z = tile[c4 * 4 + 2][v];
    o.w = tile[c4 * 4 + 3][v];
    *(float4*)(h0 + (size_t)(s * 128 + vh + v) * 128 + c4 * 4) = o;
  }
}

// out[k*opad + o] = (o<O) ? in[o*ldin + koff + k] : 0
__global__ void transpose_w(const float* __restrict__ in, float* __restrict__ out,
                            int O, int K, int ldin, int koff, int opad) {
  int idx = blockIdx.x * blockDim.x + threadIdx.x;
  if (idx >= K * opad) return;
  int k = idx / opad, o = idx % opad;
  out[idx] = (o < O) ? in[(size_t)o * ldin + koff + k] : 0.f;
}

// agg[n][c] = rs_in[n] * sum_{e in CSR row n} rs_out[src] * h[src][c]
__global__ void aggregate(const float* __restrict__ h, int lda,
                          const int* __restrict__ row_ptr, const int* __restrict__ csr,
                          const float* __restrict__ rs_out, const float* __restrict__ rs_in,
                          float* __restrict__ agg) {
  int n = blockIdx.x * blockDim.y + threadIdx.y;
  int c = threadIdx.x;
  int b = row_ptr[n], e = row_ptr[n + 1];
  float acc = 0.f;
  for (int i = b; i < e; ++i) {
    int s = csr[i];
    acc += rs_out[s] * h[(size_t)s * lda + c];
  }
  agg[(size_t)n * 128 + c] = acc * rs_in[n];
}

// ---------------- tiled fp32 GEMM, 128x128 tile, 8x8 microtile ----------------
// MODE 0: conv head : states[m*512 + colOff + c] = leaky(acc + bias[c])
// MODE 1: conv res  : ... + states[m*512 + colOff-128 + c]
// MODE 2: fusion+max: gmax[s*256 + nbase + c] = max_m(acc) + bias[nbase+c]  (block = slice)
// MODE 3: p1        : y1[m*256 + nbase + c] = leaky(acc + bias + gcon[s][c])
// MODE 4: p2        : y2[m*128 + c] = leaky(acc + bias[c]) for c<64
template<int KTOT, int MODE>
__global__ __launch_bounds__(256) void gemm_k(
    const float* __restrict__ A, int lda,
    const float* __restrict__ B, int ldb,
    const float* __restrict__ bias,
    float* __restrict__ C,
    const float* __restrict__ extra,
    int colOff)
{
  __shared__ float As[32][132];  // [k][m], transposed
  __shared__ float Bs[32][132];  // [k][n]
  const int t = threadIdx.x;
  const int tx = t & 15, ty = t >> 4;
  const int mbase = blockIdx.x * 128;
  const int nbase = blockIdx.y * 128;
  float acc[8][8];
#pragma unroll
  for (int i = 0; i < 8; ++i)
#pragma unroll
    for (int j = 0; j < 8; ++j) acc[i][j] = 0.f;

  const int ak4 = t & 7,  am = t >> 3;
  const int bc4 = t & 31, bk = t >> 5;

  for (int k0 = 0; k0 < KTOT; k0 += 32) {
    __syncthreads();
#pragma unroll
    for (int p = 0; p < 4; ++p) {
      int m = am + 32 * p;
      float4 v = *(const float4*)(A + (size_t)(mbase + m) * lda + k0 + ak4 * 4);
      As[ak4 * 4 + 0][m] = v.x;
      As[ak4 * 4 + 1][m] = v.y;
      As[ak4 * 4 + 2][m] = v.z;
      As[ak4 * 4 + 3][m] = v.w;
    }
#pragma unroll
    for (int p = 0; p < 4; ++p) {
      int k = bk + 8 * p;
      float4 v = *(const float4*)(B + (size_t)(k0 + k) * ldb + nbase + bc4 * 4);
      *(float4*)&Bs[k][bc4 * 4] = v;
    }
    __syncthreads();
#pragma unroll
    for (int kk = 0; kk < 32; ++kk) {
      float a[8], b[8];
      *(float4*)&a[0] = *(const float4*)&As[kk][ty * 8];
      *(float4*)&a[4] = *(const float4*)&As[kk][ty * 8 + 4];
      *(float4*)&b[0] = *(const float4*)&Bs[kk][tx * 8];
      *(float4*)&b[4] = *(const float4*)&Bs[kk][tx * 8 + 4];
#pragma unroll
      for (int i = 0; i < 8; ++i)
#pragma unroll
        for (int j = 0; j < 8; ++j) acc[i][j] = fmaf(a[i], b[j], acc[i][j]);
    }
  }

  if (MODE == 0 || MODE == 1) {
#pragma unroll
    for (int i = 0; i < 8; ++i) {
      size_t row = (size_t)(mbase + ty * 8 + i) * 512;
      float o[8];
#pragma unroll
      for (int j = 0; j < 8; ++j) o[j] = leaky(acc[i][j] + bias[tx * 8 + j]);
      if (MODE == 1) {
        float4 r0 = *(const float4*)(C + row + colOff - 128 + tx * 8);
        float4 r1 = *(const float4*)(C + row + colOff - 128 + tx * 8 + 4);
        o[0] += r0.x; o[1] += r0.y; o[2] += r0.z; o[3] += r0.w;
        o[4] += r1.x; o[5] += r1.y; o[6] += r1.z; o[7] += r1.w;
      }
      *(float4*)(C + row + colOff + tx * 8)     = make_float4(o[0], o[1], o[2], o[3]);
      *(float4*)(C + row + colOff + tx * 8 + 4) = make_float4(o[4], o[5], o[6], o[7]);
    }
  } else if (MODE == 2) {
    float tmax[8];
#pragma unroll
    for (int j = 0; j < 8; ++j) {
      float mv = acc[0][j];
#pragma unroll
      for (int i = 1; i < 8; ++i) mv = fmaxf(mv, acc[i][j]);
      tmax[j] = mv;
    }
    __syncthreads();
    float* red = &As[0][0];  // 16 x 128 floats, fits in As
#pragma unroll
    for (int j = 0; j < 8; ++j) red[ty * 128 + tx * 8 + j] = tmax[j];
    __syncthreads();
    if (ty == 0) {
#pragma unroll
      for (int j = 0; j < 8; ++j) {
        float mv = red[tx * 8 + j];
        for (int t2 = 1; t2 < 16; ++t2) mv = fmaxf(mv, red[t2 * 128 + tx * 8 + j]);
        C[(size_t)blockIdx.x * 256 + nbase + tx * 8 + j] = mv + bias[nbase + tx * 8 + j];
      }
    }
  } else if (MODE == 3) {
    const float* gc = extra + (size_t)blockIdx.x * 256;
#pragma unroll
    for (int i = 0; i < 8; ++i) {
      size_t row = (size_t)(mbase + ty * 8 + i) * 256;
      float o[8];
#pragma unroll
      for (int j = 0; j < 8; ++j)
        o[j] = leaky(acc[i][j] + bias[nbase + tx * 8 + j] + gc[nbase + tx * 8 + j]);
      *(float4*)(C + row + nbase + tx * 8)     = make_float4(o[0], o[1], o[2], o[3]);
      *(float4*)(C + row + nbase + tx * 8 + 4) = make_float4(o[4], o[5], o[6], o[7]);
    }
  } else {  // MODE 4
    if (tx < 8) {
#pragma unroll
      for (int i = 0; i < 8; ++i) {
        size_t row = (size_t)(mbase + ty * 8 + i) * 128;
        float o[8];
#pragma unroll
        for (int j = 0; j < 8; ++j) o[j] = leaky(acc[i][j] + bias[tx * 8 + j]);
        *(float4*)(C + row + tx * 8)     = make_float4(o[0], o[1], o[2], o[3]);
        *(float4*)(C + row + tx * 8 + 4) = make_float4(o[4], o[5], o[6], o[7]);
      }
    }
  }
}

// gcon[s][o] = sum_{c<256} gmax[s][c] * Wp1[o][c]
__global__ void gcon_kernel(const float* __restrict__ gmax, const float* __restrict__ Wp1,
                            float* __restrict__ gcon) {
  __shared__ float g[256];
  int s = blockIdx.x, o = threadIdx.x;
  g[o] = gmax[(size_t)s * 256 + o];
  __syncthreads();
  float acc = 0.f;
  const float* wr = Wp1 + (size_t)o * 768;
#pragma unroll 8
  for (int c = 0; c < 256; ++c) acc += g[c] * wr[c];
  gcon[(size_t)s * 256 + o] = acc;
}

// out[s][o][v] = b3[o] + sum_{j<64} y2[n][j] * Wp3[o][j],  n = s*128+v
__global__ void p3_kernel(const float* __restrict__ y2, const float* __restrict__ W,
                          const float* __restrict__ b, float* __restrict__ out) {
  __shared__ float w0[64], w1[64];
  int t = threadIdx.x;
  if (t < 64) { w0[t] = W[t]; w1[t] = W[64 + t]; }
  __syncthreads();
  int n = blockIdx.x * 256 + t;
  const float* row = y2 + (size_t)n * 128;
  float a0 = b[0], a1 = b[1];
#pragma unroll
  for (int j = 0; j < 64; j += 4) {
    float4 v = *(const float4*)(row + j);
    a0 += v.x * w0[j] + v.y * w0[j + 1] + v.z * w0[j + 2] + v.w * w0[j + 3];
    a1 += v.x * w1[j] + v.y * w1[j + 1] + v.z * w1[j + 2] + v.w * w1[j + 3];
  }
  int s = n >> 7, vv = n & 127;
  out[((size_t)s * 2 + 0) * 128 + vv] = a0;
  out[((size_t)s * 2 + 1) * 128 + vv] = a1;
}

extern "C" void kernel_launch(void* const* d_in, const int* in_sizes, int n_in,
                              void* d_out, int out_size, void* d_ws, size_t ws_size,
                              hipStream_t stream) {
  const float* x        = (const float*)d_in[0];
  const int*   esrc     = (const int*)d_in[1];
  const int*   edst     = (const int*)d_in[2];
  const float* W_head   = (const float*)d_in[3];
  const float* b_head   = (const float*)d_in[4];
  const float* W_res[3] = {(const float*)d_in[5], (const float*)d_in[7], (const float*)d_in[9]};
  const float* b_res[3] = {(const float*)d_in[6], (const float*)d_in[8], (const float*)d_in[10]};
  const float* W_fusion = (const float*)d_in[11];
  const float* b_fusion = (const float*)d_in[12];
  const float* W_p1     = (const float*)d_in[13];
  const float* b_p1     = (const float*)d_in[14];
  const float* W_p2     = (const float*)d_in[15];
  const float* b_p2     = (const float*)d_in[16];
  const float* W_p3     = (const float*)d_in[17];
  const float* b_p3     = (const float*)d_in[18];
  float* outp = (float*)d_out;

  float* wsf = (float*)d_ws;
  // region A (NN*256 floats): h0 | agg during conv layers; reused as y1 afterwards
  float* h0     = wsf;
  float* agg    = wsf + (size_t)NN * 128;
  float* y1     = wsf;
  float* states = wsf + (size_t)NN * 256;              // NN*512
  size_t o      = (size_t)NN * 256 + (size_t)NN * 512;
  float* rs_out = wsf + o; o += NN;
  float* rs_in  = wsf + o; o += NN;
  float* gmax   = wsf + o; o += 512 * 256;
  float* gcon   = wsf + o; o += 512 * 256;
  float* WfT    = wsf + o; o += 512 * 256;
  float* Wp1T   = wsf + o; o += 512 * 256;
  float* Wp2T   = wsf + o; o += 256 * 128;
  int* wsi     = (int*)(wsf + o);
  int* cnt_out = wsi;
  int* cnt_in  = wsi + (size_t)NN;
  int* cursor  = wsi + (size_t)2 * NN;
  int* row_ptr = wsi + (size_t)3 * NN;                 // NN+1
  int* csr     = wsi + (size_t)4 * NN + 16;            // NE
  float* y2    = states;                                // reuse states for y2 [NN][128]

  // graph preprocessing
  zero_ints<<<(3 * NN + 255) / 256, 256, 0, stream>>>(cnt_out, 3 * NN);
  deg_count<<<NE / 256, 256, 0, stream>>>(esrc, edst, cnt_out, cnt_in);
  rs_kernel<<<NN / 256, 256, 0, stream>>>(cnt_out, cnt_in, rs_out, rs_in);
  scan_kernel<<<1, 1024, 0, stream>>>(cnt_in, row_ptr);
  csr_fill<<<NE / 256, 256, 0, stream>>>(esrc, edst, row_ptr, cursor, csr);

  // input transpose + weight transposes
  transpose_x<<<1024, 256, 0, stream>>>(x, h0);
  transpose_w<<<512, 256, 0, stream>>>(W_fusion, WfT, 256, 512, 512, 0, 256);
  transpose_w<<<512, 256, 0, stream>>>(W_p1, Wp1T, 256, 512, 768, 256, 256);
  transpose_w<<<128, 256, 0, stream>>>(W_p2, Wp2T, 64, 256, 256, 0, 128);

  dim3 aggBlock(128, 2);
  // layer 1 (head)
  aggregate<<<NN / 2, aggBlock, 0, stream>>>(h0, 128, row_ptr, csr, rs_out, rs_in, agg);
  gemm_k<128, 0><<<dim3(512, 1), 256, 0, stream>>>(agg, 128, W_head, 128, b_head, states, nullptr, 0);
  // layers 2..4 (residual)
  for (int l = 1; l <= 3; ++l) {
    aggregate<<<NN / 2, aggBlock, 0, stream>>>(states + (size_t)(l - 1) * 128, 512,
                                               row_ptr, csr, rs_out, rs_in, agg);
    gemm_k<128, 1><<<dim3(512, 1), 256, 0, stream>>>(agg, 128, W_res[l - 1], 128, b_res[l - 1],
                                                     states, nullptr, l * 128);
  }
  // fusion conv + per-slice max
  gemm_k<512, 2><<<dim3(512, 2), 256, 0, stream>>>(states, 512, WfT, 256, b_fusion, gmax, nullptr, 0);
  gcon_kernel<<<512, 256, 0, stream>>>(gmax, W_p1, gcon);
  // p1
  gemm_k<512, 3><<<dim3(512, 2), 256, 0, stream>>>(states, 512, Wp1T, 256, b_p1, y1, gcon, 0);
  // p2 (N=64 padded to 128)
  gemm_k<256, 4><<<dim3(512, 1), 256, 0, stream>>>(y1, 256, Wp2T, 128, b_p2, y2, nullptr, 0);
  // p3
  p3_kernel<<<NN / 256, 256, 0, stream>>>(y2, W_p3, b_p3, outp);
}

// Round 2
// 1003.879 us; speedup vs baseline: 1.1292x; 1.1292x over previous
//
#include <hip/hip_runtime.h>

#define NN 65536
#define NE 524288
#define SLOPE 0.01f

typedef __attribute__((ext_vector_type(8))) short short8;
typedef __attribute__((ext_vector_type(16))) float f32x16;

__device__ __forceinline__ float leaky(float v) { return v >= 0.f ? v : SLOPE * v; }

__device__ __forceinline__ float b2f(unsigned short u) {
  return __uint_as_float(((unsigned int)u) << 16);
}
__device__ __forceinline__ unsigned short f2b(float f) {
  unsigned int u = __float_as_uint(f);
  u += 0x7fffu + ((u >> 16) & 1u);
  return (unsigned short)(u >> 16);
}
__device__ __forceinline__ void split2(float v, unsigned short& hi, unsigned short& lo) {
  hi = f2b(v);
  lo = f2b(v - b2f(hi));
}

// ---------------- graph preprocessing ----------------
__global__ void zero_ints(int* __restrict__ p, int n) {
  int i = blockIdx.x * blockDim.x + threadIdx.x;
  if (i < n) p[i] = 0;
}

__global__ void deg_count(const int* __restrict__ src, const int* __restrict__ dst,
                          int* __restrict__ cout, int* __restrict__ cin) {
  int e = blockIdx.x * blockDim.x + threadIdx.x;
  if (e < NE) {
    atomicAdd(&cout[src[e]], 1);
    atomicAdd(&cin[dst[e]], 1);
  }
}

__global__ void rs_kernel(const int* __restrict__ cout, const int* __restrict__ cin,
                          float* __restrict__ rs_out, float* __restrict__ rs_in) {
  int n = blockIdx.x * blockDim.x + threadIdx.x;
  if (n < NN) {
    rs_out[n] = rsqrtf((float)(cout[n] > 0 ? cout[n] : 1));
    rs_in[n]  = rsqrtf((float)(cin[n]  > 0 ? cin[n]  : 1));
  }
}

__global__ __launch_bounds__(1024) void scan_kernel(const int* __restrict__ cnt,
                                                    int* __restrict__ row_ptr) {
  __shared__ int part[1024];
  int t = threadIdx.x;
  int base = t * 64;
  int s = 0;
  for (int i = 0; i < 64; ++i) s += cnt[base + i];
  part[t] = s;
  __syncthreads();
  for (int d = 1; d < 1024; d <<= 1) {
    int v = (t >= d) ? part[t - d] : 0;
    __syncthreads();
    part[t] += v;
    __syncthreads();
  }
  int run = part[t] - s;
  for (int i = 0; i < 64; ++i) { row_ptr[base + i] = run; run += cnt[base + i]; }
  if (t == 1023) row_ptr[NN] = run;
}

__global__ void csr_fill(const int* __restrict__ src, const int* __restrict__ dst,
                         const int* __restrict__ row_ptr, int* __restrict__ cursor,
                         int* __restrict__ csr) {
  int e = blockIdx.x * blockDim.x + threadIdx.x;
  if (e < NE) {
    int d = dst[e];
    int pos = atomicAdd(&cursor[d], 1);
    csr[row_ptr[d] + pos] = src[e];
  }
}

// x [512][128c][128v] -> h0 planes [65536 node][128 c] (hi/lo bf16)
__global__ __launch_bounds__(256) void transpose_x(const float* __restrict__ x,
                                                   unsigned short* __restrict__ h0h,
                                                   unsigned short* __restrict__ h0l) {
  __shared__ float tile[128][68];
  int s  = blockIdx.x >> 1;
  int vh = (blockIdx.x & 1) * 64;
  const float* xs = x + (size_t)s * 16384;
  int t = threadIdx.x;
  int v4 = t & 15, c0 = t >> 4;
  for (int p = 0; p < 8; ++p) {
    int c = c0 + p * 16;
    float4 val = *(const float4*)(xs + (size_t)c * 128 + vh + v4 * 4);
    *(float4*)&tile[c][v4 * 4] = val;
  }
  __syncthreads();
  int c4 = t & 31, v0 = t >> 5;
  for (int p = 0; p < 8; ++p) {
    int v = v0 + p * 8;
    float o[4];
    o[0] = tile[c4 * 4 + 0][v];
    o[1] = tile[c4 * 4 + 1][v];
    o[2] = tile[c4 * 4 + 2][v];
    o[3] = tile[c4 * 4 + 3][v];
    unsigned short hh[4], ll[4];
#pragma unroll
    for (int j = 0; j < 4; ++j) split2(o[j], hh[j], ll[j]);
    size_t off = (size_t)(s * 128 + vh + v) * 128 + c4 * 4;
    uint2 wh = make_uint2((unsigned)hh[0] | ((unsigned)hh[1] << 16),
                          (unsigned)hh[2] | ((unsigned)hh[3] << 16));
    uint2 wl = make_uint2((unsigned)ll[0] | ((unsigned)ll[1] << 16),
                          (unsigned)ll[2] | ((unsigned)ll[3] << 16));
    *(uint2*)(h0h + off) = wh;
    *(uint2*)(h0l + off) = wl;
  }
}

// weight split, fragment-major layout B'[n][k]: direct (src row-major [n][ld])
__global__ void wsplit(const float* __restrict__ src, unsigned short* __restrict__ bh,
                       unsigned short* __restrict__ bl, int N, int K, int ld, int koff) {
  int idx = blockIdx.x * 256 + threadIdx.x;
  if (idx >= N * K) return;
  int n = idx / K, k = idx - n * K;
  float v = src[(size_t)n * ld + koff + k];
  unsigned short hi, lo; split2(v, hi, lo);
  bh[idx] = hi; bl[idx] = lo;
}

// weight split transposed: B'[n][k] = src[k*ld + n]   (conv weights W[k_in][n_out])
__global__ void wsplit_t(const float* __restrict__ src, unsigned short* __restrict__ bh,
                         unsigned short* __restrict__ bl, int N, int K, int ld) {
  int idx = blockIdx.x * 256 + threadIdx.x;
  if (idx >= N * K) return;
  int n = idx / K, k = idx - n * K;
  float v = src[(size_t)k * ld + n];
  unsigned short hi, lo; split2(v, hi, lo);
  bh[idx] = hi; bl[idx] = lo;
}

// agg[n][c] = rs_in[n] * sum_{e in row n} rs_out[src] * h[src][c];  h = hi+lo planes
__global__ void aggregate(const unsigned short* __restrict__ hh,
                          const unsigned short* __restrict__ hl, int lda,
                          const int* __restrict__ row_ptr, const int* __restrict__ csr,
                          const float* __restrict__ rs_out, const float* __restrict__ rs_in,
                          unsigned short* __restrict__ aggh, unsigned short* __restrict__ aggl) {
  int n = blockIdx.x * blockDim.y + threadIdx.y;
  int c = threadIdx.x;
  int b = row_ptr[n], e = row_ptr[n + 1];
  float acc = 0.f;
  for (int i = b; i < e; ++i) {
    int s = csr[i];
    size_t off = (size_t)s * lda + c;
    acc += rs_out[s] * (b2f(hh[off]) + b2f(hl[off]));
  }
  float v = acc * rs_in[n];
  unsigned short hi, lo; split2(v, hi, lo);
  aggh[(size_t)n * 128 + c] = hi;
  aggl[(size_t)n * 128 + c] = lo;
}

// ---------------- split-bf16 MFMA GEMM (no LDS in K-loop) ----------------
// C = A*B', A [M][K] hi/lo planes (lda), B' [N][K] hi/lo planes (fragment-major).
// BM=128 rows/block. Waves: 2 (M) x NWN (N); wave tile 64 x (FN*32).
// MODE 0: conv head : states[row*512+colOff+col] = leaky(acc+bias)      (split store)
// MODE 1: conv res  : ... + prev(hi+lo at colOff-128)
// MODE 2: fusion+max: outf[slice*256+col] = max_rows(acc) + bias[col]
// MODE 3: p1        : y1 = leaky(acc + bias + gcon[slice])              (split store)
// MODE 4: p2        : outf[row*64+col] = leaky(acc+bias)                (fp32 store)
template<int KTOT, int NWN, int FN, int MODE>
__global__ __launch_bounds__(128 * NWN) void mgemm(
    const unsigned short* __restrict__ Ah, const unsigned short* __restrict__ Al, int lda,
    const unsigned short* __restrict__ Bh, const unsigned short* __restrict__ Bl,
    const float* __restrict__ bias,
    float* __restrict__ outf,
    unsigned short* __restrict__ outh, unsigned short* __restrict__ outl,
    int ldo, int colOff,
    const unsigned short* __restrict__ prevh, const unsigned short* __restrict__ prevl,
    const float* __restrict__ gcon)
{
  const int t = threadIdx.x;
  const int wave = t >> 6, lane = t & 63;
  const int wm = wave & 1, wn = wave >> 1;
  const int ln = lane & 31, lh = lane >> 5;
  const int mbase = blockIdx.x * 128;

  f32x16 acc[2][FN];
#pragma unroll
  for (int fm = 0; fm < 2; ++fm)
#pragma unroll
    for (int fn = 0; fn < FN; ++fn)
#pragma unroll
      for (int e = 0; e < 16; ++e) acc[fm][fn][e] = 0.f;

  const size_t arow0 = (size_t)(mbase + wm * 64 + ln) * lda + lh * 8;
  const unsigned short* pAh0 = Ah + arow0;
  const unsigned short* pAh1 = Ah + arow0 + (size_t)32 * lda;
  const unsigned short* pAl0 = Al + arow0;
  const unsigned short* pAl1 = Al + arow0 + (size_t)32 * lda;
  const size_t bcol0 = (size_t)(wn * FN * 32 + ln) * KTOT + lh * 8;
  const unsigned short* pBh[FN];
  const unsigned short* pBl[FN];
#pragma unroll
  for (int fn = 0; fn < FN; ++fn) {
    pBh[fn] = Bh + bcol0 + (size_t)fn * 32 * KTOT;
    pBl[fn] = Bl + bcol0 + (size_t)fn * 32 * KTOT;
  }

#pragma unroll 4
  for (int k0 = 0; k0 < KTOT; k0 += 16) {
    short8 ah[2], al[2], bh[FN], bl[FN];
    ah[0] = *(const short8*)(pAh0 + k0);
    ah[1] = *(const short8*)(pAh1 + k0);
    al[0] = *(const short8*)(pAl0 + k0);
    al[1] = *(const short8*)(pAl1 + k0);
#pragma unroll
    for (int fn = 0; fn < FN; ++fn) {
      bh[fn] = *(const short8*)(pBh[fn] + k0);
      bl[fn] = *(const short8*)(pBl[fn] + k0);
    }
#pragma unroll
    for (int fm = 0; fm < 2; ++fm)
#pragma unroll
      for (int fn = 0; fn < FN; ++fn)
        acc[fm][fn] = __builtin_amdgcn_mfma_f32_32x32x16_bf16(ah[fm], bh[fn], acc[fm][fn], 0, 0, 0);
#pragma unroll
    for (int fm = 0; fm < 2; ++fm)
#pragma unroll
      for (int fn = 0; fn < FN; ++fn)
        acc[fm][fn] = __builtin_amdgcn_mfma_f32_32x32x16_bf16(ah[fm], bl[fn], acc[fm][fn], 0, 0, 0);
#pragma unroll
    for (int fm = 0; fm < 2; ++fm)
#pragma unroll
      for (int fn = 0; fn < FN; ++fn)
        acc[fm][fn] = __builtin_amdgcn_mfma_f32_32x32x16_bf16(al[fm], bh[fn], acc[fm][fn], 0, 0, 0);
  }

  // C/D fragment: col = lane&31, row = (reg&3) + 8*(reg>>2) + 4*(lane>>5)   [HW-verified]
  if constexpr (MODE == 0 || MODE == 1) {
#pragma unroll
    for (int fm = 0; fm < 2; ++fm)
#pragma unroll
      for (int fn = 0; fn < FN; ++fn) {
        const int col = wn * (FN * 32) + fn * 32 + ln;
        const float bb = bias[col];
#pragma unroll
        for (int r = 0; r < 16; ++r) {
          const int row = mbase + wm * 64 + fm * 32 + (r & 3) + 8 * (r >> 2) + 4 * lh;
          float v = leaky(acc[fm][fn][r] + bb);
          const size_t off = (size_t)row * ldo + colOff + col;
          if constexpr (MODE == 1) {
            const size_t po = off - 128;
            v += b2f(prevh[po]) + b2f(prevl[po]);
          }
          unsigned short hi, lo; split2(v, hi, lo);
          outh[off] = hi;
          outl[off] = lo;
        }
      }
  } else if constexpr (MODE == 2) {
    __shared__ float red[4 * 256];
#pragma unroll
    for (int fn = 0; fn < FN; ++fn) {
      const int col = wn * (FN * 32) + fn * 32 + ln;
      float m = -3.4e38f;
#pragma unroll
      for (int fm = 0; fm < 2; ++fm)
#pragma unroll
        for (int r = 0; r < 16; ++r) m = fmaxf(m, acc[fm][fn][r]);
      red[(wm * 2 + lh) * 256 + col] = m;
    }
    __syncthreads();
    if (t < 256) {
      float m = fmaxf(fmaxf(red[t], red[256 + t]), fmaxf(red[512 + t], red[768 + t]));
      outf[(size_t)blockIdx.x * 256 + t] = m + bias[t];
    }
  } else if constexpr (MODE == 3) {
    const float* gc = gcon + (size_t)blockIdx.x * 256;
#pragma unroll
    for (int fm = 0; fm < 2; ++fm)
#pragma unroll
      for (int fn = 0; fn < FN; ++fn) {
        const int col = wn * (FN * 32) + fn * 32 + ln;
        const float bb = bias[col] + gc[col];
#pragma unroll
        for (int r = 0; r < 16; ++r) {
          const int row = mbase + wm * 64 + fm * 32 + (r & 3) + 8 * (r >> 2) + 4 * lh;
          float v = leaky(acc[fm][fn][r] + bb);
          const size_t off = (size_t)row * ldo + col;
          unsigned short hi, lo; split2(v, hi, lo);
          outh[off] = hi;
          outl[off] = lo;
        }
      }
  } else {  // MODE 4
#pragma unroll
    for (int fm = 0; fm < 2; ++fm) {
      const int col = wn * 32 + ln;
      const float bb = bias[col];
#pragma unroll
      for (int r = 0; r < 16; ++r) {
        const int row = mbase + wm * 64 + fm * 32 + (r & 3) + 8 * (r >> 2) + 4 * lh;
        outf[(size_t)row * 64 + col] = leaky(acc[fm][0][r] + bb);
      }
    }
  }
}

// gcon[s][o] = sum_{c<256} gmax[s][c] * W_p1[o][c]
__global__ void gcon_kernel(const float* __restrict__ gmax, const float* __restrict__ Wp1,
                            float* __restrict__ gcon) {
  __shared__ float g[256];
  int s = blockIdx.x, o = threadIdx.x;
  g[o] = gmax[(size_t)s * 256 + o];
  __syncthreads();
  float acc = 0.f;
  const float* wr = Wp1 + (size_t)o * 768;
#pragma unroll 8
  for (int c = 0; c < 256; ++c) acc += g[c] * wr[c];
  gcon[(size_t)s * 256 + o] = acc;
}

// out[s][o][v] = b3[o] + sum_{j<64} y2[n][j] * Wp3[o][j],  n = s*128+v
__global__ void p3_kernel(const float* __restrict__ y2, const float* __restrict__ W,
                          const float* __restrict__ b, float* __restrict__ out) {
  __shared__ float w0[64], w1[64];
  int t = threadIdx.x;
  if (t < 64) { w0[t] = W[t]; w1[t] = W[64 + t]; }
  __syncthreads();
  int n = blockIdx.x * 256 + t;
  const float* row = y2 + (size_t)n * 64;
  float a0 = b[0], a1 = b[1];
#pragma unroll
  for (int j = 0; j < 64; j += 4) {
    float4 v = *(const float4*)(row + j);
    a0 += v.x * w0[j] + v.y * w0[j + 1] + v.z * w0[j + 2] + v.w * w0[j + 3];
    a1 += v.x * w1[j] + v.y * w1[j + 1] + v.z * w1[j + 2] + v.w * w1[j + 3];
  }
  int s = n >> 7, vv = n & 127;
  out[((size_t)s * 2 + 0) * 128 + vv] = a0;
  out[((size_t)s * 2 + 1) * 128 + vv] = a1;
}

extern "C" void kernel_launch(void* const* d_in, const int* in_sizes, int n_in,
                              void* d_out, int out_size, void* d_ws, size_t ws_size,
                              hipStream_t stream) {
  const float* x        = (const float*)d_in[0];
  const int*   esrc     = (const int*)d_in[1];
  const int*   edst     = (const int*)d_in[2];
  const float* W_head   = (const float*)d_in[3];
  const float* b_head   = (const float*)d_in[4];
  const float* W_res[3] = {(const float*)d_in[5], (const float*)d_in[7], (const float*)d_in[9]};
  const float* b_res[3] = {(const float*)d_in[6], (const float*)d_in[8], (const float*)d_in[10]};
  const float* W_fusion = (const float*)d_in[11];
  const float* b_fusion = (const float*)d_in[12];
  const float* W_p1     = (const float*)d_in[13];
  const float* b_p1     = (const float*)d_in[14];
  const float* W_p2     = (const float*)d_in[15];
  const float* b_p2     = (const float*)d_in[16];
  const float* W_p3     = (const float*)d_in[17];
  const float* b_p3     = (const float*)d_in[18];
  float* outp = (float*)d_out;

  typedef unsigned short us;
  char* w = (char*)d_ws;
  size_t off = 0;
  auto alloc = [&](size_t bytes) { char* p = w + off; off += (bytes + 255) & ~(size_t)255; return p; };

  us* states_h = (us*)alloc((size_t)NN * 512 * 2);   // 67.1 MB
  us* states_l = (us*)alloc((size_t)NN * 512 * 2);   // 67.1 MB
  char* regionA = alloc((size_t)NN * 128 * 2 * 4);   // 67.1 MB: h0h|h0l|aggh|aggl, later y1h|y1l
  us* h0h  = (us*)regionA;
  us* h0l  = (us*)(regionA + (size_t)NN * 128 * 2);
  us* aggh = (us*)(regionA + (size_t)NN * 128 * 4);
  us* aggl = (us*)(regionA + (size_t)NN * 128 * 6);
  us* y1h  = (us*)regionA;                            // overlays h0 planes
  us* y1l  = (us*)(regionA + (size_t)NN * 256 * 2);   // overlays agg planes
  float* y2 = (float*)states_h;                       // overlays states_h (states dead after p1)

  float* gmax   = (float*)alloc(512 * 256 * 4);
  float* gcon   = (float*)alloc(512 * 256 * 4);
  float* rs_out = (float*)alloc((size_t)NN * 4);
  float* rs_in  = (float*)alloc((size_t)NN * 4);
  us* cWh[4]; us* cWl[4];
  for (int l = 0; l < 4; ++l) { cWh[l] = (us*)alloc(128 * 128 * 2); cWl[l] = (us*)alloc(128 * 128 * 2); }
  us* fWh  = (us*)alloc(256 * 512 * 2);
  us* fWl  = (us*)alloc(256 * 512 * 2);
  us* p1Wh = (us*)alloc(256 * 512 * 2);
  us* p1Wl = (us*)alloc(256 * 512 * 2);
  us* p2Wh = (us*)alloc(64 * 256 * 2);
  us* p2Wl = (us*)alloc(64 * 256 * 2);
  int* cnt_out = (int*)alloc((size_t)NN * 4);
  int* cnt_in  = (int*)alloc((size_t)NN * 4);
  int* cursor  = (int*)alloc((size_t)NN * 4);
  int* row_ptr = (int*)alloc(((size_t)NN + 1) * 4);
  int* csr     = (int*)alloc((size_t)NE * 4);

  // graph preprocessing (cnt_out, cnt_in, cursor are contiguous allocs -> zero 3*NN ints)
  zero_ints<<<(3 * NN + 255) / 256, 256, 0, stream>>>(cnt_out, 3 * NN);
  deg_count<<<NE / 256, 256, 0, stream>>>(esrc, edst, cnt_out, cnt_in);
  rs_kernel<<<NN / 256, 256, 0, stream>>>(cnt_out, cnt_in, rs_out, rs_in);
  scan_kernel<<<1, 1024, 0, stream>>>(cnt_in, row_ptr);
  csr_fill<<<NE / 256, 256, 0, stream>>>(esrc, edst, row_ptr, cursor, csr);

  // input transpose + weight splits
  transpose_x<<<1024, 256, 0, stream>>>(x, h0h, h0l);
  const float* cW[4] = {W_head, W_res[0], W_res[1], W_res[2]};
  for (int l = 0; l < 4; ++l)
    wsplit_t<<<64, 256, 0, stream>>>(cW[l], cWh[l], cWl[l], 128, 128, 128);
  wsplit<<<512, 256, 0, stream>>>(W_fusion, fWh, fWl, 256, 512, 512, 0);
  wsplit<<<512, 256, 0, stream>>>(W_p1, p1Wh, p1Wl, 256, 512, 768, 256);
  wsplit<<<64, 256, 0, stream>>>(W_p2, p2Wh, p2Wl, 64, 256, 256, 0);

  dim3 aggBlock(128, 2);
  const float* cB[4] = {b_head, b_res[0], b_res[1], b_res[2]};
  // layer 1 (head): aggregate(h0) then conv GEMM -> states cols 0..127
  aggregate<<<NN / 2, aggBlock, 0, stream>>>(h0h, h0l, 128, row_ptr, csr, rs_out, rs_in, aggh, aggl);
  mgemm<128, 2, 2, 0><<<512, 256, 0, stream>>>(aggh, aggl, 128, cWh[0], cWl[0], cB[0],
                                               nullptr, states_h, states_l, 512, 0,
                                               nullptr, nullptr, nullptr);
  // layers 2..4 (residual)
  for (int l = 1; l <= 3; ++l) {
    aggregate<<<NN / 2, aggBlock, 0, stream>>>(states_h + (size_t)(l - 1) * 128,
                                               states_l + (size_t)(l - 1) * 128, 512,
                                               row_ptr, csr, rs_out, rs_in, aggh, aggl);
    mgemm<128, 2, 2, 1><<<512, 256, 0, stream>>>(aggh, aggl, 128, cWh[l], cWl[l], cB[l],
                                                 nullptr, states_h, states_l, 512, l * 128,
                                                 states_h, states_l, nullptr);
  }
  // fusion conv + per-slice max -> gmax
  mgemm<512, 4, 2, 2><<<512, 512, 0, stream>>>(states_h, states_l, 512, fWh, fWl, b_fusion,
                                               gmax, nullptr, nullptr, 0, 0,
                                               nullptr, nullptr, nullptr);
  gcon_kernel<<<512, 256, 0, stream>>>(gmax, W_p1, gcon);
  // p1 -> y1 planes
  mgemm<512, 4, 2, 3><<<512, 512, 0, stream>>>(states_h, states_l, 512, p1Wh, p1Wl, b_p1,
                                               nullptr, y1h, y1l, 256, 0,
                                               nullptr, nullptr, gcon);
  // p2 -> y2 fp32 [NN][64]
  mgemm<256, 2, 1, 4><<<512, 256, 0, stream>>>(y1h, y1l, 256, p2Wh, p2Wl, b_p2,
                                               y2, nullptr, nullptr, 0, 0,
                                               nullptr, nullptr, nullptr);
  // p3
  p3_kernel<<<NN / 256, 256, 0, stream>>>(y2, W_p3, b_p3, outp);
}

// Round 3
// 764.616 us; speedup vs baseline: 1.4825x; 1.3129x over previous
//
#include <hip/hip_runtime.h>

#define NN 65536
#define NE 524288
#define SLOPE 0.01f

typedef unsigned short us;
typedef __attribute__((ext_vector_type(8))) short short8;
typedef __attribute__((ext_vector_type(4))) float f32x4;

__device__ __forceinline__ float leaky(float v) { return v >= 0.f ? v : SLOPE * v; }
__device__ __forceinline__ float b2f(us u) { return __uint_as_float(((unsigned)u) << 16); }
__device__ __forceinline__ us f2b(float f) {
  unsigned u = __float_as_uint(f);
  u += 0x7fffu + ((u >> 16) & 1u);
  return (us)(u >> 16);
}
__device__ __forceinline__ void split2(float v, us& hi, us& lo) {
  hi = f2b(v);
  lo = f2b(v - b2f(hi));
}

__device__ __forceinline__ void gload16(const void* g, void* l) {
  __builtin_amdgcn_global_load_lds(
      (const __attribute__((address_space(1))) unsigned int*)g,
      (__attribute__((address_space(3))) unsigned int*)l, 16, 0, 0);
}

// ---------------- graph preprocessing ----------------
__global__ void zero_ints(int* __restrict__ p, int n) {
  int i = blockIdx.x * blockDim.x + threadIdx.x;
  if (i < n) p[i] = 0;
}

__global__ void deg_count(const int* __restrict__ src, const int* __restrict__ dst,
                          int* __restrict__ cout, int* __restrict__ cin) {
  int e = blockIdx.x * blockDim.x + threadIdx.x;
  if (e < NE) {
    atomicAdd(&cout[src[e]], 1);
    atomicAdd(&cin[dst[e]], 1);
  }
}

__global__ void rs_kernel(const int* __restrict__ cout, const int* __restrict__ cin,
                          float* __restrict__ rs_out, float* __restrict__ rs_in) {
  int n = blockIdx.x * blockDim.x + threadIdx.x;
  if (n < NN) {
    rs_out[n] = rsqrtf((float)(cout[n] > 0 ? cout[n] : 1));
    rs_in[n]  = rsqrtf((float)(cin[n]  > 0 ? cin[n]  : 1));
  }
}

__global__ __launch_bounds__(1024) void scan_kernel(const int* __restrict__ cnt,
                                                    int* __restrict__ row_ptr) {
  __shared__ int part[1024];
  int t = threadIdx.x;
  int base = t * 64;
  int s = 0;
  for (int i = 0; i < 64; ++i) s += cnt[base + i];
  part[t] = s;
  __syncthreads();
  for (int d = 1; d < 1024; d <<= 1) {
    int v = (t >= d) ? part[t - d] : 0;
    __syncthreads();
    part[t] += v;
    __syncthreads();
  }
  int run = part[t] - s;
  for (int i = 0; i < 64; ++i) { row_ptr[base + i] = run; run += cnt[base + i]; }
  if (t == 1023) row_ptr[NN] = run;
}

__global__ void csr_fill(const int* __restrict__ src, const int* __restrict__ dst,
                         const int* __restrict__ row_ptr, int* __restrict__ cursor,
                         int* __restrict__ csr) {
  int e = blockIdx.x * blockDim.x + threadIdx.x;
  if (e < NE) {
    int d = dst[e];
    int pos = atomicAdd(&cursor[d], 1);
    csr[row_ptr[d] + pos] = src[e];
  }
}

// x [512][128c][128v] -> h0 planes [65536 node][128 c] (hi/lo bf16)
__global__ __launch_bounds__(256) void transpose_x(const float* __restrict__ x,
                                                   us* __restrict__ h0h,
                                                   us* __restrict__ h0l) {
  __shared__ float tile[128][68];
  int s  = blockIdx.x >> 1;
  int vh = (blockIdx.x & 1) * 64;
  const float* xs = x + (size_t)s * 16384;
  int t = threadIdx.x;
  int v4 = t & 15, c0 = t >> 4;
  for (int p = 0; p < 8; ++p) {
    int c = c0 + p * 16;
    float4 val = *(const float4*)(xs + (size_t)c * 128 + vh + v4 * 4);
    *(float4*)&tile[c][v4 * 4] = val;
  }
  __syncthreads();
  int c4 = t & 31, v0 = t >> 5;
  for (int p = 0; p < 8; ++p) {
    int v = v0 + p * 8;
    float o[4];
    o[0] = tile[c4 * 4 + 0][v];
    o[1] = tile[c4 * 4 + 1][v];
    o[2] = tile[c4 * 4 + 2][v];
    o[3] = tile[c4 * 4 + 3][v];
    us hh[4], ll[4];
#pragma unroll
    for (int j = 0; j < 4; ++j) split2(o[j], hh[j], ll[j]);
    size_t off = (size_t)(s * 128 + vh + v) * 128 + c4 * 4;
    uint2 wh = make_uint2((unsigned)hh[0] | ((unsigned)hh[1] << 16),
                          (unsigned)hh[2] | ((unsigned)hh[3] << 16));
    uint2 wl = make_uint2((unsigned)ll[0] | ((unsigned)ll[1] << 16),
                          (unsigned)ll[2] | ((unsigned)ll[3] << 16));
    *(uint2*)(h0h + off) = wh;
    *(uint2*)(h0l + off) = wl;
  }
}

// weight split, fragment-major layout B'[n][k] (src row-major [n][ld], cols koff..)
__global__ void wsplit(const float* __restrict__ src, us* __restrict__ bh,
                       us* __restrict__ bl, int N, int K, int ld, int koff) {
  int idx = blockIdx.x * 256 + threadIdx.x;
  if (idx >= N * K) return;
  int n = idx / K, k = idx - n * K;
  float v = src[(size_t)n * ld + koff + k];
  us hi, lo; split2(v, hi, lo);
  bh[idx] = hi; bl[idx] = lo;
}

// weight split transposed: B'[n][k] = src[k*ld + n]   (conv weights W[k_in][n_out])
__global__ void wsplit_t(const float* __restrict__ src, us* __restrict__ bh,
                         us* __restrict__ bl, int N, int K, int ld) {
  int idx = blockIdx.x * 256 + threadIdx.x;
  if (idx >= N * K) return;
  int n = idx / K, k = idx - n * K;
  float v = src[(size_t)k * ld + n];
  us hi, lo; split2(v, hi, lo);
  bh[idx] = hi; bl[idx] = lo;
}

// wave-per-node aggregate: lanes 0-31 gather hi plane, 32-63 lo plane (8B/lane),
// shfl_xor(32) merges; writes split agg planes.
__global__ __launch_bounds__(256) void aggregate(
    const us* __restrict__ hh, const us* __restrict__ hl, int lda,
    const int* __restrict__ row_ptr, const int* __restrict__ csr,
    const float* __restrict__ rs_out, const float* __restrict__ rs_in,
    us* __restrict__ aggh, us* __restrict__ aggl) {
  const int lane = threadIdx.x & 63;
  const int n = blockIdx.x * 4 + (threadIdx.x >> 6);
  const us* base = ((lane < 32) ? hh : hl) + (size_t)(lane & 31) * 4;
  const int b = row_ptr[n], e = row_ptr[n + 1];
  float a0 = 0.f, a1 = 0.f, a2 = 0.f, a3 = 0.f;
  for (int i = b; i < e; ++i) {
    int s = csr[i];
    uint2 v = *(const uint2*)(base + (size_t)s * lda);
    float w = rs_out[s];
    a0 = fmaf(w, __uint_as_float(v.x << 16), a0);
    a1 = fmaf(w, __uint_as_float(v.x & 0xffff0000u), a1);
    a2 = fmaf(w, __uint_as_float(v.y << 16), a2);
    a3 = fmaf(w, __uint_as_float(v.y & 0xffff0000u), a3);
  }
  a0 += __shfl_xor(a0, 32);
  a1 += __shfl_xor(a1, 32);
  a2 += __shfl_xor(a2, 32);
  a3 += __shfl_xor(a3, 32);
  const float ri = rs_in[n];
  a0 *= ri; a1 *= ri; a2 *= ri; a3 *= ri;
  us h[4], l[4];
  split2(a0, h[0], l[0]); split2(a1, h[1], l[1]);
  split2(a2, h[2], l[2]); split2(a3, h[3], l[3]);
  size_t o = (size_t)n * 128 + (size_t)(lane & 31) * 4;
  if (lane < 32) {
    uint2 wv = make_uint2((unsigned)h[0] | ((unsigned)h[1] << 16),
                          (unsigned)h[2] | ((unsigned)h[3] << 16));
    *(uint2*)(aggh + o) = wv;
  } else {
    uint2 wv = make_uint2((unsigned)l[0] | ((unsigned)l[1] << 16),
                          (unsigned)l[2] | ((unsigned)l[3] << 16));
    *(uint2*)(aggl + o) = wv;
  }
}

// ---------------- LDS-staged split-bf16 MFMA GEMM (m97 structure) ----------------
// BM=128, BK=32, BN=NF*64. 512 threads = 8 waves (2M x 4N). Wave tile 64 x NF*16.
// LDS layout per plane tile: [kb][row][8 elems] -> linear DMA dest, sequential ds_read_b128.
// MODE 0: conv head  MODE 1: conv res (+prev)  MODE 2: fusion+max  MODE 3: p1 (+gcon)
// MODE 4: p2 (fp32 out, ld 64)
template<int KTOT, int NF, int MODE>
__global__ __launch_bounds__(512) void mgemm(
    const us* __restrict__ Ah, const us* __restrict__ Al, int lda,
    const us* __restrict__ Bh, const us* __restrict__ Bl,
    const float* __restrict__ bias,
    float* __restrict__ outf, us* __restrict__ outh, us* __restrict__ outl,
    int ldo, int colOff,
    const us* __restrict__ prevh, const us* __restrict__ prevl,
    const float* __restrict__ gcon) {
  constexpr int BN  = NF * 64;
  constexpr int BCH = BN * 4;                 // 16B chunks per B plane tile
  constexpr int IB  = (BCH + 511) / 512;
  constexpr int BSH = (NF == 4) ? 8 : ((NF == 2) ? 7 : 6);

  __shared__ __align__(16) us sAh[4][128][8];
  __shared__ __align__(16) us sAl[4][128][8];
  __shared__ __align__(16) us sBh[4][BN][8];
  __shared__ __align__(16) us sBl[4][BN][8];

  const int t = threadIdx.x;
  const int mbase = blockIdx.x * 128;

  // staging maps (A: 1 chunk/thread/plane; B: IB chunks)
  const int akb = t >> 7, ar = t & 127;
  const us* gAh = Ah + (size_t)(mbase + ar) * lda + akb * 8;
  const us* gAl = Al + (size_t)(mbase + ar) * lda + akb * 8;
  us* dAh = &sAh[akb][ar][0];
  us* dAl = &sAl[akb][ar][0];

  const us* gBh[IB]; const us* gBl[IB];
  us* dBh[IB]; us* dBl[IB];
  bool bact[IB];
#pragma unroll
  for (int i = 0; i < IB; ++i) {
    int ci = i * 512 + t;
    bact[i] = (ci < BCH);
    int kb = (ci >> BSH) & 3, r = ci & (BN - 1);
    gBh[i] = Bh + (size_t)r * KTOT + kb * 8;
    gBl[i] = Bl + (size_t)r * KTOT + kb * 8;
    dBh[i] = &sBh[kb][r][0];
    dBl[i] = &sBl[kb][r][0];
  }

  const int lane = t & 63, wv = t >> 6;
  const int wm = wv & 1, wn = wv >> 1;
  const int l15 = lane & 15, lkb = lane >> 4;

  f32x4 acc[4][NF];
#pragma unroll
  for (int i = 0; i < 4; ++i)
#pragma unroll
    for (int j = 0; j < NF; ++j)
#pragma unroll
      for (int e = 0; e < 4; ++e) acc[i][j][e] = 0.f;

  for (int k0 = 0; k0 < KTOT; k0 += 32) {
    __syncthreads();
    gload16(gAh + k0, dAh);
    gload16(gAl + k0, dAl);
#pragma unroll
    for (int i = 0; i < IB; ++i)
      if (bact[i]) {
        gload16(gBh[i] + k0, dBh[i]);
        gload16(gBl[i] + k0, dBl[i]);
      }
    __syncthreads();

    short8 ah[4], al[4], bh[NF], bl[NF];
#pragma unroll
    for (int fm = 0; fm < 4; ++fm) {
      ah[fm] = *(const short8*)&sAh[lkb][wm * 64 + fm * 16 + l15][0];
      al[fm] = *(const short8*)&sAl[lkb][wm * 64 + fm * 16 + l15][0];
    }
#pragma unroll
    for (int fn = 0; fn < NF; ++fn)
      bh[fn] = *(const short8*)&sBh[lkb][wn * (NF * 16) + fn * 16 + l15][0];
#pragma unroll
    for (int fm = 0; fm < 4; ++fm)
#pragma unroll
      for (int fn = 0; fn < NF; ++fn)
        acc[fm][fn] = __builtin_amdgcn_mfma_f32_16x16x32_bf16(ah[fm], bh[fn], acc[fm][fn], 0, 0, 0);
#pragma unroll
    for (int fm = 0; fm < 4; ++fm)
#pragma unroll
      for (int fn = 0; fn < NF; ++fn)
        acc[fm][fn] = __builtin_amdgcn_mfma_f32_16x16x32_bf16(al[fm], bh[fn], acc[fm][fn], 0, 0, 0);
#pragma unroll
    for (int fn = 0; fn < NF; ++fn)
      bl[fn] = *(const short8*)&sBl[lkb][wn * (NF * 16) + fn * 16 + l15][0];
#pragma unroll
    for (int fm = 0; fm < 4; ++fm)
#pragma unroll
      for (int fn = 0; fn < NF; ++fn)
        acc[fm][fn] = __builtin_amdgcn_mfma_f32_16x16x32_bf16(ah[fm], bl[fn], acc[fm][fn], 0, 0, 0);
  }

  // C/D: col = lane&15, row = (lane>>4)*4 + reg
  if constexpr (MODE == 0 || MODE == 1 || MODE == 3) {
    const float* gc = (MODE == 3) ? (gcon + (size_t)blockIdx.x * 256) : nullptr;
#pragma unroll
    for (int fm = 0; fm < 4; ++fm)
#pragma unroll
      for (int fn = 0; fn < NF; ++fn) {
        const int col = wn * (NF * 16) + fn * 16 + l15;
        float bb = bias[col];
        if constexpr (MODE == 3) bb += gc[col];
#pragma unroll
        for (int r = 0; r < 4; ++r) {
          const int row = mbase + wm * 64 + fm * 16 + lkb * 4 + r;
          float v = leaky(acc[fm][fn][r] + bb);
          const size_t off = (size_t)row * ldo + colOff + col;
          if constexpr (MODE == 1) v += b2f(prevh[off - 128]) + b2f(prevl[off - 128]);
          us hi, lo; split2(v, hi, lo);
          outh[off] = hi;
          outl[off] = lo;
        }
      }
  } else if constexpr (MODE == 2) {
    __shared__ float red[2][256];
    float mx[NF];
#pragma unroll
    for (int fn = 0; fn < NF; ++fn) {
      float m = acc[0][fn][0];
#pragma unroll
      for (int fm = 0; fm < 4; ++fm)
#pragma unroll
        for (int r = 0; r < 4; ++r) m = fmaxf(m, acc[fm][fn][r]);
      m = fmaxf(m, __shfl_xor(m, 16));
      m = fmaxf(m, __shfl_xor(m, 32));
      mx[fn] = m;
    }
    if (lane < 16) {
#pragma unroll
      for (int fn = 0; fn < NF; ++fn) red[wm][wn * (NF * 16) + fn * 16 + l15] = mx[fn];
    }
    __syncthreads();
    if (t < 256) outf[(size_t)blockIdx.x * 256 + t] = fmaxf(red[0][t], red[1][t]) + bias[t];
  } else {  // MODE 4
#pragma unroll
    for (int fm = 0; fm < 4; ++fm) {
      const int col = wn * 16 + l15;
      const float bb = bias[col];
#pragma unroll
      for (int r = 0; r < 4; ++r) {
        const int row = mbase + wm * 64 + fm * 16 + lkb * 4 + r;
        outf[(size_t)row * 64 + col] = leaky(acc[fm][0][r] + bb);
      }
    }
  }
}

// gcon[s][o] = sum_{c<256} gmax[s][c] * W_p1[o][c]
__global__ void gcon_kernel(const float* __restrict__ gmax, const float* __restrict__ Wp1,
                            float* __restrict__ gcon) {
  __shared__ float g[256];
  int s = blockIdx.x, o = threadIdx.x;
  g[o] = gmax[(size_t)s * 256 + o];
  __syncthreads();
  float acc = 0.f;
  const float* wr = Wp1 + (size_t)o * 768;
#pragma unroll 8
  for (int c = 0; c < 256; ++c) acc += g[c] * wr[c];
  gcon[(size_t)s * 256 + o] = acc;
}

// out[s][o][v] = b3[o] + sum_{j<64} y2[n][j] * Wp3[o][j],  n = s*128+v
__global__ void p3_kernel(const float* __restrict__ y2, const float* __restrict__ W,
                          const float* __restrict__ b, float* __restrict__ out) {
  __shared__ float w0[64], w1[64];
  int t = threadIdx.x;
  if (t < 64) { w0[t] = W[t]; w1[t] = W[64 + t]; }
  __syncthreads();
  int n = blockIdx.x * 256 + t;
  const float* row = y2 + (size_t)n * 64;
  float a0 = b[0], a1 = b[1];
#pragma unroll
  for (int j = 0; j < 64; j += 4) {
    float4 v = *(const float4*)(row + j);
    a0 += v.x * w0[j] + v.y * w0[j + 1] + v.z * w0[j + 2] + v.w * w0[j + 3];
    a1 += v.x * w1[j] + v.y * w1[j + 1] + v.z * w1[j + 2] + v.w * w1[j + 3];
  }
  int s = n >> 7, vv = n & 127;
  out[((size_t)s * 2 + 0) * 128 + vv] = a0;
  out[((size_t)s * 2 + 1) * 128 + vv] = a1;
}

extern "C" void kernel_launch(void* const* d_in, const int* in_sizes, int n_in,
                              void* d_out, int out_size, void* d_ws, size_t ws_size,
                              hipStream_t stream) {
  const float* x        = (const float*)d_in[0];
  const int*   esrc     = (const int*)d_in[1];
  const int*   edst     = (const int*)d_in[2];
  const float* W_head   = (const float*)d_in[3];
  const float* b_head   = (const float*)d_in[4];
  const float* W_res[3] = {(const float*)d_in[5], (const float*)d_in[7], (const float*)d_in[9]};
  const float* b_res[3] = {(const float*)d_in[6], (const float*)d_in[8], (const float*)d_in[10]};
  const float* W_fusion = (const float*)d_in[11];
  const float* b_fusion = (const float*)d_in[12];
  const float* W_p1     = (const float*)d_in[13];
  const float* b_p1     = (const float*)d_in[14];
  const float* W_p2     = (const float*)d_in[15];
  const float* b_p2     = (const float*)d_in[16];
  const float* W_p3     = (const float*)d_in[17];
  const float* b_p3     = (const float*)d_in[18];
  float* outp = (float*)d_out;

  char* w = (char*)d_ws;
  size_t off = 0;
  auto alloc = [&](size_t bytes) { char* p = w + off; off += (bytes + 255) & ~(size_t)255; return p; };

  us* states_h = (us*)alloc((size_t)NN * 512 * 2);
  us* states_l = (us*)alloc((size_t)NN * 512 * 2);
  char* regionA = alloc((size_t)NN * 128 * 2 * 4);   // h0h|h0l|aggh|aggl, later y1h|y1l
  us* h0h  = (us*)regionA;
  us* h0l  = (us*)(regionA + (size_t)NN * 128 * 2);
  us* aggh = (us*)(regionA + (size_t)NN * 128 * 4);
  us* aggl = (us*)(regionA + (size_t)NN * 128 * 6);
  us* y1h  = (us*)regionA;
  us* y1l  = (us*)(regionA + (size_t)NN * 256 * 2);
  float* y2 = (float*)states_h;                       // states dead after p1

  float* gmax   = (float*)alloc(512 * 256 * 4);
  float* gcon   = (float*)alloc(512 * 256 * 4);
  float* rs_out = (float*)alloc((size_t)NN * 4);
  float* rs_in  = (float*)alloc((size_t)NN * 4);
  us* cWh[4]; us* cWl[4];
  for (int l = 0; l < 4; ++l) { cWh[l] = (us*)alloc(128 * 128 * 2); cWl[l] = (us*)alloc(128 * 128 * 2); }
  us* fWh  = (us*)alloc(256 * 512 * 2);
  us* fWl  = (us*)alloc(256 * 512 * 2);
  us* p1Wh = (us*)alloc(256 * 512 * 2);
  us* p1Wl = (us*)alloc(256 * 512 * 2);
  us* p2Wh = (us*)alloc(64 * 256 * 2);
  us* p2Wl = (us*)alloc(64 * 256 * 2);
  int* cnt_out = (int*)alloc((size_t)NN * 4);
  int* cnt_in  = (int*)alloc((size_t)NN * 4);
  int* cursor  = (int*)alloc((size_t)NN * 4);
  int* row_ptr = (int*)alloc(((size_t)NN + 1) * 4);
  int* csr     = (int*)alloc((size_t)NE * 4);

  zero_ints<<<(3 * NN + 255) / 256, 256, 0, stream>>>(cnt_out, 3 * NN);
  deg_count<<<NE / 256, 256, 0, stream>>>(esrc, edst, cnt_out, cnt_in);
  rs_kernel<<<NN / 256, 256, 0, stream>>>(cnt_out, cnt_in, rs_out, rs_in);
  scan_kernel<<<1, 1024, 0, stream>>>(cnt_in, row_ptr);
  csr_fill<<<NE / 256, 256, 0, stream>>>(esrc, edst, row_ptr, cursor, csr);

  transpose_x<<<1024, 256, 0, stream>>>(x, h0h, h0l);
  const float* cW[4] = {W_head, W_res[0], W_res[1], W_res[2]};
  for (int l = 0; l < 4; ++l)
    wsplit_t<<<64, 256, 0, stream>>>(cW[l], cWh[l], cWl[l], 128, 128, 128);
  wsplit<<<512, 256, 0, stream>>>(W_fusion, fWh, fWl, 256, 512, 512, 0);
  wsplit<<<512, 256, 0, stream>>>(W_p1, p1Wh, p1Wl, 256, 512, 768, 256);
  wsplit<<<64, 256, 0, stream>>>(W_p2, p2Wh, p2Wl, 64, 256, 256, 0);

  const float* cB[4] = {b_head, b_res[0], b_res[1], b_res[2]};
  // layer 1 (head)
  aggregate<<<NN / 4, 256, 0, stream>>>(h0h, h0l, 128, row_ptr, csr, rs_out, rs_in, aggh, aggl);
  mgemm<128, 2, 0><<<512, 512, 0, stream>>>(aggh, aggl, 128, cWh[0], cWl[0], cB[0],
                                            nullptr, states_h, states_l, 512, 0,
                                            nullptr, nullptr, nullptr);
  // layers 2..4 (residual)
  for (int l = 1; l <= 3; ++l) {
    aggregate<<<NN / 4, 256, 0, stream>>>(states_h + (size_t)(l - 1) * 128,
                                          states_l + (size_t)(l - 1) * 128, 512,
                                          row_ptr, csr, rs_out, rs_in, aggh, aggl);
    mgemm<128, 2, 1><<<512, 512, 0, stream>>>(aggh, aggl, 128, cWh[l], cWl[l], cB[l],
                                              nullptr, states_h, states_l, 512, l * 128,
                                              states_h, states_l, nullptr);
  }
  // fusion conv + per-slice max -> gmax
  mgemm<512, 4, 2><<<512, 512, 0, stream>>>(states_h, states_l, 512, fWh, fWl, b_fusion,
                                            gmax, nullptr, nullptr, 0, 0,
                                            nullptr, nullptr, nullptr);
  gcon_kernel<<<512, 256, 0, stream>>>(gmax, W_p1, gcon);
  // p1 -> y1 planes
  mgemm<512, 4, 3><<<512, 512, 0, stream>>>(states_h, states_l, 512, p1Wh, p1Wl, b_p1,
                                            nullptr, y1h, y1l, 256, 0,
                                            nullptr, nullptr, gcon);
  // p2 -> y2 fp32 [NN][64]
  mgemm<256, 1, 4><<<512, 512, 0, stream>>>(y1h, y1l, 256, p2Wh, p2Wl, b_p2,
                                            y2, nullptr, nullptr, 0, 0,
                                            nullptr, nullptr, nullptr);
  // p3
  p3_kernel<<<NN / 256, 256, 0, stream>>>(y2, W_p3, b_p3, outp);
}

// Round 4
// 638.002 us; speedup vs baseline: 1.7768x; 1.1985x over previous
//
#include <hip/hip_runtime.h>

#define NN 65536
#define NE 524288
#define SLOPE 0.01f

typedef unsigned short us;
typedef __attribute__((ext_vector_type(8))) short short8;
typedef __attribute__((ext_vector_type(4))) float f32x4;

__device__ __forceinline__ float leaky(float v) { return v >= 0.f ? v : SLOPE * v; }
__device__ __forceinline__ float b2f(us u) { return __uint_as_float(((unsigned)u) << 16); }
__device__ __forceinline__ us f2b(float f) {
  unsigned u = __float_as_uint(f);
  u += 0x7fffu + ((u >> 16) & 1u);
  return (us)(u >> 16);
}
__device__ __forceinline__ void split2(float v, us& hi, us& lo) {
  hi = f2b(v);
  lo = f2b(v - b2f(hi));
}

__device__ __forceinline__ void gload16(const void* g, void* l) {
  __builtin_amdgcn_global_load_lds(
      (const __attribute__((address_space(1))) unsigned int*)g,
      (__attribute__((address_space(3))) unsigned int*)l, 16, 0, 0);
}

// ---------------- graph preprocessing ----------------
__global__ void zero_ints(int* __restrict__ p, int n) {
  int i = blockIdx.x * blockDim.x + threadIdx.x;
  if (i < n) p[i] = 0;
}

__global__ void deg_count(const int* __restrict__ src, const int* __restrict__ dst,
                          int* __restrict__ cout, int* __restrict__ cin) {
  int e = blockIdx.x * blockDim.x + threadIdx.x;
  if (e < NE) {
    atomicAdd(&cout[src[e]], 1);
    atomicAdd(&cin[dst[e]], 1);
  }
}

__global__ void rs_kernel(const int* __restrict__ cout, const int* __restrict__ cin,
                          float* __restrict__ rs_out, float* __restrict__ rs_in) {
  int n = blockIdx.x * blockDim.x + threadIdx.x;
  if (n < NN) {
    rs_out[n] = rsqrtf((float)(cout[n] > 0 ? cout[n] : 1));
    rs_in[n]  = rsqrtf((float)(cin[n]  > 0 ? cin[n]  : 1));
  }
}

__global__ __launch_bounds__(1024) void scan_kernel(const int* __restrict__ cnt,
                                                    int* __restrict__ row_ptr) {
  __shared__ int part[1024];
  int t = threadIdx.x;
  int base = t * 64;
  int s = 0;
  for (int i = 0; i < 64; ++i) s += cnt[base + i];
  part[t] = s;
  __syncthreads();
  for (int d = 1; d < 1024; d <<= 1) {
    int v = (t >= d) ? part[t - d] : 0;
    __syncthreads();
    part[t] += v;
    __syncthreads();
  }
  int run = part[t] - s;
  for (int i = 0; i < 64; ++i) { row_ptr[base + i] = run; run += cnt[base + i]; }
  if (t == 1023) row_ptr[NN] = run;
}

__global__ void csr_fill(const int* __restrict__ src, const int* __restrict__ dst,
                         const int* __restrict__ row_ptr, int* __restrict__ cursor,
                         int* __restrict__ csr) {
  int e = blockIdx.x * blockDim.x + threadIdx.x;
  if (e < NE) {
    int d = dst[e];
    int pos = atomicAdd(&cursor[d], 1);
    csr[row_ptr[d] + pos] = src[e];
  }
}

// x [512][128c][128v] -> h0 planes [65536 node][128 c] (hi/lo bf16)
__global__ __launch_bounds__(256) void transpose_x(const float* __restrict__ x,
                                                   us* __restrict__ h0h,
                                                   us* __restrict__ h0l) {
  __shared__ float tile[128][68];
  int s  = blockIdx.x >> 1;
  int vh = (blockIdx.x & 1) * 64;
  const float* xs = x + (size_t)s * 16384;
  int t = threadIdx.x;
  int v4 = t & 15, c0 = t >> 4;
  for (int p = 0; p < 8; ++p) {
    int c = c0 + p * 16;
    float4 val = *(const float4*)(xs + (size_t)c * 128 + vh + v4 * 4);
    *(float4*)&tile[c][v4 * 4] = val;
  }
  __syncthreads();
  int c4 = t & 31, v0 = t >> 5;
  for (int p = 0; p < 8; ++p) {
    int v = v0 + p * 8;
    float o[4];
    o[0] = tile[c4 * 4 + 0][v];
    o[1] = tile[c4 * 4 + 1][v];
    o[2] = tile[c4 * 4 + 2][v];
    o[3] = tile[c4 * 4 + 3][v];
    us hh[4], ll[4];
#pragma unroll
    for (int j = 0; j < 4; ++j) split2(o[j], hh[j], ll[j]);
    size_t off = (size_t)(s * 128 + vh + v) * 128 + c4 * 4;
    uint2 wh = make_uint2((unsigned)hh[0] | ((unsigned)hh[1] << 16),
                          (unsigned)hh[2] | ((unsigned)hh[3] << 16));
    uint2 wl = make_uint2((unsigned)ll[0] | ((unsigned)ll[1] << 16),
                          (unsigned)ll[2] | ((unsigned)ll[3] << 16));
    *(uint2*)(h0h + off) = wh;
    *(uint2*)(h0l + off) = wl;
  }
}

// weight split, fragment-major layout B'[n][k] (src row-major [n][ld], cols koff..)
__global__ void wsplit(const float* __restrict__ src, us* __restrict__ bh,
                       us* __restrict__ bl, int N, int K, int ld, int koff) {
  int idx = blockIdx.x * 256 + threadIdx.x;
  if (idx >= N * K) return;
  int n = idx / K, k = idx - n * K;
  float v = src[(size_t)n * ld + koff + k];
  us hi, lo; split2(v, hi, lo);
  bh[idx] = hi; bl[idx] = lo;
}

// weight split transposed: B'[n][k] = src[k*ld + n]   (conv weights W[k_in][n_out])
__global__ void wsplit_t(const float* __restrict__ src, us* __restrict__ bh,
                         us* __restrict__ bl, int N, int K, int ld) {
  int idx = blockIdx.x * 256 + threadIdx.x;
  if (idx >= N * K) return;
  int n = idx / K, k = idx - n * K;
  float v = src[(size_t)k * ld + n];
  us hi, lo; split2(v, hi, lo);
  bh[idx] = hi; bl[idx] = lo;
}

// wave-per-node aggregate: lanes 0-31 gather hi plane, 32-63 lo plane (8B/lane),
// 2-edge unroll for MLP; shfl_xor(32) merges; writes split agg planes.
__global__ __launch_bounds__(256) void aggregate(
    const us* __restrict__ hh, const us* __restrict__ hl, int lda,
    const int* __restrict__ row_ptr, const int* __restrict__ csr,
    const float* __restrict__ rs_out, const float* __restrict__ rs_in,
    us* __restrict__ aggh, us* __restrict__ aggl) {
  const int lane = threadIdx.x & 63;
  const int n = blockIdx.x * 4 + (threadIdx.x >> 6);
  const us* base = ((lane < 32) ? hh : hl) + (size_t)(lane & 31) * 4;
  const int b = row_ptr[n], e = row_ptr[n + 1];
  float a0 = 0.f, a1 = 0.f, a2 = 0.f, a3 = 0.f;
  int i = b;
  for (; i + 2 <= e; i += 2) {
    int s0 = csr[i], s1 = csr[i + 1];
    uint2 v0 = *(const uint2*)(base + (size_t)s0 * lda);
    uint2 v1 = *(const uint2*)(base + (size_t)s1 * lda);
    float w0 = rs_out[s0], w1 = rs_out[s1];
    a0 = fmaf(w0, __uint_as_float(v0.x << 16), a0);
    a1 = fmaf(w0, __uint_as_float(v0.x & 0xffff0000u), a1);
    a2 = fmaf(w0, __uint_as_float(v0.y << 16), a2);
    a3 = fmaf(w0, __uint_as_float(v0.y & 0xffff0000u), a3);
    a0 = fmaf(w1, __uint_as_float(v1.x << 16), a0);
    a1 = fmaf(w1, __uint_as_float(v1.x & 0xffff0000u), a1);
    a2 = fmaf(w1, __uint_as_float(v1.y << 16), a2);
    a3 = fmaf(w1, __uint_as_float(v1.y & 0xffff0000u), a3);
  }
  if (i < e) {
    int s0 = csr[i];
    uint2 v0 = *(const uint2*)(base + (size_t)s0 * lda);
    float w0 = rs_out[s0];
    a0 = fmaf(w0, __uint_as_float(v0.x << 16), a0);
    a1 = fmaf(w0, __uint_as_float(v0.x & 0xffff0000u), a1);
    a2 = fmaf(w0, __uint_as_float(v0.y << 16), a2);
    a3 = fmaf(w0, __uint_as_float(v0.y & 0xffff0000u), a3);
  }
  a0 += __shfl_xor(a0, 32);
  a1 += __shfl_xor(a1, 32);
  a2 += __shfl_xor(a2, 32);
  a3 += __shfl_xor(a3, 32);
  const float ri = rs_in[n];
  a0 *= ri; a1 *= ri; a2 *= ri; a3 *= ri;
  us h[4], l[4];
  split2(a0, h[0], l[0]); split2(a1, h[1], l[1]);
  split2(a2, h[2], l[2]); split2(a3, h[3], l[3]);
  size_t o = (size_t)n * 128 + (size_t)(lane & 31) * 4;
  if (lane < 32) {
    uint2 wv = make_uint2((unsigned)h[0] | ((unsigned)h[1] << 16),
                          (unsigned)h[2] | ((unsigned)h[3] << 16));
    *(uint2*)(aggh + o) = wv;
  } else {
    uint2 wv = make_uint2((unsigned)l[0] | ((unsigned)l[1] << 16),
                          (unsigned)l[2] | ((unsigned)l[3] << 16));
    *(uint2*)(aggl + o) = wv;
  }
}

// ---------------- double-buffered split-bf16 MFMA GEMM (2-phase prefetch) ----------------
// BM=128, BK=32, BN=NF*64. 512 threads = 8 waves (2M x 4N). Wave tile 64 x NF*16.
// Prefetch: STAGE(buf^1, kt+1) issued BEFORE ds_read+MFMA of buf; one vmcnt(0)+barrier
// per K-step (T3 minimum-2-phase recipe).
// NSPLIT=2: grid = 2*Mblocks; XCD-pair swizzle puts both N-halves of an M-panel on one XCD.
// MODE 0: conv head  MODE 1: conv res (+prev)  MODE 2: fusion+max  MODE 3: p1 (+gcon)
// MODE 4: p2 (fp32 out, ld 64)
template<int KTOT, int NF, int MODE, int NSPLIT>
__global__ __launch_bounds__(512, 4) void mgemm(
    const us* __restrict__ Ah, const us* __restrict__ Al, int lda,
    const us* __restrict__ Bh, const us* __restrict__ Bl,
    const float* __restrict__ bias,
    float* __restrict__ outf, us* __restrict__ outh, us* __restrict__ outl,
    int ldo, int colOff,
    const us* __restrict__ prevh, const us* __restrict__ prevl,
    const float* __restrict__ gcon) {
  constexpr int BN  = NF * 64;
  constexpr int BCH = BN * 4;                 // 16B chunks per B plane tile
  constexpr int BSH = (NF == 2) ? 7 : 6;      // log2(BN)
  constexpr int NT  = KTOT / 32;

  __shared__ __align__(16) us sAh[2][4][128][8];
  __shared__ __align__(16) us sAl[2][4][128][8];
  __shared__ __align__(16) us sBh[2][4][BN][8];
  __shared__ __align__(16) us sBl[2][4][BN][8];

  const int t = threadIdx.x;
  int mb, nb;
  if constexpr (NSPLIT == 2) {
    int lid = (blockIdx.x & 7) * ((int)gridDim.x >> 3) + (blockIdx.x >> 3);
    mb = lid >> 1; nb = lid & 1;
  } else {
    mb = blockIdx.x; nb = 0;
  }
  const int mbase = mb * 128;
  const int nbase = nb * BN;

  // staging maps
  const int akb = t >> 7, ar = t & 127;
  const us* gAh = Ah + (size_t)(mbase + ar) * lda + akb * 8;
  const us* gAl = Al + (size_t)(mbase + ar) * lda + akb * 8;
  const bool bact = (t < BCH);
  const int bkb = (t >> BSH) & 3, br = t & (BN - 1);
  const us* gBh = Bh + (size_t)(nbase + br) * KTOT + bkb * 8;
  const us* gBl = Bl + (size_t)(nbase + br) * KTOT + bkb * 8;

  const int lane = t & 63, wv = t >> 6;
  const int wm = wv & 1, wn = wv >> 1;
  const int l15 = lane & 15, lkb = lane >> 4;

  f32x4 acc[4][NF];
#pragma unroll
  for (int i = 0; i < 4; ++i)
#pragma unroll
    for (int j = 0; j < NF; ++j)
#pragma unroll
      for (int e = 0; e < 4; ++e) acc[i][j][e] = 0.f;

  auto stage = [&](int buf, int k0) {
    gload16(gAh + k0, &sAh[buf][akb][ar][0]);
    gload16(gAl + k0, &sAl[buf][akb][ar][0]);
    if (bact) {
      gload16(gBh + k0, &sBh[buf][bkb][br][0]);
      gload16(gBl + k0, &sBl[buf][bkb][br][0]);
    }
  };

  stage(0, 0);
  __syncthreads();
  int cur = 0;

  for (int kt = 0; kt < NT; ++kt) {
    if (kt + 1 < NT) stage(cur ^ 1, (kt + 1) * 32);   // prefetch next K-tile

    short8 ah[4], al[4], bh[NF], bl[NF];
#pragma unroll
    for (int fm = 0; fm < 4; ++fm) {
      ah[fm] = *(const short8*)&sAh[cur][lkb][wm * 64 + fm * 16 + l15][0];
      al[fm] = *(const short8*)&sAl[cur][lkb][wm * 64 + fm * 16 + l15][0];
    }
#pragma unroll
    for (int fn = 0; fn < NF; ++fn) {
      bh[fn] = *(const short8*)&sBh[cur][lkb][wn * (NF * 16) + fn * 16 + l15][0];
      bl[fn] = *(const short8*)&sBl[cur][lkb][wn * (NF * 16) + fn * 16 + l15][0];
    }
#pragma unroll
    for (int fm = 0; fm < 4; ++fm)
#pragma unroll
      for (int fn = 0; fn < NF; ++fn)
        acc[fm][fn] = __builtin_amdgcn_mfma_f32_16x16x32_bf16(ah[fm], bh[fn], acc[fm][fn], 0, 0, 0);
#pragma unroll
    for (int fm = 0; fm < 4; ++fm)
#pragma unroll
      for (int fn = 0; fn < NF; ++fn)
        acc[fm][fn] = __builtin_amdgcn_mfma_f32_16x16x32_bf16(al[fm], bh[fn], acc[fm][fn], 0, 0, 0);
#pragma unroll
    for (int fm = 0; fm < 4; ++fm)
#pragma unroll
      for (int fn = 0; fn < NF; ++fn)
        acc[fm][fn] = __builtin_amdgcn_mfma_f32_16x16x32_bf16(ah[fm], bl[fn], acc[fm][fn], 0, 0, 0);

    __syncthreads();   // drains prefetch (vmcnt 0) + frees buf for next stage
    cur ^= 1;
  }

  // C/D: col = lane&15, row = (lane>>4)*4 + reg
  if constexpr (MODE == 0 || MODE == 1 || MODE == 3) {
    const float* gc = (MODE == 3) ? (gcon + (size_t)mb * 256 + nbase) : nullptr;
#pragma unroll
    for (int fm = 0; fm < 4; ++fm)
#pragma unroll
      for (int fn = 0; fn < NF; ++fn) {
        const int col = wn * (NF * 16) + fn * 16 + l15;
        float bb = bias[nbase + col];
        if constexpr (MODE == 3) bb += gc[col];
#pragma unroll
        for (int r = 0; r < 4; ++r) {
          const int row = mbase + wm * 64 + fm * 16 + lkb * 4 + r;
          float v = leaky(acc[fm][fn][r] + bb);
          const size_t off = (size_t)row * ldo + colOff + nbase + col;
          if constexpr (MODE == 1) v += b2f(prevh[off - 128]) + b2f(prevl[off - 128]);
          us hi, lo; split2(v, hi, lo);
          outh[off] = hi;
          outl[off] = lo;
        }
      }
  } else if constexpr (MODE == 2) {
    __shared__ float red[2][128];
#pragma unroll
    for (int fn = 0; fn < NF; ++fn) {
      float m = acc[0][fn][0];
#pragma unroll
      for (int fm = 0; fm < 4; ++fm)
#pragma unroll
        for (int r = 0; r < 4; ++r) m = fmaxf(m, acc[fm][fn][r]);
      m = fmaxf(m, __shfl_xor(m, 16));
      m = fmaxf(m, __shfl_xor(m, 32));
      if (lane < 16) red[wm][wn * (NF * 16) + fn * 16 + l15] = m;
    }
    __syncthreads();
    if (t < 128)
      outf[(size_t)mb * 256 + nbase + t] = fmaxf(red[0][t], red[1][t]) + bias[nbase + t];
  } else {  // MODE 4
#pragma unroll
    for (int fm = 0; fm < 4; ++fm) {
      const int col = wn * 16 + l15;
      const float bb = bias[col];
#pragma unroll
      for (int r = 0; r < 4; ++r) {
        const int row = mbase + wm * 64 + fm * 16 + lkb * 4 + r;
        outf[(size_t)row * 64 + col] = leaky(acc[fm][0][r] + bb);
      }
    }
  }
}

// gcon[s][o] = sum_{c<256} gmax[s][c] * W_p1[o][c]
__global__ void gcon_kernel(const float* __restrict__ gmax, const float* __restrict__ Wp1,
                            float* __restrict__ gcon) {
  __shared__ float g[256];
  int s = blockIdx.x, o = threadIdx.x;
  g[o] = gmax[(size_t)s * 256 + o];
  __syncthreads();
  float acc = 0.f;
  const float* wr = Wp1 + (size_t)o * 768;
#pragma unroll 8
  for (int c = 0; c < 256; ++c) acc += g[c] * wr[c];
  gcon[(size_t)s * 256 + o] = acc;
}

// out[s][o][v] = b3[o] + sum_{j<64} y2[n][j] * Wp3[o][j],  n = s*128+v
__global__ void p3_kernel(const float* __restrict__ y2, const float* __restrict__ W,
                          const float* __restrict__ b, float* __restrict__ out) {
  __shared__ float w0[64], w1[64];
  int t = threadIdx.x;
  if (t < 64) { w0[t] = W[t]; w1[t] = W[64 + t]; }
  __syncthreads();
  int n = blockIdx.x * 256 + t;
  const float* row = y2 + (size_t)n * 64;
  float a0 = b[0], a1 = b[1];
#pragma unroll
  for (int j = 0; j < 64; j += 4) {
    float4 v = *(const float4*)(row + j);
    a0 += v.x * w0[j] + v.y * w0[j + 1] + v.z * w0[j + 2] + v.w * w0[j + 3];
    a1 += v.x * w1[j] + v.y * w1[j + 1] + v.z * w1[j + 2] + v.w * w1[j + 3];
  }
  int s = n >> 7, vv = n & 127;
  out[((size_t)s * 2 + 0) * 128 + vv] = a0;
  out[((size_t)s * 2 + 1) * 128 + vv] = a1;
}

extern "C" void kernel_launch(void* const* d_in, const int* in_sizes, int n_in,
                              void* d_out, int out_size, void* d_ws, size_t ws_size,
                              hipStream_t stream) {
  const float* x        = (const float*)d_in[0];
  const int*   esrc     = (const int*)d_in[1];
  const int*   edst     = (const int*)d_in[2];
  const float* W_head   = (const float*)d_in[3];
  const float* b_head   = (const float*)d_in[4];
  const float* W_res[3] = {(const float*)d_in[5], (const float*)d_in[7], (const float*)d_in[9]};
  const float* b_res[3] = {(const float*)d_in[6], (const float*)d_in[8], (const float*)d_in[10]};
  const float* W_fusion = (const float*)d_in[11];
  const float* b_fusion = (const float*)d_in[12];
  const float* W_p1     = (const float*)d_in[13];
  const float* b_p1     = (const float*)d_in[14];
  const float* W_p2     = (const float*)d_in[15];
  const float* b_p2     = (const float*)d_in[16];
  const float* W_p3     = (const float*)d_in[17];
  const float* b_p3     = (const float*)d_in[18];
  float* outp = (float*)d_out;

  char* w = (char*)d_ws;
  size_t off = 0;
  auto alloc = [&](size_t bytes) { char* p = w + off; off += (bytes + 255) & ~(size_t)255; return p; };

  us* states_h = (us*)alloc((size_t)NN * 512 * 2);
  us* states_l = (us*)alloc((size_t)NN * 512 * 2);
  char* regionA = alloc((size_t)NN * 128 * 2 * 4);   // h0h|h0l|aggh|aggl, later y1h|y1l
  us* h0h  = (us*)regionA;
  us* h0l  = (us*)(regionA + (size_t)NN * 128 * 2);
  us* aggh = (us*)(regionA + (size_t)NN * 128 * 4);
  us* aggl = (us*)(regionA + (size_t)NN * 128 * 6);
  us* y1h  = (us*)regionA;
  us* y1l  = (us*)(regionA + (size_t)NN * 256 * 2);
  float* y2 = (float*)states_h;                       // states dead after p1

  float* gmax   = (float*)alloc(512 * 256 * 4);
  float* gcon   = (float*)alloc(512 * 256 * 4);
  float* rs_out = (float*)alloc((size_t)NN * 4);
  float* rs_in  = (float*)alloc((size_t)NN * 4);
  us* cWh[4]; us* cWl[4];
  for (int l = 0; l < 4; ++l) { cWh[l] = (us*)alloc(128 * 128 * 2); cWl[l] = (us*)alloc(128 * 128 * 2); }
  us* fWh  = (us*)alloc(256 * 512 * 2);
  us* fWl  = (us*)alloc(256 * 512 * 2);
  us* p1Wh = (us*)alloc(256 * 512 * 2);
  us* p1Wl = (us*)alloc(256 * 512 * 2);
  us* p2Wh = (us*)alloc(64 * 256 * 2);
  us* p2Wl = (us*)alloc(64 * 256 * 2);
  int* cnt_out = (int*)alloc((size_t)NN * 4);
  int* cnt_in  = (int*)alloc((size_t)NN * 4);
  int* cursor  = (int*)alloc((size_t)NN * 4);
  int* row_ptr = (int*)alloc(((size_t)NN + 1) * 4);
  int* csr     = (int*)alloc((size_t)NE * 4);

  zero_ints<<<(3 * NN + 255) / 256, 256, 0, stream>>>(cnt_out, 3 * NN);
  deg_count<<<NE / 256, 256, 0, stream>>>(esrc, edst, cnt_out, cnt_in);
  rs_kernel<<<NN / 256, 256, 0, stream>>>(cnt_out, cnt_in, rs_out, rs_in);
  scan_kernel<<<1, 1024, 0, stream>>>(cnt_in, row_ptr);
  csr_fill<<<NE / 256, 256, 0, stream>>>(esrc, edst, row_ptr, cursor, csr);

  transpose_x<<<1024, 256, 0, stream>>>(x, h0h, h0l);
  const float* cW[4] = {W_head, W_res[0], W_res[1], W_res[2]};
  for (int l = 0; l < 4; ++l)
    wsplit_t<<<64, 256, 0, stream>>>(cW[l], cWh[l], cWl[l], 128, 128, 128);
  wsplit<<<512, 256, 0, stream>>>(W_fusion, fWh, fWl, 256, 512, 512, 0);
  wsplit<<<512, 256, 0, stream>>>(W_p1, p1Wh, p1Wl, 256, 512, 768, 256);
  wsplit<<<64, 256, 0, stream>>>(W_p2, p2Wh, p2Wl, 64, 256, 256, 0);

  const float* cB[4] = {b_head, b_res[0], b_res[1], b_res[2]};
  // layer 1 (head)
  aggregate<<<NN / 4, 256, 0, stream>>>(h0h, h0l, 128, row_ptr, csr, rs_out, rs_in, aggh, aggl);
  mgemm<128, 2, 0, 1><<<512, 512, 0, stream>>>(aggh, aggl, 128, cWh[0], cWl[0], cB[0],
                                               nullptr, states_h, states_l, 512, 0,
                                               nullptr, nullptr, nullptr);
  // layers 2..4 (residual)
  for (int l = 1; l <= 3; ++l) {
    aggregate<<<NN / 4, 256, 0, stream>>>(states_h + (size_t)(l - 1) * 128,
                                          states_l + (size_t)(l - 1) * 128, 512,
                                          row_ptr, csr, rs_out, rs_in, aggh, aggl);
    mgemm<128, 2, 1, 1><<<512, 512, 0, stream>>>(aggh, aggl, 128, cWh[l], cWl[l], cB[l],
                                                 nullptr, states_h, states_l, 512, l * 128,
                                                 states_h, states_l, nullptr);
  }
  // fusion conv + per-slice max -> gmax  (N=256 split into 2 blocks)
  mgemm<512, 2, 2, 2><<<1024, 512, 0, stream>>>(states_h, states_l, 512, fWh, fWl, b_fusion,
                                                gmax, nullptr, nullptr, 0, 0,
                                                nullptr, nullptr, nullptr);
  gcon_kernel<<<512, 256, 0, stream>>>(gmax, W_p1, gcon);
  // p1 -> y1 planes
  mgemm<512, 2, 3, 2><<<1024, 512, 0, stream>>>(states_h, states_l, 512, p1Wh, p1Wl, b_p1,
                                                nullptr, y1h, y1l, 256, 0,
                                                nullptr, nullptr, gcon);
  // p2 -> y2 fp32 [NN][64]
  mgemm<256, 1, 4, 1><<<512, 512, 0, stream>>>(y1h, y1l, 256, p2Wh, p2Wl, b_p2,
                                               y2, nullptr, nullptr, 0, 0,
                                               nullptr, nullptr, nullptr);
  // p3
  p3_kernel<<<NN / 256, 256, 0, stream>>>(y2, W_p3, b_p3, outp);
}

// Round 5
// 628.372 us; speedup vs baseline: 1.8040x; 1.0153x over previous
//
#include <hip/hip_runtime.h>

#define NN 65536
#define NE 524288
#define SLOPE 0.01f

typedef unsigned short us;
typedef __attribute__((ext_vector_type(8))) short short8;
typedef __attribute__((ext_vector_type(4))) float f32x4;

__device__ __forceinline__ float leaky(float v) { return v >= 0.f ? v : SLOPE * v; }
__device__ __forceinline__ float b2f(us u) { return __uint_as_float(((unsigned)u) << 16); }
__device__ __forceinline__ us f2b(float f) {
  unsigned u = __float_as_uint(f);
  u += 0x7fffu + ((u >> 16) & 1u);
  return (us)(u >> 16);
}
__device__ __forceinline__ void split2(float v, us& hi, us& lo) {
  hi = f2b(v);
  lo = f2b(v - b2f(hi));
}

__device__ __forceinline__ void gload16(const void* g, void* l) {
  __builtin_amdgcn_global_load_lds(
      (const __attribute__((address_space(1))) unsigned int*)g,
      (__attribute__((address_space(3))) unsigned int*)l, 16, 0, 0);
}

// ---------------- graph preprocessing ----------------
__global__ void zero_ints(int* __restrict__ p, int n) {
  int i = blockIdx.x * blockDim.x + threadIdx.x;
  if (i < n) p[i] = 0;
}

__global__ void deg_count(const int* __restrict__ src, const int* __restrict__ dst,
                          int* __restrict__ cout, int* __restrict__ cin) {
  int e = blockIdx.x * blockDim.x + threadIdx.x;
  if (e < NE) {
    atomicAdd(&cout[src[e]], 1);
    atomicAdd(&cin[dst[e]], 1);
  }
}

__global__ void rs_kernel(const int* __restrict__ cout, const int* __restrict__ cin,
                          float* __restrict__ rs_out, float* __restrict__ rs_in) {
  int n = blockIdx.x * blockDim.x + threadIdx.x;
  if (n < NN) {
    rs_out[n] = rsqrtf((float)(cout[n] > 0 ? cout[n] : 1));
    rs_in[n]  = rsqrtf((float)(cin[n]  > 0 ? cin[n]  : 1));
  }
}

__global__ __launch_bounds__(1024) void scan_kernel(const int* __restrict__ cnt,
                                                    int* __restrict__ row_ptr) {
  __shared__ int part[1024];
  int t = threadIdx.x;
  int base = t * 64;
  int s = 0;
  for (int i = 0; i < 64; ++i) s += cnt[base + i];
  part[t] = s;
  __syncthreads();
  for (int d = 1; d < 1024; d <<= 1) {
    int v = (t >= d) ? part[t - d] : 0;
    __syncthreads();
    part[t] += v;
    __syncthreads();
  }
  int run = part[t] - s;
  for (int i = 0; i < 64; ++i) { row_ptr[base + i] = run; run += cnt[base + i]; }
  if (t == 1023) row_ptr[NN] = run;
}

__global__ void csr_fill(const int* __restrict__ src, const int* __restrict__ dst,
                         const int* __restrict__ row_ptr, int* __restrict__ cursor,
                         int* __restrict__ csr) {
  int e = blockIdx.x * blockDim.x + threadIdx.x;
  if (e < NE) {
    int d = dst[e];
    int pos = atomicAdd(&cursor[d], 1);
    csr[row_ptr[d] + pos] = src[e];
  }
}

// x [512][128c][128v] -> h0 planes [65536 node][128 c] (hi/lo bf16)
__global__ __launch_bounds__(256) void transpose_x(const float* __restrict__ x,
                                                   us* __restrict__ h0h,
                                                   us* __restrict__ h0l) {
  __shared__ float tile[128][68];
  int s  = blockIdx.x >> 1;
  int vh = (blockIdx.x & 1) * 64;
  const float* xs = x + (size_t)s * 16384;
  int t = threadIdx.x;
  int v4 = t & 15, c0 = t >> 4;
  for (int p = 0; p < 8; ++p) {
    int c = c0 + p * 16;
    float4 val = *(const float4*)(xs + (size_t)c * 128 + vh + v4 * 4);
    *(float4*)&tile[c][v4 * 4] = val;
  }
  __syncthreads();
  int c4 = t & 31, v0 = t >> 5;
  for (int p = 0; p < 8; ++p) {
    int v = v0 + p * 8;
    float o[4];
    o[0] = tile[c4 * 4 + 0][v];
    o[1] = tile[c4 * 4 + 1][v];
    o[2] = tile[c4 * 4 + 2][v];
    o[3] = tile[c4 * 4 + 3][v];
    us hh[4], ll[4];
#pragma unroll
    for (int j = 0; j < 4; ++j) split2(o[j], hh[j], ll[j]);
    size_t off = (size_t)(s * 128 + vh + v) * 128 + c4 * 4;
    uint2 wh = make_uint2((unsigned)hh[0] | ((unsigned)hh[1] << 16),
                          (unsigned)hh[2] | ((unsigned)hh[3] << 16));
    uint2 wl = make_uint2((unsigned)ll[0] | ((unsigned)ll[1] << 16),
                          (unsigned)ll[2] | ((unsigned)ll[3] << 16));
    *(uint2*)(h0h + off) = wh;
    *(uint2*)(h0l + off) = wl;
  }
}

// weight split, fragment-major layout B'[n][k] (src row-major [n][ld], cols koff..)
__global__ void wsplit(const float* __restrict__ src, us* __restrict__ bh,
                       us* __restrict__ bl, int N, int K, int ld, int koff) {
  int idx = blockIdx.x * 256 + threadIdx.x;
  if (idx >= N * K) return;
  int n = idx / K, k = idx - n * K;
  float v = src[(size_t)n * ld + koff + k];
  us hi, lo; split2(v, hi, lo);
  bh[idx] = hi; bl[idx] = lo;
}

// weight split transposed: B'[n][k] = src[k*ld + n]   (conv weights W[k_in][n_out])
__global__ void wsplit_t(const float* __restrict__ src, us* __restrict__ bh,
                         us* __restrict__ bl, int N, int K, int ld) {
  int idx = blockIdx.x * 256 + threadIdx.x;
  if (idx >= N * K) return;
  int n = idx / K, k = idx - n * K;
  float v = src[(size_t)k * ld + n];
  us hi, lo; split2(v, hi, lo);
  bh[idx] = hi; bl[idx] = lo;
}

// wave-per-node aggregate: lanes 0-31 gather hi plane, 32-63 lo plane (8B/lane),
// 4-edge unroll for MLP; shfl_xor(32) merges; writes split agg planes.
__global__ __launch_bounds__(256) void aggregate(
    const us* __restrict__ hh, const us* __restrict__ hl, int lda,
    const int* __restrict__ row_ptr, const int* __restrict__ csr,
    const float* __restrict__ rs_out, const float* __restrict__ rs_in,
    us* __restrict__ aggh, us* __restrict__ aggl) {
  const int lane = threadIdx.x & 63;
  const int n = blockIdx.x * 4 + (threadIdx.x >> 6);
  const us* base = ((lane < 32) ? hh : hl) + (size_t)(lane & 31) * 4;
  const int b = row_ptr[n], e = row_ptr[n + 1];
  float a0 = 0.f, a1 = 0.f, a2 = 0.f, a3 = 0.f;
  int i = b;
  for (; i + 4 <= e; i += 4) {
    int s0 = csr[i], s1 = csr[i + 1], s2 = csr[i + 2], s3 = csr[i + 3];
    uint2 v0 = *(const uint2*)(base + (size_t)s0 * lda);
    uint2 v1 = *(const uint2*)(base + (size_t)s1 * lda);
    uint2 v2 = *(const uint2*)(base + (size_t)s2 * lda);
    uint2 v3 = *(const uint2*)(base + (size_t)s3 * lda);
    float w0 = rs_out[s0], w1 = rs_out[s1], w2 = rs_out[s2], w3 = rs_out[s3];
    a0 = fmaf(w0, __uint_as_float(v0.x << 16), a0);
    a1 = fmaf(w0, __uint_as_float(v0.x & 0xffff0000u), a1);
    a2 = fmaf(w0, __uint_as_float(v0.y << 16), a2);
    a3 = fmaf(w0, __uint_as_float(v0.y & 0xffff0000u), a3);
    a0 = fmaf(w1, __uint_as_float(v1.x << 16), a0);
    a1 = fmaf(w1, __uint_as_float(v1.x & 0xffff0000u), a1);
    a2 = fmaf(w1, __uint_as_float(v1.y << 16), a2);
    a3 = fmaf(w1, __uint_as_float(v1.y & 0xffff0000u), a3);
    a0 = fmaf(w2, __uint_as_float(v2.x << 16), a0);
    a1 = fmaf(w2, __uint_as_float(v2.x & 0xffff0000u), a1);
    a2 = fmaf(w2, __uint_as_float(v2.y << 16), a2);
    a3 = fmaf(w2, __uint_as_float(v2.y & 0xffff0000u), a3);
    a0 = fmaf(w3, __uint_as_float(v3.x << 16), a0);
    a1 = fmaf(w3, __uint_as_float(v3.x & 0xffff0000u), a1);
    a2 = fmaf(w3, __uint_as_float(v3.y << 16), a2);
    a3 = fmaf(w3, __uint_as_float(v3.y & 0xffff0000u), a3);
  }
  for (; i < e; ++i) {
    int s0 = csr[i];
    uint2 v0 = *(const uint2*)(base + (size_t)s0 * lda);
    float w0 = rs_out[s0];
    a0 = fmaf(w0, __uint_as_float(v0.x << 16), a0);
    a1 = fmaf(w0, __uint_as_float(v0.x & 0xffff0000u), a1);
    a2 = fmaf(w0, __uint_as_float(v0.y << 16), a2);
    a3 = fmaf(w0, __uint_as_float(v0.y & 0xffff0000u), a3);
  }
  a0 += __shfl_xor(a0, 32);
  a1 += __shfl_xor(a1, 32);
  a2 += __shfl_xor(a2, 32);
  a3 += __shfl_xor(a3, 32);
  const float ri = rs_in[n];
  a0 *= ri; a1 *= ri; a2 *= ri; a3 *= ri;
  us h[4], l[4];
  split2(a0, h[0], l[0]); split2(a1, h[1], l[1]);
  split2(a2, h[2], l[2]); split2(a3, h[3], l[3]);
  size_t o = (size_t)n * 128 + (size_t)(lane & 31) * 4;
  if (lane < 32) {
    uint2 wv = make_uint2((unsigned)h[0] | ((unsigned)h[1] << 16),
                          (unsigned)h[2] | ((unsigned)h[3] << 16));
    *(uint2*)(aggh + o) = wv;
  } else {
    uint2 wv = make_uint2((unsigned)l[0] | ((unsigned)l[1] << 16),
                          (unsigned)l[2] | ((unsigned)l[3] << 16));
    *(uint2*)(aggl + o) = wv;
  }
}

// ---------------- counted-vmcnt double-buffered split-bf16 MFMA GEMM ----------------
// BM=128, BK=32, BN=NF*64. 512 threads = 8 waves (2M x 4N). Wave tile 64 x NF*16.
// T4: raw s_barrier + s_waitcnt vmcnt(LPT) — next buffer's loads stay in flight
// across barriers (never drain to 0 in the main loop). Uniform LPT loads/thread.
// Buffer parity is static (loop unrolled x2) to keep register arrays static-indexed.
// MODE 0: conv head  MODE 1: conv res (+prev)  MODE 2: fusion+max  MODE 3: p1 (+gcon)
// MODE 4: p2 (fp32 out, ld 64)
template<int KTOT, int NF, int MODE, int NSPLIT>
__global__ __launch_bounds__(512, 4) void mgemm(
    const us* __restrict__ Ah, const us* __restrict__ Al, int lda,
    const us* __restrict__ Bh, const us* __restrict__ Bl,
    const float* __restrict__ bias,
    float* __restrict__ outf, us* __restrict__ outh, us* __restrict__ outl,
    int ldo, int colOff,
    const us* __restrict__ prevh, const us* __restrict__ prevl,
    const float* __restrict__ gcon) {
  constexpr int BN  = NF * 64;
  constexpr int LB  = (NF == 2) ? 7 : 6;        // log2(BN)
  constexpr int NT  = KTOT / 32;                // even for all uses
  constexpr int LPT = 2 + (BN * 8) / 512;       // uniform loads per thread per stage

  __shared__ __align__(16) us sAh[2][4][128][8];
  __shared__ __align__(16) us sAl[2][4][128][8];
  __shared__ __align__(16) us sBh[2][4][BN][8];
  __shared__ __align__(16) us sBl[2][4][BN][8];

  const int t = threadIdx.x;
  int mb, nb;
  if constexpr (NSPLIT == 2) {
    int lid = (blockIdx.x & 7) * ((int)gridDim.x >> 3) + (blockIdx.x >> 3);
    mb = lid >> 1; nb = lid & 1;
  } else {
    mb = blockIdx.x; nb = 0;
  }
  const int mbase = mb * 128;
  const int nbase = nb * BN;

  // uniform chunk map: ids [0,512)=A-hi, [512,1024)=A-lo, then B-hi, B-lo.
  // chunk c (A): row=c&127, kb=c>>7;  (B): row=c&(BN-1), kb=c>>LB.
  // LDS offset = c*16B within plane buffer -> lane-linear per wave (DMA-safe).
  const us* gp[LPT];
  us* lp0[LPT];
  us* lp1[LPT];
#pragma unroll
  for (int i = 0; i < LPT; ++i) {
    int id = i * 512 + t;
    if (id < 512) {
      int row = id & 127, kb = id >> 7;
      gp[i]  = Ah + (size_t)(mbase + row) * lda + kb * 8;
      lp0[i] = &sAh[0][kb][row][0];
      lp1[i] = &sAh[1][kb][row][0];
    } else if (id < 1024) {
      int c = id - 512;
      int row = c & 127, kb = c >> 7;
      gp[i]  = Al + (size_t)(mbase + row) * lda + kb * 8;
      lp0[i] = &sAl[0][kb][row][0];
      lp1[i] = &sAl[1][kb][row][0];
    } else if (id < 1024 + BN * 4) {
      int c = id - 1024;
      int row = c & (BN - 1), kb = c >> LB;
      gp[i]  = Bh + (size_t)(nbase + row) * KTOT + kb * 8;
      lp0[i] = &sBh[0][kb][row][0];
      lp1[i] = &sBh[1][kb][row][0];
    } else {
      int c = id - 1024 - BN * 4;
      int row = c & (BN - 1), kb = c >> LB;
      gp[i]  = Bl + (size_t)(nbase + row) * KTOT + kb * 8;
      lp0[i] = &sBl[0][kb][row][0];
      lp1[i] = &sBl[1][kb][row][0];
    }
  }

  const int lane = t & 63, wvi = t >> 6;
  const int wm = wvi & 1, wn = wvi >> 1;
  const int l15 = lane & 15, lkb = lane >> 4;

  f32x4 acc[4][NF];
#pragma unroll
  for (int i = 0; i < 4; ++i)
#pragma unroll
    for (int j = 0; j < NF; ++j)
#pragma unroll
      for (int e = 0; e < 4; ++e) acc[i][j][e] = 0.f;

  auto stageb = [&](us* const* lp, int k0) {
#pragma unroll
    for (int i = 0; i < LPT; ++i) gload16(gp[i] + k0, lp[i]);
  };
  auto waitL = [&]() {
    if constexpr (LPT == 4) asm volatile("s_waitcnt vmcnt(4)" ::: "memory");
    else                    asm volatile("s_waitcnt vmcnt(3)" ::: "memory");
    __builtin_amdgcn_sched_barrier(0);
  };
  auto wait0 = [&]() {
    asm volatile("s_waitcnt vmcnt(0)" ::: "memory");
    __builtin_amdgcn_sched_barrier(0);
  };
  auto bar = [&]() {
    __builtin_amdgcn_s_barrier();
    __builtin_amdgcn_sched_barrier(0);
  };
  auto kstep = [&](us (&bAh)[4][128][8], us (&bAl)[4][128][8],
                   us (&bBh)[4][BN][8], us (&bBl)[4][BN][8]) {
    short8 ah[4], al[4], bh[NF], bl[NF];
#pragma unroll
    for (int fm = 0; fm < 4; ++fm) {
      ah[fm] = *(const short8*)&bAh[lkb][wm * 64 + fm * 16 + l15][0];
      al[fm] = *(const short8*)&bAl[lkb][wm * 64 + fm * 16 + l15][0];
    }
#pragma unroll
    for (int fn = 0; fn < NF; ++fn) {
      bh[fn] = *(const short8*)&bBh[lkb][wn * (NF * 16) + fn * 16 + l15][0];
      bl[fn] = *(const short8*)&bBl[lkb][wn * (NF * 16) + fn * 16 + l15][0];
    }
    __builtin_amdgcn_s_setprio(1);
#pragma unroll
    for (int fm = 0; fm < 4; ++fm)
#pragma unroll
      for (int fn = 0; fn < NF; ++fn)
        acc[fm][fn] = __builtin_amdgcn_mfma_f32_16x16x32_bf16(ah[fm], bh[fn], acc[fm][fn], 0, 0, 0);
#pragma unroll
    for (int fm = 0; fm < 4; ++fm)
#pragma unroll
      for (int fn = 0; fn < NF; ++fn)
        acc[fm][fn] = __builtin_amdgcn_mfma_f32_16x16x32_bf16(al[fm], bh[fn], acc[fm][fn], 0, 0, 0);
#pragma unroll
    for (int fm = 0; fm < 4; ++fm)
#pragma unroll
      for (int fn = 0; fn < NF; ++fn)
        acc[fm][fn] = __builtin_amdgcn_mfma_f32_16x16x32_bf16(ah[fm], bl[fn], acc[fm][fn], 0, 0, 0);
    __builtin_amdgcn_s_setprio(0);
  };

  stageb(lp0, 0);
  stageb(lp1, 32);
#pragma unroll 1
  for (int kt = 0; kt < NT; kt += 2) {
    waitL(); bar();
    kstep(sAh[0], sAl[0], sBh[0], sBl[0]);
    bar();
    if (kt + 2 < NT) stageb(lp0, (kt + 2) * 32);
    if (kt + 3 < NT) waitL(); else wait0();
    bar();
    kstep(sAh[1], sAl[1], sBh[1], sBl[1]);
    bar();
    if (kt + 3 < NT) stageb(lp1, (kt + 3) * 32);
  }

  // C/D: col = lane&15, row = (lane>>4)*4 + reg
  if constexpr (MODE == 0 || MODE == 1 || MODE == 3) {
    const float* gc = (MODE == 3) ? (gcon + (size_t)mb * 256 + nbase) : nullptr;
#pragma unroll
    for (int fm = 0; fm < 4; ++fm)
#pragma unroll
      for (int fn = 0; fn < NF; ++fn) {
        const int col = wn * (NF * 16) + fn * 16 + l15;
        float bb = bias[nbase + col];
        if constexpr (MODE == 3) bb += gc[col];
#pragma unroll
        for (int r = 0; r < 4; ++r) {
          const int row = mbase + wm * 64 + fm * 16 + lkb * 4 + r;
          float v = leaky(acc[fm][fn][r] + bb);
          const size_t off = (size_t)row * ldo + colOff + nbase + col;
          if constexpr (MODE == 1) v += b2f(prevh[off - 128]) + b2f(prevl[off - 128]);
          us hi, lo; split2(v, hi, lo);
          outh[off] = hi;
          outl[off] = lo;
        }
      }
  } else if constexpr (MODE == 2) {
    __shared__ float red[2][128];
#pragma unroll
    for (int fn = 0; fn < NF; ++fn) {
      float m = acc[0][fn][0];
#pragma unroll
      for (int fm = 0; fm < 4; ++fm)
#pragma unroll
        for (int r = 0; r < 4; ++r) m = fmaxf(m, acc[fm][fn][r]);
      m = fmaxf(m, __shfl_xor(m, 16));
      m = fmaxf(m, __shfl_xor(m, 32));
      if (lane < 16) red[wm][wn * (NF * 16) + fn * 16 + l15] = m;
    }
    __syncthreads();
    if (t < 128)
      outf[(size_t)mb * 256 + nbase + t] = fmaxf(red[0][t], red[1][t]) + bias[nbase + t];
  } else {  // MODE 4
#pragma unroll
    for (int fm = 0; fm < 4; ++fm) {
      const int col = wn * 16 + l15;
      const float bb = bias[col];
#pragma unroll
      for (int r = 0; r < 4; ++r) {
        const int row = mbase + wm * 64 + fm * 16 + lkb * 4 + r;
        outf[(size_t)row * 64 + col] = leaky(acc[fm][0][r] + bb);
      }
    }
  }
}

// gcon[s][o] = sum_{c<256} gmax[s][c] * W_p1[o][c]
__global__ void gcon_kernel(const float* __restrict__ gmax, const float* __restrict__ Wp1,
                            float* __restrict__ gcon) {
  __shared__ float g[256];
  int s = blockIdx.x, o = threadIdx.x;
  g[o] = gmax[(size_t)s * 256 + o];
  __syncthreads();
  float acc = 0.f;
  const float* wr = Wp1 + (size_t)o * 768;
#pragma unroll 8
  for (int c = 0; c < 256; ++c) acc += g[c] * wr[c];
  gcon[(size_t)s * 256 + o] = acc;
}

// out[s][o][v] = b3[o] + sum_{j<64} y2[n][j] * Wp3[o][j],  n = s*128+v
__global__ void p3_kernel(const float* __restrict__ y2, const float* __restrict__ W,
                          const float* __restrict__ b, float* __restrict__ out) {
  __shared__ float w0[64], w1[64];
  int t = threadIdx.x;
  if (t < 64) { w0[t] = W[t]; w1[t] = W[64 + t]; }
  __syncthreads();
  int n = blockIdx.x * 256 + t;
  const float* row = y2 + (size_t)n * 64;
  float a0 = b[0], a1 = b[1];
#pragma unroll
  for (int j = 0; j < 64; j += 4) {
    float4 v = *(const float4*)(row + j);
    a0 += v.x * w0[j] + v.y * w0[j + 1] + v.z * w0[j + 2] + v.w * w0[j + 3];
    a1 += v.x * w1[j] + v.y * w1[j + 1] + v.z * w1[j + 2] + v.w * w1[j + 3];
  }
  int s = n >> 7, vv = n & 127;
  out[((size_t)s * 2 + 0) * 128 + vv] = a0;
  out[((size_t)s * 2 + 1) * 128 + vv] = a1;
}

extern "C" void kernel_launch(void* const* d_in, const int* in_sizes, int n_in,
                              void* d_out, int out_size, void* d_ws, size_t ws_size,
                              hipStream_t stream) {
  const float* x        = (const float*)d_in[0];
  const int*   esrc     = (const int*)d_in[1];
  const int*   edst     = (const int*)d_in[2];
  const float* W_head   = (const float*)d_in[3];
  const float* b_head   = (const float*)d_in[4];
  const float* W_res[3] = {(const float*)d_in[5], (const float*)d_in[7], (const float*)d_in[9]};
  const float* b_res[3] = {(const float*)d_in[6], (const float*)d_in[8], (const float*)d_in[10]};
  const float* W_fusion = (const float*)d_in[11];
  const float* b_fusion = (const float*)d_in[12];
  const float* W_p1     = (const float*)d_in[13];
  const float* b_p1     = (const float*)d_in[14];
  const float* W_p2     = (const float*)d_in[15];
  const float* b_p2     = (const float*)d_in[16];
  const float* W_p3     = (const float*)d_in[17];
  const float* b_p3     = (const float*)d_in[18];
  float* outp = (float*)d_out;

  char* w = (char*)d_ws;
  size_t off = 0;
  auto alloc = [&](size_t bytes) { char* p = w + off; off += (bytes + 255) & ~(size_t)255; return p; };

  us* states_h = (us*)alloc((size_t)NN * 512 * 2);
  us* states_l = (us*)alloc((size_t)NN * 512 * 2);
  char* regionA = alloc((size_t)NN * 128 * 2 * 4);   // h0h|h0l|aggh|aggl, later y1h|y1l
  us* h0h  = (us*)regionA;
  us* h0l  = (us*)(regionA + (size_t)NN * 128 * 2);
  us* aggh = (us*)(regionA + (size_t)NN * 128 * 4);
  us* aggl = (us*)(regionA + (size_t)NN * 128 * 6);
  us* y1h  = (us*)regionA;
  us* y1l  = (us*)(regionA + (size_t)NN * 256 * 2);
  float* y2 = (float*)states_h;                       // states dead after p1

  float* gmax   = (float*)alloc(512 * 256 * 4);
  float* gcon   = (float*)alloc(512 * 256 * 4);
  float* rs_out = (float*)alloc((size_t)NN * 4);
  float* rs_in  = (float*)alloc((size_t)NN * 4);
  us* cWh[4]; us* cWl[4];
  for (int l = 0; l < 4; ++l) { cWh[l] = (us*)alloc(128 * 128 * 2); cWl[l] = (us*)alloc(128 * 128 * 2); }
  us* fWh  = (us*)alloc(256 * 512 * 2);
  us* fWl  = (us*)alloc(256 * 512 * 2);
  us* p1Wh = (us*)alloc(256 * 512 * 2);
  us* p1Wl = (us*)alloc(256 * 512 * 2);
  us* p2Wh = (us*)alloc(64 * 256 * 2);
  us* p2Wl = (us*)alloc(64 * 256 * 2);
  int* cnt_out = (int*)alloc((size_t)NN * 4);
  int* cnt_in  = (int*)alloc((size_t)NN * 4);
  int* cursor  = (int*)alloc((size_t)NN * 4);
  int* row_ptr = (int*)alloc(((size_t)NN + 1) * 4);
  int* csr     = (int*)alloc((size_t)NE * 4);

  zero_ints<<<(3 * NN + 255) / 256, 256, 0, stream>>>(cnt_out, 3 * NN);
  deg_count<<<NE / 256, 256, 0, stream>>>(esrc, edst, cnt_out, cnt_in);
  rs_kernel<<<NN / 256, 256, 0, stream>>>(cnt_out, cnt_in, rs_out, rs_in);
  scan_kernel<<<1, 1024, 0, stream>>>(cnt_in, row_ptr);
  csr_fill<<<NE / 256, 256, 0, stream>>>(esrc, edst, row_ptr, cursor, csr);

  transpose_x<<<1024, 256, 0, stream>>>(x, h0h, h0l);
  const float* cW[4] = {W_head, W_res[0], W_res[1], W_res[2]};
  for (int l = 0; l < 4; ++l)
    wsplit_t<<<64, 256, 0, stream>>>(cW[l], cWh[l], cWl[l], 128, 128, 128);
  wsplit<<<512, 256, 0, stream>>>(W_fusion, fWh, fWl, 256, 512, 512, 0);
  wsplit<<<512, 256, 0, stream>>>(W_p1, p1Wh, p1Wl, 256, 512, 768, 256);
  wsplit<<<64, 256, 0, stream>>>(W_p2, p2Wh, p2Wl, 64, 256, 256, 0);

  const float* cB[4] = {b_head, b_res[0], b_res[1], b_res[2]};
  // layer 1 (head)
  aggregate<<<NN / 4, 256, 0, stream>>>(h0h, h0l, 128, row_ptr, csr, rs_out, rs_in, aggh, aggl);
  mgemm<128, 2, 0, 1><<<512, 512, 0, stream>>>(aggh, aggl, 128, cWh[0], cWl[0], cB[0],
                                               nullptr, states_h, states_l, 512, 0,
                                               nullptr, nullptr, nullptr);
  // layers 2..4 (residual)
  for (int l = 1; l <= 3; ++l) {
    aggregate<<<NN / 4, 256, 0, stream>>>(states_h + (size_t)(l - 1) * 128,
                                          states_l + (size_t)(l - 1) * 128, 512,
                                          row_ptr, csr, rs_out, rs_in, aggh, aggl);
    mgemm<128, 2, 1, 1><<<512, 512, 0, stream>>>(aggh, aggl, 128, cWh[l], cWl[l], cB[l],
                                                 nullptr, states_h, states_l, 512, l * 128,
                                                 states_h, states_l, nullptr);
  }
  // fusion conv + per-slice max -> gmax  (N=256 split into 2 blocks)
  mgemm<512, 2, 2, 2><<<1024, 512, 0, stream>>>(states_h, states_l, 512, fWh, fWl, b_fusion,
                                                gmax, nullptr, nullptr, 0, 0,
                                                nullptr, nullptr, nullptr);
  gcon_kernel<<<512, 256, 0, stream>>>(gmax, W_p1, gcon);
  // p1 -> y1 planes
  mgemm<512, 2, 3, 2><<<1024, 512, 0, stream>>>(states_h, states_l, 512, p1Wh, p1Wl, b_p1,
                                                nullptr, y1h, y1l, 256, 0,
                                                nullptr, nullptr, gcon);
  // p2 -> y2 fp32 [NN][64]
  mgemm<256, 1, 4, 1><<<512, 512, 0, stream>>>(y1h, y1l, 256, p2Wh, p2Wl, b_p2,
                                               y2, nullptr, nullptr, 0, 0,
                                               nullptr, nullptr, nullptr);
  // p3
  p3_kernel<<<NN / 256, 256, 0, stream>>>(y2, W_p3, b_p3, outp);
}

// Round 6
// 616.472 us; speedup vs baseline: 1.8388x; 1.0193x over previous
//
#include <hip/hip_runtime.h>

#define NN 65536
#define NE 524288
#define SLOPE 0.01f

typedef unsigned short us;
typedef __attribute__((ext_vector_type(8))) short short8;
typedef __attribute__((ext_vector_type(4))) float f32x4;

__device__ __forceinline__ float leaky(float v) { return v >= 0.f ? v : SLOPE * v; }
__device__ __forceinline__ float b2f(us u) { return __uint_as_float(((unsigned)u) << 16); }
__device__ __forceinline__ us f2b(float f) {
  unsigned u = __float_as_uint(f);
  u += 0x7fffu + ((u >> 16) & 1u);
  return (us)(u >> 16);
}
__device__ __forceinline__ void split2(float v, us& hi, us& lo) {
  hi = f2b(v);
  lo = f2b(v - b2f(hi));
}

__device__ __forceinline__ void gload16(const void* g, void* l) {
  __builtin_amdgcn_global_load_lds(
      (const __attribute__((address_space(1))) unsigned int*)g,
      (__attribute__((address_space(3))) unsigned int*)l, 16, 0, 0);
}

// ---------------- graph preprocessing ----------------
__global__ void zero_ints(int* __restrict__ p, int n) {
  int i = blockIdx.x * blockDim.x + threadIdx.x;
  if (i < n) p[i] = 0;
}

__global__ void deg_count(const int* __restrict__ src, const int* __restrict__ dst,
                          int* __restrict__ cout, int* __restrict__ cin) {
  int e = blockIdx.x * blockDim.x + threadIdx.x;
  if (e < NE) {
    atomicAdd(&cout[src[e]], 1);
    atomicAdd(&cin[dst[e]], 1);
  }
}

__global__ void rs_kernel(const int* __restrict__ cout, const int* __restrict__ cin,
                          float* __restrict__ rs_out, float* __restrict__ rs_in) {
  int n = blockIdx.x * blockDim.x + threadIdx.x;
  if (n < NN) {
    rs_out[n] = rsqrtf((float)(cout[n] > 0 ? cout[n] : 1));
    rs_in[n]  = rsqrtf((float)(cin[n]  > 0 ? cin[n]  : 1));
  }
}

__global__ __launch_bounds__(1024) void scan_kernel(const int* __restrict__ cnt,
                                                    int* __restrict__ row_ptr) {
  __shared__ int part[1024];
  int t = threadIdx.x;
  int base = t * 64;
  int s = 0;
  for (int i = 0; i < 64; ++i) s += cnt[base + i];
  part[t] = s;
  __syncthreads();
  for (int d = 1; d < 1024; d <<= 1) {
    int v = (t >= d) ? part[t - d] : 0;
    __syncthreads();
    part[t] += v;
    __syncthreads();
  }
  int run = part[t] - s;
  for (int i = 0; i < 64; ++i) { row_ptr[base + i] = run; run += cnt[base + i]; }
  if (t == 1023) row_ptr[NN] = run;
}

__global__ void csr_fill(const int* __restrict__ src, const int* __restrict__ dst,
                         const int* __restrict__ row_ptr, int* __restrict__ cursor,
                         int* __restrict__ csr) {
  int e = blockIdx.x * blockDim.x + threadIdx.x;
  if (e < NE) {
    int d = dst[e];
    int pos = atomicAdd(&cursor[d], 1);
    csr[row_ptr[d] + pos] = src[e];
  }
}

// x [512][128c][128v] -> h0 planes [65536 node][128 c] (hi/lo bf16)
__global__ __launch_bounds__(256) void transpose_x(const float* __restrict__ x,
                                                   us* __restrict__ h0h,
                                                   us* __restrict__ h0l) {
  __shared__ float tile[128][68];
  int s  = blockIdx.x >> 1;
  int vh = (blockIdx.x & 1) * 64;
  const float* xs = x + (size_t)s * 16384;
  int t = threadIdx.x;
  int v4 = t & 15, c0 = t >> 4;
  for (int p = 0; p < 8; ++p) {
    int c = c0 + p * 16;
    float4 val = *(const float4*)(xs + (size_t)c * 128 + vh + v4 * 4);
    *(float4*)&tile[c][v4 * 4] = val;
  }
  __syncthreads();
  int c4 = t & 31, v0 = t >> 5;
  for (int p = 0; p < 8; ++p) {
    int v = v0 + p * 8;
    float o[4];
    o[0] = tile[c4 * 4 + 0][v];
    o[1] = tile[c4 * 4 + 1][v];
    o[2] = tile[c4 * 4 + 2][v];
    o[3] = tile[c4 * 4 + 3][v];
    us hh[4], ll[4];
#pragma unroll
    for (int j = 0; j < 4; ++j) split2(o[j], hh[j], ll[j]);
    size_t off = (size_t)(s * 128 + vh + v) * 128 + c4 * 4;
    uint2 wh = make_uint2((unsigned)hh[0] | ((unsigned)hh[1] << 16),
                          (unsigned)hh[2] | ((unsigned)hh[3] << 16));
    uint2 wl = make_uint2((unsigned)ll[0] | ((unsigned)ll[1] << 16),
                          (unsigned)ll[2] | ((unsigned)ll[3] << 16));
    *(uint2*)(h0h + off) = wh;
    *(uint2*)(h0l + off) = wl;
  }
}

// weight split, fragment-major layout B'[n][k] (src row-major [n][ld], cols koff..)
__global__ void wsplit(const float* __restrict__ src, us* __restrict__ bh,
                       us* __restrict__ bl, int N, int K, int ld, int koff) {
  int idx = blockIdx.x * 256 + threadIdx.x;
  if (idx >= N * K) return;
  int n = idx / K, k = idx - n * K;
  float v = src[(size_t)n * ld + koff + k];
  us hi, lo; split2(v, hi, lo);
  bh[idx] = hi; bl[idx] = lo;
}

// weight split transposed: B'[n][k] = src[k*ld + n]   (conv weights W[k_in][n_out])
__global__ void wsplit_t(const float* __restrict__ src, us* __restrict__ bh,
                         us* __restrict__ bl, int N, int K, int ld) {
  int idx = blockIdx.x * 256 + threadIdx.x;
  if (idx >= N * K) return;
  int n = idx / K, k = idx - n * K;
  float v = src[(size_t)k * ld + n];
  us hi, lo; split2(v, hi, lo);
  bh[idx] = hi; bl[idx] = lo;
}

// wave-per-node aggregate: lanes 0-31 gather hi plane, 32-63 lo plane (8B/lane),
// 4-edge unroll for MLP; shfl_xor(32) merges; writes split agg planes.
__global__ __launch_bounds__(256) void aggregate(
    const us* __restrict__ hh, const us* __restrict__ hl, int lda,
    const int* __restrict__ row_ptr, const int* __restrict__ csr,
    const float* __restrict__ rs_out, const float* __restrict__ rs_in,
    us* __restrict__ aggh, us* __restrict__ aggl) {
  const int lane = threadIdx.x & 63;
  const int n = blockIdx.x * 4 + (threadIdx.x >> 6);
  const us* base = ((lane < 32) ? hh : hl) + (size_t)(lane & 31) * 4;
  const int b = row_ptr[n], e = row_ptr[n + 1];
  float a0 = 0.f, a1 = 0.f, a2 = 0.f, a3 = 0.f;
  int i = b;
  for (; i + 4 <= e; i += 4) {
    int s0 = csr[i], s1 = csr[i + 1], s2 = csr[i + 2], s3 = csr[i + 3];
    uint2 v0 = *(const uint2*)(base + (size_t)s0 * lda);
    uint2 v1 = *(const uint2*)(base + (size_t)s1 * lda);
    uint2 v2 = *(const uint2*)(base + (size_t)s2 * lda);
    uint2 v3 = *(const uint2*)(base + (size_t)s3 * lda);
    float w0 = rs_out[s0], w1 = rs_out[s1], w2 = rs_out[s2], w3 = rs_out[s3];
    a0 = fmaf(w0, __uint_as_float(v0.x << 16), a0);
    a1 = fmaf(w0, __uint_as_float(v0.x & 0xffff0000u), a1);
    a2 = fmaf(w0, __uint_as_float(v0.y << 16), a2);
    a3 = fmaf(w0, __uint_as_float(v0.y & 0xffff0000u), a3);
    a0 = fmaf(w1, __uint_as_float(v1.x << 16), a0);
    a1 = fmaf(w1, __uint_as_float(v1.x & 0xffff0000u), a1);
    a2 = fmaf(w1, __uint_as_float(v1.y << 16), a2);
    a3 = fmaf(w1, __uint_as_float(v1.y & 0xffff0000u), a3);
    a0 = fmaf(w2, __uint_as_float(v2.x << 16), a0);
    a1 = fmaf(w2, __uint_as_float(v2.x & 0xffff0000u), a1);
    a2 = fmaf(w2, __uint_as_float(v2.y << 16), a2);
    a3 = fmaf(w2, __uint_as_float(v2.y & 0xffff0000u), a3);
    a0 = fmaf(w3, __uint_as_float(v3.x << 16), a0);
    a1 = fmaf(w3, __uint_as_float(v3.x & 0xffff0000u), a1);
    a2 = fmaf(w3, __uint_as_float(v3.y << 16), a2);
    a3 = fmaf(w3, __uint_as_float(v3.y & 0xffff0000u), a3);
  }
  for (; i < e; ++i) {
    int s0 = csr[i];
    uint2 v0 = *(const uint2*)(base + (size_t)s0 * lda);
    float w0 = rs_out[s0];
    a0 = fmaf(w0, __uint_as_float(v0.x << 16), a0);
    a1 = fmaf(w0, __uint_as_float(v0.x & 0xffff0000u), a1);
    a2 = fmaf(w0, __uint_as_float(v0.y << 16), a2);
    a3 = fmaf(w0, __uint_as_float(v0.y & 0xffff0000u), a3);
  }
  a0 += __shfl_xor(a0, 32);
  a1 += __shfl_xor(a1, 32);
  a2 += __shfl_xor(a2, 32);
  a3 += __shfl_xor(a3, 32);
  const float ri = rs_in[n];
  a0 *= ri; a1 *= ri; a2 *= ri; a3 *= ri;
  us h[4], l[4];
  split2(a0, h[0], l[0]); split2(a1, h[1], l[1]);
  split2(a2, h[2], l[2]); split2(a3, h[3], l[3]);
  size_t o = (size_t)n * 128 + (size_t)(lane & 31) * 4;
  if (lane < 32) {
    uint2 wv = make_uint2((unsigned)h[0] | ((unsigned)h[1] << 16),
                          (unsigned)h[2] | ((unsigned)h[3] << 16));
    *(uint2*)(aggh + o) = wv;
  } else {
    uint2 wv = make_uint2((unsigned)l[0] | ((unsigned)l[1] << 16),
                          (unsigned)l[2] | ((unsigned)l[3] << 16));
    *(uint2*)(aggl + o) = wv;
  }
}

// ---------------- 256-row multi-phase split-bf16 MFMA GEMM ----------------
// BM=256, BN = full N. 512 threads = 8 waves (WM x WN). Wave tile (256/WM) x (BN/WN).
// Dbuf flat LDS; 4 planes (Ah,Al,Bh,Bl) staged linearly (chunk id == LDS slot -> DMA-safe).
// Per K-tile (BK=32): PH phases of {ds_read subtile; setprio1; MFMA cluster; setprio0; bar};
// boundary: counted s_waitcnt vmcnt(LPT) + bar (prefetched tile's loads stay in flight
// through the phases). Grid = M/256 = 256 blocks = 1 per CU.
// MODE 0: conv head  MODE 1: conv res (+prev)  MODE 2: fusion+max  MODE 3: p1 (+gcon)
// MODE 4: p2 (fp32 out, ld 64)
template<int KTOT, int BN, int WM, int PH, int MODE>
__global__ __launch_bounds__(512) void mgemm8(
    const us* __restrict__ Ah, const us* __restrict__ Al, int lda,
    const us* __restrict__ Bh, const us* __restrict__ Bl,
    const float* __restrict__ bias,
    float* __restrict__ outf, us* __restrict__ outh, us* __restrict__ outl,
    int ldo, int colOff,
    const us* __restrict__ prevh, const us* __restrict__ prevl,
    const float* __restrict__ gcon) {
  constexpr int WN  = 8 / WM;
  constexpr int FM  = 16 / WM;           // 16x16 fragments in M per wave
  constexpr int FMP = FM / PH;           // fm per phase
  constexpr int NT  = KTOT / 32;         // K-tiles (even everywhere)
  constexpr int LBN = (BN == 256) ? 8 : ((BN == 128) ? 7 : 6);
  constexpr int CHT = 2048 + BN * 8;     // 16B chunks per tile (Ah,Al,Bh,Bl)
  constexpr int LPT = CHT / 512;         // gloads per thread per tile

  __shared__ __align__(16) us L[2][CHT * 8];

  const int t = threadIdx.x;
  const int mbase = blockIdx.x * 256;

  // chunk map: id [0,1024)=Ah, [1024,2048)=Al, [2048,2048+BN*4)=Bh, rest Bl.
  const us* gp[LPT];
#pragma unroll
  for (int i = 0; i < LPT; ++i) {
    int id = i * 512 + t;
    if (id < 1024) {
      int row = id & 255, kb = id >> 8;
      gp[i] = Ah + (size_t)(mbase + row) * lda + kb * 8;
    } else if (id < 2048) {
      int c = id - 1024, row = c & 255, kb = c >> 8;
      gp[i] = Al + (size_t)(mbase + row) * lda + kb * 8;
    } else if (id < 2048 + BN * 4) {
      int c = id - 2048, row = c & (BN - 1), kb = c >> LBN;
      gp[i] = Bh + (size_t)row * KTOT + kb * 8;
    } else {
      int c = id - 2048 - BN * 4, row = c & (BN - 1), kb = c >> LBN;
      gp[i] = Bl + (size_t)row * KTOT + kb * 8;
    }
  }

  const int lane = t & 63, wvi = t >> 6;
  const int wm = wvi & (WM - 1), wn = wvi / WM;
  const int l15 = lane & 15, lkb = lane >> 4;
  const int wrow = wm * (256 / WM);

  f32x4 acc[FM][4];
#pragma unroll
  for (int i = 0; i < FM; ++i)
#pragma unroll
    for (int j = 0; j < 4; ++j)
#pragma unroll
      for (int e = 0; e < 4; ++e) acc[i][j][e] = 0.f;

  auto stage = [&](us* Lb, int k0) {
#pragma unroll
    for (int i = 0; i < LPT; ++i)
      gload16(gp[i] + k0, Lb + (size_t)(i * 512 + t) * 8);
  };
  auto waitL = [&]() {
    if constexpr (LPT == 8)      asm volatile("s_waitcnt vmcnt(8)" ::: "memory");
    else if constexpr (LPT == 6) asm volatile("s_waitcnt vmcnt(6)" ::: "memory");
    else                         asm volatile("s_waitcnt vmcnt(5)" ::: "memory");
    __builtin_amdgcn_sched_barrier(0);
  };
  auto wait0 = [&]() {
    asm volatile("s_waitcnt vmcnt(0)" ::: "memory");
    __builtin_amdgcn_sched_barrier(0);
  };
  auto phases = [&](const us* Lb) {
#pragma unroll
    for (int p = 0; p < PH; ++p) {
      short8 ah[FMP], al[FMP], bh[4], bl[4];
#pragma unroll
      for (int f = 0; f < FMP; ++f) {
        const int arow = wrow + (p * FMP + f) * 16 + l15;
        ah[f] = *(const short8*)(Lb + ((size_t)(lkb * 256 + arow)) * 8);
        al[f] = *(const short8*)(Lb + ((size_t)(1024 + lkb * 256 + arow)) * 8);
      }
#pragma unroll
      for (int fn = 0; fn < 4; ++fn) {
        const int bcol = wn * 64 + fn * 16 + l15;
        bh[fn] = *(const short8*)(Lb + ((size_t)(2048 + lkb * BN + bcol)) * 8);
        bl[fn] = *(const short8*)(Lb + ((size_t)(2048 + BN * 4 + lkb * BN + bcol)) * 8);
      }
      __builtin_amdgcn_s_setprio(1);
#pragma unroll
      for (int f = 0; f < FMP; ++f)
#pragma unroll
        for (int fn = 0; fn < 4; ++fn)
          acc[p * FMP + f][fn] =
              __builtin_amdgcn_mfma_f32_16x16x32_bf16(ah[f], bh[fn], acc[p * FMP + f][fn], 0, 0, 0);
#pragma unroll
      for (int f = 0; f < FMP; ++f)
#pragma unroll
        for (int fn = 0; fn < 4; ++fn)
          acc[p * FMP + f][fn] =
              __builtin_amdgcn_mfma_f32_16x16x32_bf16(al[f], bh[fn], acc[p * FMP + f][fn], 0, 0, 0);
#pragma unroll
      for (int f = 0; f < FMP; ++f)
#pragma unroll
        for (int fn = 0; fn < 4; ++fn)
          acc[p * FMP + f][fn] =
              __builtin_amdgcn_mfma_f32_16x16x32_bf16(ah[f], bl[fn], acc[p * FMP + f][fn], 0, 0, 0);
      __builtin_amdgcn_s_setprio(0);
      __builtin_amdgcn_s_barrier();
    }
  };

  stage(L[0], 0);
  if (NT > 1) stage(L[1], 32);
#pragma unroll 1
  for (int kt = 0; kt < NT; kt += 2) {
    waitL();
    __builtin_amdgcn_s_barrier();
    phases(L[0]);
    if (kt + 2 < NT) stage(L[0], (kt + 2) * 32);
    if (kt + 3 < NT) waitL(); else wait0();
    __builtin_amdgcn_s_barrier();
    phases(L[1]);
    if (kt + 3 < NT) stage(L[1], (kt + 3) * 32);
  }

  // C/D: col = lane&15, row = (lane>>4)*4 + reg
  if constexpr (MODE == 0 || MODE == 1 || MODE == 3) {
    const float* gc = (MODE == 3) ? (gcon + (size_t)(blockIdx.x * 2 + wm) * 256) : nullptr;
#pragma unroll
    for (int fm = 0; fm < FM; ++fm)
#pragma unroll
      for (int fn = 0; fn < 4; ++fn) {
        const int col = wn * 64 + fn * 16 + l15;
        float bb = bias[col];
        if constexpr (MODE == 3) bb += gc[col];
#pragma unroll
        for (int r = 0; r < 4; ++r) {
          const int row = mbase + wrow + fm * 16 + lkb * 4 + r;
          float v = leaky(acc[fm][fn][r] + bb);
          const size_t off = (size_t)row * ldo + colOff + col;
          if constexpr (MODE == 1) v += b2f(prevh[off - 128]) + b2f(prevl[off - 128]);
          us hi, lo; split2(v, hi, lo);
          outh[off] = hi;
          outl[off] = lo;
        }
      }
  } else if constexpr (MODE == 2) {
    // WM==2: wave wm covers rows of slice blockIdx.x*2+wm entirely; cols disjoint by wn.
#pragma unroll
    for (int fn = 0; fn < 4; ++fn) {
      float m = acc[0][fn][0];
#pragma unroll
      for (int fm = 0; fm < FM; ++fm)
#pragma unroll
        for (int r = 0; r < 4; ++r) m = fmaxf(m, acc[fm][fn][r]);
      m = fmaxf(m, __shfl_xor(m, 16));
      m = fmaxf(m, __shfl_xor(m, 32));
      if (lane < 16) {
        const int col = wn * 64 + fn * 16 + l15;
        outf[(size_t)(blockIdx.x * 2 + wm) * 256 + col] = m + bias[col];
      }
    }
  } else {  // MODE 4: p2, BN=64, WN=1
#pragma unroll
    for (int fm = 0; fm < FM; ++fm)
#pragma unroll
      for (int fn = 0; fn < 4; ++fn) {
        const int col = fn * 16 + l15;
        const float bb = bias[col];
#pragma unroll
        for (int r = 0; r < 4; ++r) {
          const int row = mbase + wrow + fm * 16 + lkb * 4 + r;
          outf[(size_t)row * 64 + col] = leaky(acc[fm][fn][r] + bb);
        }
      }
  }
}

// gcon[s][o] = sum_{c<256} gmax[s][c] * W_p1[o][c]
__global__ void gcon_kernel(const float* __restrict__ gmax, const float* __restrict__ Wp1,
                            float* __restrict__ gcon) {
  __shared__ float g[256];
  int s = blockIdx.x, o = threadIdx.x;
  g[o] = gmax[(size_t)s * 256 + o];
  __syncthreads();
  float acc = 0.f;
  const float* wr = Wp1 + (size_t)o * 768;
#pragma unroll 8
  for (int c = 0; c < 256; ++c) acc += g[c] * wr[c];
  gcon[(size_t)s * 256 + o] = acc;
}

// out[s][o][v] = b3[o] + sum_{j<64} y2[n][j] * Wp3[o][j],  n = s*128+v
__global__ void p3_kernel(const float* __restrict__ y2, const float* __restrict__ W,
                          const float* __restrict__ b, float* __restrict__ out) {
  __shared__ float w0[64], w1[64];
  int t = threadIdx.x;
  if (t < 64) { w0[t] = W[t]; w1[t] = W[64 + t]; }
  __syncthreads();
  int n = blockIdx.x * 256 + t;
  const float* row = y2 + (size_t)n * 64;
  float a0 = b[0], a1 = b[1];
#pragma unroll
  for (int j = 0; j < 64; j += 4) {
    float4 v = *(const float4*)(row + j);
    a0 += v.x * w0[j] + v.y * w0[j + 1] + v.z * w0[j + 2] + v.w * w0[j + 3];
    a1 += v.x * w1[j] + v.y * w1[j + 1] + v.z * w1[j + 2] + v.w * w1[j + 3];
  }
  int s = n >> 7, vv = n & 127;
  out[((size_t)s * 2 + 0) * 128 + vv] = a0;
  out[((size_t)s * 2 + 1) * 128 + vv] = a1;
}

extern "C" void kernel_launch(void* const* d_in, const int* in_sizes, int n_in,
                              void* d_out, int out_size, void* d_ws, size_t ws_size,
                              hipStream_t stream) {
  const float* x        = (const float*)d_in[0];
  const int*   esrc     = (const int*)d_in[1];
  const int*   edst     = (const int*)d_in[2];
  const float* W_head   = (const float*)d_in[3];
  const float* b_head   = (const float*)d_in[4];
  const float* W_res[3] = {(const float*)d_in[5], (const float*)d_in[7], (const float*)d_in[9]};
  const float* b_res[3] = {(const float*)d_in[6], (const float*)d_in[8], (const float*)d_in[10]};
  const float* W_fusion = (const float*)d_in[11];
  const float* b_fusion = (const float*)d_in[12];
  const float* W_p1     = (const float*)d_in[13];
  const float* b_p1     = (const float*)d_in[14];
  const float* W_p2     = (const float*)d_in[15];
  const float* b_p2     = (const float*)d_in[16];
  const float* W_p3     = (const float*)d_in[17];
  const float* b_p3     = (const float*)d_in[18];
  float* outp = (float*)d_out;

  char* w = (char*)d_ws;
  size_t off = 0;
  auto alloc = [&](size_t bytes) { char* p = w + off; off += (bytes + 255) & ~(size_t)255; return p; };

  us* states_h = (us*)alloc((size_t)NN * 512 * 2);
  us* states_l = (us*)alloc((size_t)NN * 512 * 2);
  char* regionA = alloc((size_t)NN * 128 * 2 * 4);   // h0h|h0l|aggh|aggl, later y1h|y1l
  us* h0h  = (us*)regionA;
  us* h0l  = (us*)(regionA + (size_t)NN * 128 * 2);
  us* aggh = (us*)(regionA + (size_t)NN * 128 * 4);
  us* aggl = (us*)(regionA + (size_t)NN * 128 * 6);
  us* y1h  = (us*)regionA;
  us* y1l  = (us*)(regionA + (size_t)NN * 256 * 2);
  float* y2 = (float*)states_h;                       // states dead after p1

  float* gmax   = (float*)alloc(512 * 256 * 4);
  float* gcon   = (float*)alloc(512 * 256 * 4);
  float* rs_out = (float*)alloc((size_t)NN * 4);
  float* rs_in  = (float*)alloc((size_t)NN * 4);
  us* cWh[4]; us* cWl[4];
  for (int l = 0; l < 4; ++l) { cWh[l] = (us*)alloc(128 * 128 * 2); cWl[l] = (us*)alloc(128 * 128 * 2); }
  us* fWh  = (us*)alloc(256 * 512 * 2);
  us* fWl  = (us*)alloc(256 * 512 * 2);
  us* p1Wh = (us*)alloc(256 * 512 * 2);
  us* p1Wl = (us*)alloc(256 * 512 * 2);
  us* p2Wh = (us*)alloc(64 * 256 * 2);
  us* p2Wl = (us*)alloc(64 * 256 * 2);
  int* cnt_out = (int*)alloc((size_t)NN * 4);
  int* cnt_in  = (int*)alloc((size_t)NN * 4);
  int* cursor  = (int*)alloc((size_t)NN * 4);
  int* row_ptr = (int*)alloc(((size_t)NN + 1) * 4);
  int* csr     = (int*)alloc((size_t)NE * 4);

  zero_ints<<<(3 * NN + 255) / 256, 256, 0, stream>>>(cnt_out, 3 * NN);
  deg_count<<<NE / 256, 256, 0, stream>>>(esrc, edst, cnt_out, cnt_in);
  rs_kernel<<<NN / 256, 256, 0, stream>>>(cnt_out, cnt_in, rs_out, rs_in);
  scan_kernel<<<1, 1024, 0, stream>>>(cnt_in, row_ptr);
  csr_fill<<<NE / 256, 256, 0, stream>>>(esrc, edst, row_ptr, cursor, csr);

  transpose_x<<<1024, 256, 0, stream>>>(x, h0h, h0l);
  const float* cW[4] = {W_head, W_res[0], W_res[1], W_res[2]};
  for (int l = 0; l < 4; ++l)
    wsplit_t<<<64, 256, 0, stream>>>(cW[l], cWh[l], cWl[l], 128, 128, 128);
  wsplit<<<512, 256, 0, stream>>>(W_fusion, fWh, fWl, 256, 512, 512, 0);
  wsplit<<<512, 256, 0, stream>>>(W_p1, p1Wh, p1Wl, 256, 512, 768, 256);
  wsplit<<<64, 256, 0, stream>>>(W_p2, p2Wh, p2Wl, 64, 256, 256, 0);

  const float* cB[4] = {b_head, b_res[0], b_res[1], b_res[2]};
  // layer 1 (head)
  aggregate<<<NN / 4, 256, 0, stream>>>(h0h, h0l, 128, row_ptr, csr, rs_out, rs_in, aggh, aggl);
  mgemm8<128, 128, 4, 2, 0><<<256, 512, 0, stream>>>(aggh, aggl, 128, cWh[0], cWl[0], cB[0],
                                                     nullptr, states_h, states_l, 512, 0,
                                                     nullptr, nullptr, nullptr);
  // layers 2..4 (residual)
  for (int l = 1; l <= 3; ++l) {
    aggregate<<<NN / 4, 256, 0, stream>>>(states_h + (size_t)(l - 1) * 128,
                                          states_l + (size_t)(l - 1) * 128, 512,
                                          row_ptr, csr, rs_out, rs_in, aggh, aggl);
    mgemm8<128, 128, 4, 2, 1><<<256, 512, 0, stream>>>(aggh, aggl, 128, cWh[l], cWl[l], cB[l],
                                                       nullptr, states_h, states_l, 512, l * 128,
                                                       states_h, states_l, nullptr);
  }
  // fusion conv + per-slice max -> gmax
  mgemm8<512, 256, 2, 4, 2><<<256, 512, 0, stream>>>(states_h, states_l, 512, fWh, fWl, b_fusion,
                                                     gmax, nullptr, nullptr, 0, 0,
                                                     nullptr, nullptr, nullptr);
  gcon_kernel<<<512, 256, 0, stream>>>(gmax, W_p1, gcon);
  // p1 -> y1 planes
  mgemm8<512, 256, 2, 4, 3><<<256, 512, 0, stream>>>(states_h, states_l, 512, p1Wh, p1Wl, b_p1,
                                                     nullptr, y1h, y1l, 256, 0,
                                                     nullptr, nullptr, gcon);
  // p2 -> y2 fp32 [NN][64]
  mgemm8<256, 64, 8, 2, 4><<<256, 512, 0, stream>>>(y1h, y1l, 256, p2Wh, p2Wl, b_p2,
                                                    y2, nullptr, nullptr, 0, 0,
                                                    nullptr, nullptr, nullptr);
  // p3
  p3_kernel<<<NN / 256, 256, 0, stream>>>(y2, W_p3, b_p3, outp);
}

// Round 8
// 612.312 us; speedup vs baseline: 1.8513x; 1.0068x over previous
//
#include <hip/hip_runtime.h>

#define NN 65536
#define NE 524288
#define SLOPE 0.01f

typedef unsigned short us;
typedef __attribute__((ext_vector_type(8))) short short8;
typedef __attribute__((ext_vector_type(4))) float f32x4;

__device__ __forceinline__ float leaky(float v) { return v >= 0.f ? v : SLOPE * v; }
__device__ __forceinline__ float b2f(us u) { return __uint_as_float(((unsigned)u) << 16); }
__device__ __forceinline__ us f2b(float f) {
  unsigned u = __float_as_uint(f);
  u += 0x7fffu + ((u >> 16) & 1u);
  return (us)(u >> 16);
}
__device__ __forceinline__ void split2(float v, us& hi, us& lo) {
  hi = f2b(v);
  lo = f2b(v - b2f(hi));
}

__device__ __forceinline__ void gload16(const void* g, void* l) {
  __builtin_amdgcn_global_load_lds(
      (const __attribute__((address_space(1))) unsigned int*)g,
      (__attribute__((address_space(3))) unsigned int*)l, 16, 0, 0);
}

// ---------------- graph preprocessing ----------------
__global__ void zero_ints(int* __restrict__ p, int n) {
  int i = blockIdx.x * blockDim.x + threadIdx.x;
  if (i < n) p[i] = 0;
}

__global__ void deg_count(const int* __restrict__ src, const int* __restrict__ dst,
                          int* __restrict__ cout, int* __restrict__ cin) {
  int e = blockIdx.x * blockDim.x + threadIdx.x;
  if (e < NE) {
    atomicAdd(&cout[src[e]], 1);
    atomicAdd(&cin[dst[e]], 1);
  }
}

__global__ void rs_kernel(const int* __restrict__ cout, const int* __restrict__ cin,
                          float* __restrict__ rs_out, float* __restrict__ rs_in) {
  int n = blockIdx.x * blockDim.x + threadIdx.x;
  if (n < NN) {
    rs_out[n] = rsqrtf((float)(cout[n] > 0 ? cout[n] : 1));
    rs_in[n]  = rsqrtf((float)(cin[n]  > 0 ? cin[n]  : 1));
  }
}

__global__ __launch_bounds__(1024) void scan_kernel(const int* __restrict__ cnt,
                                                    int* __restrict__ row_ptr) {
  __shared__ int part[1024];
  int t = threadIdx.x;
  int base = t * 64;
  int s = 0;
  for (int i = 0; i < 64; ++i) s += cnt[base + i];
  part[t] = s;
  __syncthreads();
  for (int d = 1; d < 1024; d <<= 1) {
    int v = (t >= d) ? part[t - d] : 0;
    __syncthreads();
    part[t] += v;
    __syncthreads();
  }
  int run = part[t] - s;
  for (int i = 0; i < 64; ++i) { row_ptr[base + i] = run; run += cnt[base + i]; }
  if (t == 1023) row_ptr[NN] = run;
}

__global__ void csr_fill(const int* __restrict__ src, const int* __restrict__ dst,
                         const int* __restrict__ row_ptr, int* __restrict__ cursor,
                         int* __restrict__ csr) {
  int e = blockIdx.x * blockDim.x + threadIdx.x;
  if (e < NE) {
    int d = dst[e];
    int pos = atomicAdd(&cursor[d], 1);
    csr[row_ptr[d] + pos] = src[e];
  }
}

// x [512][128c][128v] -> h0 planes [65536 node][128 c] (hi/lo bf16)
__global__ __launch_bounds__(256) void transpose_x(const float* __restrict__ x,
                                                   us* __restrict__ h0h,
                                                   us* __restrict__ h0l) {
  __shared__ float tile[128][68];
  int s  = blockIdx.x >> 1;
  int vh = (blockIdx.x & 1) * 64;
  const float* xs = x + (size_t)s * 16384;
  int t = threadIdx.x;
  int v4 = t & 15, c0 = t >> 4;
  for (int p = 0; p < 8; ++p) {
    int c = c0 + p * 16;
    float4 val = *(const float4*)(xs + (size_t)c * 128 + vh + v4 * 4);
    *(float4*)&tile[c][v4 * 4] = val;
  }
  __syncthreads();
  int c4 = t & 31, v0 = t >> 5;
  for (int p = 0; p < 8; ++p) {
    int v = v0 + p * 8;
    float o[4];
    o[0] = tile[c4 * 4 + 0][v];
    o[1] = tile[c4 * 4 + 1][v];
    o[2] = tile[c4 * 4 + 2][v];
    o[3] = tile[c4 * 4 + 3][v];
    us hh[4], ll[4];
#pragma unroll
    for (int j = 0; j < 4; ++j) split2(o[j], hh[j], ll[j]);
    size_t off = (size_t)(s * 128 + vh + v) * 128 + c4 * 4;
    uint2 wh = make_uint2((unsigned)hh[0] | ((unsigned)hh[1] << 16),
                          (unsigned)hh[2] | ((unsigned)hh[3] << 16));
    uint2 wl = make_uint2((unsigned)ll[0] | ((unsigned)ll[1] << 16),
                          (unsigned)ll[2] | ((unsigned)ll[3] << 16));
    *(uint2*)(h0h + off) = wh;
    *(uint2*)(h0l + off) = wl;
  }
}

// weight split, fragment-major layout B'[n][k] (src row-major [n][ld], cols koff..)
__global__ void wsplit(const float* __restrict__ src, us* __restrict__ bh,
                       us* __restrict__ bl, int N, int K, int ld, int koff) {
  int idx = blockIdx.x * 256 + threadIdx.x;
  if (idx >= N * K) return;
  int n = idx / K, k = idx - n * K;
  float v = src[(size_t)n * ld + koff + k];
  us hi, lo; split2(v, hi, lo);
  bh[idx] = hi; bl[idx] = lo;
}

// weight split transposed: B'[n][k] = src[k*ld + n]   (conv weights W[k_in][n_out])
__global__ void wsplit_t(const float* __restrict__ src, us* __restrict__ bh,
                         us* __restrict__ bl, int N, int K, int ld) {
  int idx = blockIdx.x * 256 + threadIdx.x;
  if (idx >= N * K) return;
  int n = idx / K, k = idx - n * K;
  float v = src[(size_t)k * ld + n];
  us hi, lo; split2(v, hi, lo);
  bh[idx] = hi; bl[idx] = lo;
}

// wave-per-node aggregate: lanes 0-31 gather hi plane, 32-63 lo plane (8B/lane),
// 4-edge unroll for MLP; shfl_xor(32) merges; writes split agg planes.
__global__ __launch_bounds__(256) void aggregate(
    const us* __restrict__ hh, const us* __restrict__ hl, int lda,
    const int* __restrict__ row_ptr, const int* __restrict__ csr,
    const float* __restrict__ rs_out, const float* __restrict__ rs_in,
    us* __restrict__ aggh, us* __restrict__ aggl) {
  const int lane = threadIdx.x & 63;
  const int n = blockIdx.x * 4 + (threadIdx.x >> 6);
  const us* base = ((lane < 32) ? hh : hl) + (size_t)(lane & 31) * 4;
  const int b = row_ptr[n], e = row_ptr[n + 1];
  float a0 = 0.f, a1 = 0.f, a2 = 0.f, a3 = 0.f;
  int i = b;
  for (; i + 4 <= e; i += 4) {
    int s0 = csr[i], s1 = csr[i + 1], s2 = csr[i + 2], s3 = csr[i + 3];
    uint2 v0 = *(const uint2*)(base + (size_t)s0 * lda);
    uint2 v1 = *(const uint2*)(base + (size_t)s1 * lda);
    uint2 v2 = *(const uint2*)(base + (size_t)s2 * lda);
    uint2 v3 = *(const uint2*)(base + (size_t)s3 * lda);
    float w0 = rs_out[s0], w1 = rs_out[s1], w2 = rs_out[s2], w3 = rs_out[s3];
    a0 = fmaf(w0, __uint_as_float(v0.x << 16), a0);
    a1 = fmaf(w0, __uint_as_float(v0.x & 0xffff0000u), a1);
    a2 = fmaf(w0, __uint_as_float(v0.y << 16), a2);
    a3 = fmaf(w0, __uint_as_float(v0.y & 0xffff0000u), a3);
    a0 = fmaf(w1, __uint_as_float(v1.x << 16), a0);
    a1 = fmaf(w1, __uint_as_float(v1.x & 0xffff0000u), a1);
    a2 = fmaf(w1, __uint_as_float(v1.y << 16), a2);
    a3 = fmaf(w1, __uint_as_float(v1.y & 0xffff0000u), a3);
    a0 = fmaf(w2, __uint_as_float(v2.x << 16), a0);
    a1 = fmaf(w2, __uint_as_float(v2.x & 0xffff0000u), a1);
    a2 = fmaf(w2, __uint_as_float(v2.y << 16), a2);
    a3 = fmaf(w2, __uint_as_float(v2.y & 0xffff0000u), a3);
    a0 = fmaf(w3, __uint_as_float(v3.x << 16), a0);
    a1 = fmaf(w3, __uint_as_float(v3.x & 0xffff0000u), a1);
    a2 = fmaf(w3, __uint_as_float(v3.y << 16), a2);
    a3 = fmaf(w3, __uint_as_float(v3.y & 0xffff0000u), a3);
  }
  for (; i < e; ++i) {
    int s0 = csr[i];
    uint2 v0 = *(const uint2*)(base + (size_t)s0 * lda);
    float w0 = rs_out[s0];
    a0 = fmaf(w0, __uint_as_float(v0.x << 16), a0);
    a1 = fmaf(w0, __uint_as_float(v0.x & 0xffff0000u), a1);
    a2 = fmaf(w0, __uint_as_float(v0.y << 16), a2);
    a3 = fmaf(w0, __uint_as_float(v0.y & 0xffff0000u), a3);
  }
  a0 += __shfl_xor(a0, 32);
  a1 += __shfl_xor(a1, 32);
  a2 += __shfl_xor(a2, 32);
  a3 += __shfl_xor(a3, 32);
  const float ri = rs_in[n];
  a0 *= ri; a1 *= ri; a2 *= ri; a3 *= ri;
  us h[4], l[4];
  split2(a0, h[0], l[0]); split2(a1, h[1], l[1]);
  split2(a2, h[2], l[2]); split2(a3, h[3], l[3]);
  size_t o = (size_t)n * 128 + (size_t)(lane & 31) * 4;
  if (lane < 32) {
    uint2 wv = make_uint2((unsigned)h[0] | ((unsigned)h[1] << 16),
                          (unsigned)h[2] | ((unsigned)h[3] << 16));
    *(uint2*)(aggh + o) = wv;
  } else {
    uint2 wv = make_uint2((unsigned)l[0] | ((unsigned)l[1] << 16),
                          (unsigned)l[2] | ((unsigned)l[3] << 16));
    *(uint2*)(aggl + o) = wv;
  }
}

// ---------------- 256-row multi-phase split-bf16 MFMA GEMM (m201-style phases) ----------------
// BM=256, BN = full N. 512 threads = 8 waves (WM x WN). Wave tile (256/WM) x (BN/WN).
// Dbuf flat LDS; 4 planes staged linearly (chunk id == LDS slot -> DMA-safe).
// K-loop: waitL (counted vmcnt) -> s_barrier (publishes tile: each wave's own DMA landed
// at its waitL; barrier => ALL waves' landed) -> ktile.
// ktile: B-frags read ONCE into regs; then PH phases of
//   {ds_read A-subtile; s_barrier; lgkmcnt(0)+sched_barrier; setprio1; MFMA; setprio0; s_barrier}
// MODE 0: conv head  MODE 1: conv res (+prev)  MODE 2: fusion+max  MODE 3: p1 (+gcon)
// MODE 4: p2 (fp32 out, ld 64)
template<int KTOT, int BN, int WM, int PH, int MODE>
__global__ __launch_bounds__(512) void mgemm8(
    const us* __restrict__ Ah, const us* __restrict__ Al, int lda,
    const us* __restrict__ Bh, const us* __restrict__ Bl,
    const float* __restrict__ bias,
    float* __restrict__ outf, us* __restrict__ outh, us* __restrict__ outl,
    int ldo, int colOff,
    const us* __restrict__ prevh, const us* __restrict__ prevl,
    const float* __restrict__ gcon) {
  constexpr int WN  = 8 / WM;
  constexpr int FM  = 16 / WM;           // 16x16 fragments in M per wave
  constexpr int FMP = FM / PH;           // fm per phase
  constexpr int NT  = KTOT / 32;         // K-tiles (even everywhere)
  constexpr int LBN = (BN == 256) ? 8 : ((BN == 128) ? 7 : 6);
  constexpr int CHT = 2048 + BN * 8;     // 16B chunks per tile (Ah,Al,Bh,Bl)
  constexpr int LPT = CHT / 512;         // gloads per thread per tile

  __shared__ __align__(16) us L[2][CHT * 8];

  const int t = threadIdx.x;
  const int mbase = blockIdx.x * 256;

  // chunk map: id [0,1024)=Ah, [1024,2048)=Al, [2048,2048+BN*4)=Bh, rest Bl.
  const us* gp[LPT];
#pragma unroll
  for (int i = 0; i < LPT; ++i) {
    int id = i * 512 + t;
    if (id < 1024) {
      int row = id & 255, kb = id >> 8;
      gp[i] = Ah + (size_t)(mbase + row) * lda + kb * 8;
    } else if (id < 2048) {
      int c = id - 1024, row = c & 255, kb = c >> 8;
      gp[i] = Al + (size_t)(mbase + row) * lda + kb * 8;
    } else if (id < 2048 + BN * 4) {
      int c = id - 2048, row = c & (BN - 1), kb = c >> LBN;
      gp[i] = Bh + (size_t)row * KTOT + kb * 8;
    } else {
      int c = id - 2048 - BN * 4, row = c & (BN - 1), kb = c >> LBN;
      gp[i] = Bl + (size_t)row * KTOT + kb * 8;
    }
  }

  const int lane = t & 63, wvi = t >> 6;
  const int wm = wvi & (WM - 1), wn = wvi / WM;
  const int l15 = lane & 15, lkb = lane >> 4;
  const int wrow = wm * (256 / WM);

  f32x4 acc[FM][4];
#pragma unroll
  for (int i = 0; i < FM; ++i)
#pragma unroll
    for (int j = 0; j < 4; ++j)
#pragma unroll
      for (int e = 0; e < 4; ++e) acc[i][j][e] = 0.f;

  auto stage = [&](us* Lb, int k0) {
#pragma unroll
    for (int i = 0; i < LPT; ++i)
      gload16(gp[i] + k0, Lb + (size_t)(i * 512 + t) * 8);
  };
  auto waitL = [&]() {
    if constexpr (LPT == 8)      asm volatile("s_waitcnt vmcnt(8)" ::: "memory");
    else if constexpr (LPT == 6) asm volatile("s_waitcnt vmcnt(6)" ::: "memory");
    else                         asm volatile("s_waitcnt vmcnt(5)" ::: "memory");
    __builtin_amdgcn_sched_barrier(0);
  };
  auto wait0 = [&]() {
    asm volatile("s_waitcnt vmcnt(0)" ::: "memory");
    __builtin_amdgcn_sched_barrier(0);
  };
  auto bar = [&]() {
    __builtin_amdgcn_s_barrier();
    __builtin_amdgcn_sched_barrier(0);
  };
  // One K-tile: B-frags hoisted (read once), then PH phases of
  // {ds_read A; barrier; lgkmcnt(0); MFMA cluster; barrier}.
  auto ktile = [&](const us* Lb) {
    short8 bh[4], bl[4];
#pragma unroll
    for (int fn = 0; fn < 4; ++fn) {
      const int bcol = wn * 64 + fn * 16 + l15;
      bh[fn] = *(const short8*)(Lb + ((size_t)(2048 + lkb * BN + bcol)) * 8);
      bl[fn] = *(const short8*)(Lb + ((size_t)(2048 + BN * 4 + lkb * BN + bcol)) * 8);
    }
#pragma unroll
    for (int p = 0; p < PH; ++p) {
      short8 ah[FMP], al[FMP];
#pragma unroll
      for (int f = 0; f < FMP; ++f) {
        const int arow = wrow + (p * FMP + f) * 16 + l15;
        ah[f] = *(const short8*)(Lb + ((size_t)(lkb * 256 + arow)) * 8);
        al[f] = *(const short8*)(Lb + ((size_t)(1024 + lkb * 256 + arow)) * 8);
      }
      __builtin_amdgcn_s_barrier();
      asm volatile("s_waitcnt lgkmcnt(0)" ::: "memory");
      __builtin_amdgcn_sched_barrier(0);
      __builtin_amdgcn_s_setprio(1);
#pragma unroll
      for (int f = 0; f < FMP; ++f)
#pragma unroll
        for (int fn = 0; fn < 4; ++fn)
          acc[p * FMP + f][fn] =
              __builtin_amdgcn_mfma_f32_16x16x32_bf16(ah[f], bh[fn], acc[p * FMP + f][fn], 0, 0, 0);
#pragma unroll
      for (int f = 0; f < FMP; ++f)
#pragma unroll
        for (int fn = 0; fn < 4; ++fn)
          acc[p * FMP + f][fn] =
              __builtin_amdgcn_mfma_f32_16x16x32_bf16(al[f], bh[fn], acc[p * FMP + f][fn], 0, 0, 0);
#pragma unroll
      for (int f = 0; f < FMP; ++f)
#pragma unroll
        for (int fn = 0; fn < 4; ++fn)
          acc[p * FMP + f][fn] =
              __builtin_amdgcn_mfma_f32_16x16x32_bf16(ah[f], bl[fn], acc[p * FMP + f][fn], 0, 0, 0);
      __builtin_amdgcn_s_setprio(0);
      __builtin_amdgcn_s_barrier();
    }
  };

  stage(L[0], 0);
  if (NT > 1) stage(L[1], 32);
#pragma unroll 1
  for (int kt = 0; kt < NT; kt += 2) {
    waitL();
    bar();                       // publish L[0]: all waves' DMA landed
    ktile(L[0]);
    if (kt + 2 < NT) stage(L[0], (kt + 2) * 32);
    if (kt + 3 < NT) waitL(); else wait0();
    bar();                       // publish L[1]
    ktile(L[1]);
    if (kt + 3 < NT) stage(L[1], (kt + 3) * 32);
  }

  // C/D: col = lane&15, row = (lane>>4)*4 + reg
  if constexpr (MODE == 0 || MODE == 1 || MODE == 3) {
    const float* gc = (MODE == 3) ? (gcon + (size_t)(blockIdx.x * 2 + wm) * 256) : nullptr;
#pragma unroll
    for (int fm = 0; fm < FM; ++fm)
#pragma unroll
      for (int fn = 0; fn < 4; ++fn) {
        const int col = wn * 64 + fn * 16 + l15;
        float bb = bias[col];
        if constexpr (MODE == 3) bb += gc[col];
#pragma unroll
        for (int r = 0; r < 4; ++r) {
          const int row = mbase + wrow + fm * 16 + lkb * 4 + r;
          float v = leaky(acc[fm][fn][r] + bb);
          const size_t off = (size_t)row * ldo + colOff + col;
          if constexpr (MODE == 1) v += b2f(prevh[off - 128]) + b2f(prevl[off - 128]);
          us hi, lo; split2(v, hi, lo);
          outh[off] = hi;
          outl[off] = lo;
        }
      }
  } else if constexpr (MODE == 2) {
    // WM==2: wave wm covers rows of slice blockIdx.x*2+wm entirely; cols disjoint by wn.
#pragma unroll
    for (int fn = 0; fn < 4; ++fn) {
      float m = acc[0][fn][0];
#pragma unroll
      for (int fm = 0; fm < FM; ++fm)
#pragma unroll
        for (int r = 0; r < 4; ++r) m = fmaxf(m, acc[fm][fn][r]);
      m = fmaxf(m, __shfl_xor(m, 16));
      m = fmaxf(m, __shfl_xor(m, 32));
      if (lane < 16) {
        const int col = wn * 64 + fn * 16 + l15;
        outf[(size_t)(blockIdx.x * 2 + wm) * 256 + col] = m + bias[col];
      }
    }
  } else {  // MODE 4: p2, BN=64, WN=1
#pragma unroll
    for (int fm = 0; fm < FM; ++fm)
#pragma unroll
      for (int fn = 0; fn < 4; ++fn) {
        const int col = fn * 16 + l15;
        const float bb = bias[col];
#pragma unroll
        for (int r = 0; r < 4; ++r) {
          const int row = mbase + wrow + fm * 16 + lkb * 4 + r;
          outf[(size_t)row * 64 + col] = leaky(acc[fm][fn][r] + bb);
        }
      }
  }
}

// gcon[s][o] = sum_{c<256} gmax[s][c] * W_p1[o][c]
__global__ void gcon_kernel(const float* __restrict__ gmax, const float* __restrict__ Wp1,
                            float* __restrict__ gcon) {
  __shared__ float g[256];
  int s = blockIdx.x, o = threadIdx.x;
  g[o] = gmax[(size_t)s * 256 + o];
  __syncthreads();
  float acc = 0.f;
  const float* wr = Wp1 + (size_t)o * 768;
#pragma unroll 8
  for (int c = 0; c < 256; ++c) acc += g[c] * wr[c];
  gcon[(size_t)s * 256 + o] = acc;
}

// out[s][o][v] = b3[o] + sum_{j<64} y2[n][j] * Wp3[o][j],  n = s*128+v
__global__ void p3_kernel(const float* __restrict__ y2, const float* __restrict__ W,
                          const float* __restrict__ b, float* __restrict__ out) {
  __shared__ float w0[64], w1[64];
  int t = threadIdx.x;
  if (t < 64) { w0[t] = W[t]; w1[t] = W[64 + t]; }
  __syncthreads();
  int n = blockIdx.x * 256 + t;
  const float* row = y2 + (size_t)n * 64;
  float a0 = b[0], a1 = b[1];
#pragma unroll
  for (int j = 0; j < 64; j += 4) {
    float4 v = *(const float4*)(row + j);
    a0 += v.x * w0[j] + v.y * w0[j + 1] + v.z * w0[j + 2] + v.w * w0[j + 3];
    a1 += v.x * w1[j] + v.y * w1[j + 1] + v.z * w1[j + 2] + v.w * w1[j + 3];
  }
  int s = n >> 7, vv = n & 127;
  out[((size_t)s * 2 + 0) * 128 + vv] = a0;
  out[((size_t)s * 2 + 1) * 128 + vv] = a1;
}

extern "C" void kernel_launch(void* const* d_in, const int* in_sizes, int n_in,
                              void* d_out, int out_size, void* d_ws, size_t ws_size,
                              hipStream_t stream) {
  const float* x        = (const float*)d_in[0];
  const int*   esrc     = (const int*)d_in[1];
  const int*   edst     = (const int*)d_in[2];
  const float* W_head   = (const float*)d_in[3];
  const float* b_head   = (const float*)d_in[4];
  const float* W_res[3] = {(const float*)d_in[5], (const float*)d_in[7], (const float*)d_in[9]};
  const float* b_res[3] = {(const float*)d_in[6], (const float*)d_in[8], (const float*)d_in[10]};
  const float* W_fusion = (const float*)d_in[11];
  const float* b_fusion = (const float*)d_in[12];
  const float* W_p1     = (const float*)d_in[13];
  const float* b_p1     = (const float*)d_in[14];
  const float* W_p2     = (const float*)d_in[15];
  const float* b_p2     = (const float*)d_in[16];
  const float* W_p3     = (const float*)d_in[17];
  const float* b_p3     = (const float*)d_in[18];
  float* outp = (float*)d_out;

  char* w = (char*)d_ws;
  size_t off = 0;
  auto alloc = [&](size_t bytes) { char* p = w + off; off += (bytes + 255) & ~(size_t)255; return p; };

  us* states_h = (us*)alloc((size_t)NN * 512 * 2);
  us* states_l = (us*)alloc((size_t)NN * 512 * 2);
  char* regionA = alloc((size_t)NN * 128 * 2 * 4);   // h0h|h0l|aggh|aggl, later y1h|y1l
  us* h0h  = (us*)regionA;
  us* h0l  = (us*)(regionA + (size_t)NN * 128 * 2);
  us* aggh = (us*)(regionA + (size_t)NN * 128 * 4);
  us* aggl = (us*)(regionA + (size_t)NN * 128 * 6);
  us* y1h  = (us*)regionA;
  us* y1l  = (us*)(regionA + (size_t)NN * 256 * 2);
  float* y2 = (float*)states_h;                       // states dead after p1

  float* gmax   = (float*)alloc(512 * 256 * 4);
  float* gcon   = (float*)alloc(512 * 256 * 4);
  float* rs_out = (float*)alloc((size_t)NN * 4);
  float* rs_in  = (float*)alloc((size_t)NN * 4);
  us* cWh[4]; us* cWl[4];
  for (int l = 0; l < 4; ++l) { cWh[l] = (us*)alloc(128 * 128 * 2); cWl[l] = (us*)alloc(128 * 128 * 2); }
  us* fWh  = (us*)alloc(256 * 512 * 2);
  us* fWl  = (us*)alloc(256 * 512 * 2);
  us* p1Wh = (us*)alloc(256 * 512 * 2);
  us* p1Wl = (us*)alloc(256 * 512 * 2);
  us* p2Wh = (us*)alloc(64 * 256 * 2);
  us* p2Wl = (us*)alloc(64 * 256 * 2);
  int* cnt_out = (int*)alloc((size_t)NN * 4);
  int* cnt_in  = (int*)alloc((size_t)NN * 4);
  int* cursor  = (int*)alloc((size_t)NN * 4);
  int* row_ptr = (int*)alloc(((size_t)NN + 1) * 4);
  int* csr     = (int*)alloc((size_t)NE * 4);

  zero_ints<<<(3 * NN + 255) / 256, 256, 0, stream>>>(cnt_out, 3 * NN);
  deg_count<<<NE / 256, 256, 0, stream>>>(esrc, edst, cnt_out, cnt_in);
  rs_kernel<<<NN / 256, 256, 0, stream>>>(cnt_out, cnt_in, rs_out, rs_in);
  scan_kernel<<<1, 1024, 0, stream>>>(cnt_in, row_ptr);
  csr_fill<<<NE / 256, 256, 0, stream>>>(esrc, edst, row_ptr, cursor, csr);

  transpose_x<<<1024, 256, 0, stream>>>(x, h0h, h0l);
  const float* cW[4] = {W_head, W_res[0], W_res[1], W_res[2]};
  for (int l = 0; l < 4; ++l)
    wsplit_t<<<64, 256, 0, stream>>>(cW[l], cWh[l], cWl[l], 128, 128, 128);
  wsplit<<<512, 256, 0, stream>>>(W_fusion, fWh, fWl, 256, 512, 512, 0);
  wsplit<<<512, 256, 0, stream>>>(W_p1, p1Wh, p1Wl, 256, 512, 768, 256);
  wsplit<<<64, 256, 0, stream>>>(W_p2, p2Wh, p2Wl, 64, 256, 256, 0);

  const float* cB[4] = {b_head, b_res[0], b_res[1], b_res[2]};
  // layer 1 (head)
  aggregate<<<NN / 4, 256, 0, stream>>>(h0h, h0l, 128, row_ptr, csr, rs_out, rs_in, aggh, aggl);
  mgemm8<128, 128, 4, 2, 0><<<256, 512, 0, stream>>>(aggh, aggl, 128, cWh[0], cWl[0], cB[0],
                                                     nullptr, states_h, states_l, 512, 0,
                                                     nullptr, nullptr, nullptr);
  // layers 2..4 (residual)
  for (int l = 1; l <= 3; ++l) {
    aggregate<<<NN / 4, 256, 0, stream>>>(states_h + (size_t)(l - 1) * 128,
                                          states_l + (size_t)(l - 1) * 128, 512,
                                          row_ptr, csr, rs_out, rs_in, aggh, aggl);
    mgemm8<128, 128, 4, 2, 1><<<256, 512, 0, stream>>>(aggh, aggl, 128, cWh[l], cWl[l], cB[l],
                                                       nullptr, states_h, states_l, 512, l * 128,
                                                       states_h, states_l, nullptr);
  }
  // fusion conv + per-slice max -> gmax
  mgemm8<512, 256, 2, 4, 2><<<256, 512, 0, stream>>>(states_h, states_l, 512, fWh, fWl, b_fusion,
                                                     gmax, nullptr, nullptr, 0, 0,
                                                     nullptr, nullptr, nullptr);
  gcon_kernel<<<512, 256, 0, stream>>>(gmax, W_p1, gcon);
  // p1 -> y1 planes
  mgemm8<512, 256, 2, 4, 3><<<256, 512, 0, stream>>>(states_h, states_l, 512, p1Wh, p1Wl, b_p1,
                                                     nullptr, y1h, y1l, 256, 0,
                                                     nullptr, nullptr, gcon);
  // p2 -> y2 fp32 [NN][64]
  mgemm8<256, 64, 8, 2, 4><<<256, 512, 0, stream>>>(y1h, y1l, 256, p2Wh, p2Wl, b_p2,
                                                    y2, nullptr, nullptr, 0, 0,
                                                    nullptr, nullptr, nullptr);
  // p3
  p3_kernel<<<NN / 256, 256, 0, stream>>>(y2, W_p3, b_p3, outp);
}

// Round 9
// 607.542 us; speedup vs baseline: 1.8658x; 1.0079x over previous
//
#include <hip/hip_runtime.h>

#define NN 65536
#define NE 524288
#define SLOPE 0.01f

typedef unsigned short us;
typedef __attribute__((ext_vector_type(8))) short short8;
typedef __attribute__((ext_vector_type(4))) float f32x4;

__device__ __forceinline__ float leaky(float v) { return v >= 0.f ? v : SLOPE * v; }
__device__ __forceinline__ float b2f(us u) { return __uint_as_float(((unsigned)u) << 16); }
__device__ __forceinline__ us f2b(float f) {
  unsigned u = __float_as_uint(f);
  u += 0x7fffu + ((u >> 16) & 1u);
  return (us)(u >> 16);
}
__device__ __forceinline__ void split2(float v, us& hi, us& lo) {
  hi = f2b(v);
  lo = f2b(v - b2f(hi));
}

__device__ __forceinline__ void gload16(const void* g, void* l) {
  __builtin_amdgcn_global_load_lds(
      (const __attribute__((address_space(1))) unsigned int*)g,
      (__attribute__((address_space(3))) unsigned int*)l, 16, 0, 0);
}

// ---------------- graph preprocessing ----------------
__global__ void zero_ints(int* __restrict__ p, int n) {
  int i = blockIdx.x * blockDim.x + threadIdx.x;
  if (i < n) p[i] = 0;
}

__global__ void deg_count(const int* __restrict__ src, const int* __restrict__ dst,
                          int* __restrict__ cout, int* __restrict__ cin) {
  int e = blockIdx.x * blockDim.x + threadIdx.x;
  if (e < NE) {
    atomicAdd(&cout[src[e]], 1);
    atomicAdd(&cin[dst[e]], 1);
  }
}

__global__ void rs_kernel(const int* __restrict__ cout, const int* __restrict__ cin,
                          float* __restrict__ rs_out, float* __restrict__ rs_in) {
  int n = blockIdx.x * blockDim.x + threadIdx.x;
  if (n < NN) {
    rs_out[n] = rsqrtf((float)(cout[n] > 0 ? cout[n] : 1));
    rs_in[n]  = rsqrtf((float)(cin[n]  > 0 ? cin[n]  : 1));
  }
}

__global__ __launch_bounds__(1024) void scan_kernel(const int* __restrict__ cnt,
                                                    int* __restrict__ row_ptr) {
  __shared__ int part[1024];
  int t = threadIdx.x;
  int base = t * 64;
  int s = 0;
  for (int i = 0; i < 64; ++i) s += cnt[base + i];
  part[t] = s;
  __syncthreads();
  for (int d = 1; d < 1024; d <<= 1) {
    int v = (t >= d) ? part[t - d] : 0;
    __syncthreads();
    part[t] += v;
    __syncthreads();
  }
  int run = part[t] - s;
  for (int i = 0; i < 64; ++i) { row_ptr[base + i] = run; run += cnt[base + i]; }
  if (t == 1023) row_ptr[NN] = run;
}

__global__ void csr_fill(const int* __restrict__ src, const int* __restrict__ dst,
                         const int* __restrict__ row_ptr, int* __restrict__ cursor,
                         int* __restrict__ csr) {
  int e = blockIdx.x * blockDim.x + threadIdx.x;
  if (e < NE) {
    int d = dst[e];
    int pos = atomicAdd(&cursor[d], 1);
    csr[row_ptr[d] + pos] = src[e];
  }
}

// x [512][128c][128v] -> h0 planes [65536 node][128 c] (hi/lo bf16)
__global__ __launch_bounds__(256) void transpose_x(const float* __restrict__ x,
                                                   us* __restrict__ h0h,
                                                   us* __restrict__ h0l) {
  __shared__ float tile[128][68];
  int s  = blockIdx.x >> 1;
  int vh = (blockIdx.x & 1) * 64;
  const float* xs = x + (size_t)s * 16384;
  int t = threadIdx.x;
  int v4 = t & 15, c0 = t >> 4;
  for (int p = 0; p < 8; ++p) {
    int c = c0 + p * 16;
    float4 val = *(const float4*)(xs + (size_t)c * 128 + vh + v4 * 4);
    *(float4*)&tile[c][v4 * 4] = val;
  }
  __syncthreads();
  int c4 = t & 31, v0 = t >> 5;
  for (int p = 0; p < 8; ++p) {
    int v = v0 + p * 8;
    float o[4];
    o[0] = tile[c4 * 4 + 0][v];
    o[1] = tile[c4 * 4 + 1][v];
    o[2] = tile[c4 * 4 + 2][v];
    o[3] = tile[c4 * 4 + 3][v];
    us hh[4], ll[4];
#pragma unroll
    for (int j = 0; j < 4; ++j) split2(o[j], hh[j], ll[j]);
    size_t off = (size_t)(s * 128 + vh + v) * 128 + c4 * 4;
    uint2 wh = make_uint2((unsigned)hh[0] | ((unsigned)hh[1] << 16),
                          (unsigned)hh[2] | ((unsigned)hh[3] << 16));
    uint2 wl = make_uint2((unsigned)ll[0] | ((unsigned)ll[1] << 16),
                          (unsigned)ll[2] | ((unsigned)ll[3] << 16));
    *(uint2*)(h0h + off) = wh;
    *(uint2*)(h0l + off) = wl;
  }
}

// weight split, fragment-major layout B'[n][k] (src row-major [n][ld], cols koff..)
__global__ void wsplit(const float* __restrict__ src, us* __restrict__ bh,
                       us* __restrict__ bl, int N, int K, int ld, int koff) {
  int idx = blockIdx.x * 256 + threadIdx.x;
  if (idx >= N * K) return;
  int n = idx / K, k = idx - n * K;
  float v = src[(size_t)n * ld + koff + k];
  us hi, lo; split2(v, hi, lo);
  bh[idx] = hi; bl[idx] = lo;
}

// weight split transposed: B'[n][k] = src[k*ld + n]   (conv weights W[k_in][n_out])
__global__ void wsplit_t(const float* __restrict__ src, us* __restrict__ bh,
                         us* __restrict__ bl, int N, int K, int ld) {
  int idx = blockIdx.x * 256 + threadIdx.x;
  if (idx >= N * K) return;
  int n = idx / K, k = idx - n * K;
  float v = src[(size_t)k * ld + n];
  us hi, lo; split2(v, hi, lo);
  bh[idx] = hi; bl[idx] = lo;
}

// wave-per-node aggregate: lanes 0-31 gather hi plane, 32-63 lo plane (8B/lane),
// 4-edge unroll for MLP; shfl_xor(32) merges; writes split agg planes.
__global__ __launch_bounds__(256) void aggregate(
    const us* __restrict__ hh, const us* __restrict__ hl, int lda,
    const int* __restrict__ row_ptr, const int* __restrict__ csr,
    const float* __restrict__ rs_out, const float* __restrict__ rs_in,
    us* __restrict__ aggh, us* __restrict__ aggl) {
  const int lane = threadIdx.x & 63;
  const int n = blockIdx.x * 4 + (threadIdx.x >> 6);
  const us* base = ((lane < 32) ? hh : hl) + (size_t)(lane & 31) * 4;
  const int b = row_ptr[n], e = row_ptr[n + 1];
  float a0 = 0.f, a1 = 0.f, a2 = 0.f, a3 = 0.f;
  int i = b;
  for (; i + 4 <= e; i += 4) {
    int s0 = csr[i], s1 = csr[i + 1], s2 = csr[i + 2], s3 = csr[i + 3];
    uint2 v0 = *(const uint2*)(base + (size_t)s0 * lda);
    uint2 v1 = *(const uint2*)(base + (size_t)s1 * lda);
    uint2 v2 = *(const uint2*)(base + (size_t)s2 * lda);
    uint2 v3 = *(const uint2*)(base + (size_t)s3 * lda);
    float w0 = rs_out[s0], w1 = rs_out[s1], w2 = rs_out[s2], w3 = rs_out[s3];
    a0 = fmaf(w0, __uint_as_float(v0.x << 16), a0);
    a1 = fmaf(w0, __uint_as_float(v0.x & 0xffff0000u), a1);
    a2 = fmaf(w0, __uint_as_float(v0.y << 16), a2);
    a3 = fmaf(w0, __uint_as_float(v0.y & 0xffff0000u), a3);
    a0 = fmaf(w1, __uint_as_float(v1.x << 16), a0);
    a1 = fmaf(w1, __uint_as_float(v1.x & 0xffff0000u), a1);
    a2 = fmaf(w1, __uint_as_float(v1.y << 16), a2);
    a3 = fmaf(w1, __uint_as_float(v1.y & 0xffff0000u), a3);
    a0 = fmaf(w2, __uint_as_float(v2.x << 16), a0);
    a1 = fmaf(w2, __uint_as_float(v2.x & 0xffff0000u), a1);
    a2 = fmaf(w2, __uint_as_float(v2.y << 16), a2);
    a3 = fmaf(w2, __uint_as_float(v2.y & 0xffff0000u), a3);
    a0 = fmaf(w3, __uint_as_float(v3.x << 16), a0);
    a1 = fmaf(w3, __uint_as_float(v3.x & 0xffff0000u), a1);
    a2 = fmaf(w3, __uint_as_float(v3.y << 16), a2);
    a3 = fmaf(w3, __uint_as_float(v3.y & 0xffff0000u), a3);
  }
  for (; i < e; ++i) {
    int s0 = csr[i];
    uint2 v0 = *(const uint2*)(base + (size_t)s0 * lda);
    float w0 = rs_out[s0];
    a0 = fmaf(w0, __uint_as_float(v0.x << 16), a0);
    a1 = fmaf(w0, __uint_as_float(v0.x & 0xffff0000u), a1);
    a2 = fmaf(w0, __uint_as_float(v0.y << 16), a2);
    a3 = fmaf(w0, __uint_as_float(v0.y & 0xffff0000u), a3);
  }
  a0 += __shfl_xor(a0, 32);
  a1 += __shfl_xor(a1, 32);
  a2 += __shfl_xor(a2, 32);
  a3 += __shfl_xor(a3, 32);
  const float ri = rs_in[n];
  a0 *= ri; a1 *= ri; a2 *= ri; a3 *= ri;
  us h[4], l[4];
  split2(a0, h[0], l[0]); split2(a1, h[1], l[1]);
  split2(a2, h[2], l[2]); split2(a3, h[3], l[3]);
  size_t o = (size_t)n * 128 + (size_t)(lane & 31) * 4;
  if (lane < 32) {
    uint2 wv = make_uint2((unsigned)h[0] | ((unsigned)h[1] << 16),
                          (unsigned)h[2] | ((unsigned)h[3] << 16));
    *(uint2*)(aggh + o) = wv;
  } else {
    uint2 wv = make_uint2((unsigned)l[0] | ((unsigned)l[1] << 16),
                          (unsigned)l[2] | ((unsigned)l[3] << 16));
    *(uint2*)(aggl + o) = wv;
  }
}

// ---------------- 256-row free-run split-bf16 MFMA GEMM (minimal barriers) ----------------
// BM=256, BN = full N. 512 threads = 8 waves (WM x WN). Dbuf flat LDS, planes staged
// linearly (chunk id == LDS slot -> DMA-safe). Per K-tile only TWO runtime barriers:
//   waitL(counted vmcnt) -> bar(publish) -> ktile free-run (sched_barrier-fenced phases,
//   compiler-managed lgkmcnt, waves slip for ds_read/MFMA overlap) -> bar(readers done)
//   -> burst restage.
// MODE 0: conv head  MODE 1: conv res (+prev)  MODE 2: fusion+max  MODE 3: p1 (+gcon)
// MODE 4: p2 (fp32 out, ld 64)
template<int KTOT, int BN, int WM, int PH, int MODE>
__global__ __launch_bounds__(512) void mgemm8(
    const us* __restrict__ Ah, const us* __restrict__ Al, int lda,
    const us* __restrict__ Bh, const us* __restrict__ Bl,
    const float* __restrict__ bias,
    float* __restrict__ outf, us* __restrict__ outh, us* __restrict__ outl,
    int ldo, int colOff,
    const us* __restrict__ prevh, const us* __restrict__ prevl,
    const float* __restrict__ gcon) {
  constexpr int WN  = 8 / WM;
  constexpr int FM  = 16 / WM;           // 16x16 fragments in M per wave
  constexpr int FMP = FM / PH;           // fm per phase
  constexpr int NT  = KTOT / 32;         // K-tiles (even everywhere)
  constexpr int LBN = (BN == 256) ? 8 : ((BN == 128) ? 7 : 6);
  constexpr int CHT = 2048 + BN * 8;     // 16B chunks per tile (Ah,Al,Bh,Bl)
  constexpr int LPT = CHT / 512;         // gloads per thread per tile

  __shared__ __align__(16) us L[2][CHT * 8];

  const int t = threadIdx.x;
  const int mbase = blockIdx.x * 256;

  // chunk map: id [0,1024)=Ah, [1024,2048)=Al, [2048,2048+BN*4)=Bh, rest Bl.
  const us* gp[LPT];
#pragma unroll
  for (int i = 0; i < LPT; ++i) {
    int id = i * 512 + t;
    if (id < 1024) {
      int row = id & 255, kb = id >> 8;
      gp[i] = Ah + (size_t)(mbase + row) * lda + kb * 8;
    } else if (id < 2048) {
      int c = id - 1024, row = c & 255, kb = c >> 8;
      gp[i] = Al + (size_t)(mbase + row) * lda + kb * 8;
    } else if (id < 2048 + BN * 4) {
      int c = id - 2048, row = c & (BN - 1), kb = c >> LBN;
      gp[i] = Bh + (size_t)row * KTOT + kb * 8;
    } else {
      int c = id - 2048 - BN * 4, row = c & (BN - 1), kb = c >> LBN;
      gp[i] = Bl + (size_t)row * KTOT + kb * 8;
    }
  }

  const int lane = t & 63, wvi = t >> 6;
  const int wm = wvi & (WM - 1), wn = wvi / WM;
  const int l15 = lane & 15, lkb = lane >> 4;
  const int wrow = wm * (256 / WM);

  f32x4 acc[FM][4];
#pragma unroll
  for (int i = 0; i < FM; ++i)
#pragma unroll
    for (int j = 0; j < 4; ++j)
#pragma unroll
      for (int e = 0; e < 4; ++e) acc[i][j][e] = 0.f;

  auto stage = [&](us* Lb, int k0) {
#pragma unroll
    for (int i = 0; i < LPT; ++i)
      gload16(gp[i] + k0, Lb + (size_t)(i * 512 + t) * 8);
  };
  auto waitL = [&]() {
    if constexpr (LPT == 8)      asm volatile("s_waitcnt vmcnt(8)" ::: "memory");
    else if constexpr (LPT == 6) asm volatile("s_waitcnt vmcnt(6)" ::: "memory");
    else                         asm volatile("s_waitcnt vmcnt(5)" ::: "memory");
    __builtin_amdgcn_sched_barrier(0);
  };
  auto wait0 = [&]() {
    asm volatile("s_waitcnt vmcnt(0)" ::: "memory");
    __builtin_amdgcn_sched_barrier(0);
  };
  auto bar = [&]() {
    __builtin_amdgcn_s_barrier();
    __builtin_amdgcn_sched_barrier(0);
  };
  // Free-run K-tile: B-frags hoisted (read once); phases fenced only by
  // sched_barrier(0) (compile-time, caps reg pressure) — no runtime barriers inside.
  auto ktile = [&](const us* Lb) {
    short8 bh[4], bl[4];
#pragma unroll
    for (int fn = 0; fn < 4; ++fn) {
      const int bcol = wn * 64 + fn * 16 + l15;
      bh[fn] = *(const short8*)(Lb + ((size_t)(2048 + lkb * BN + bcol)) * 8);
      bl[fn] = *(const short8*)(Lb + ((size_t)(2048 + BN * 4 + lkb * BN + bcol)) * 8);
    }
#pragma unroll
    for (int p = 0; p < PH; ++p) {
      short8 ah[FMP], al[FMP];
#pragma unroll
      for (int f = 0; f < FMP; ++f) {
        const int arow = wrow + (p * FMP + f) * 16 + l15;
        ah[f] = *(const short8*)(Lb + ((size_t)(lkb * 256 + arow)) * 8);
        al[f] = *(const short8*)(Lb + ((size_t)(1024 + lkb * 256 + arow)) * 8);
      }
      __builtin_amdgcn_s_setprio(1);
#pragma unroll
      for (int f = 0; f < FMP; ++f)
#pragma unroll
        for (int fn = 0; fn < 4; ++fn)
          acc[p * FMP + f][fn] =
              __builtin_amdgcn_mfma_f32_16x16x32_bf16(ah[f], bh[fn], acc[p * FMP + f][fn], 0, 0, 0);
#pragma unroll
      for (int f = 0; f < FMP; ++f)
#pragma unroll
        for (int fn = 0; fn < 4; ++fn)
          acc[p * FMP + f][fn] =
              __builtin_amdgcn_mfma_f32_16x16x32_bf16(al[f], bh[fn], acc[p * FMP + f][fn], 0, 0, 0);
#pragma unroll
      for (int f = 0; f < FMP; ++f)
#pragma unroll
        for (int fn = 0; fn < 4; ++fn)
          acc[p * FMP + f][fn] =
              __builtin_amdgcn_mfma_f32_16x16x32_bf16(ah[f], bl[fn], acc[p * FMP + f][fn], 0, 0, 0);
      __builtin_amdgcn_s_setprio(0);
      __builtin_amdgcn_sched_barrier(0);
    }
  };

  stage(L[0], 0);
  if (NT > 1) stage(L[1], 32);
#pragma unroll 1
  for (int kt = 0; kt < NT; kt += 2) {
    waitL();
    bar();                       // publish L0: all waves' DMA landed
    ktile(L[0]);
    bar();                       // all waves done reading L0
    if (kt + 2 < NT) stage(L[0], (kt + 2) * 32);
    if (kt + 3 < NT) waitL(); else wait0();
    bar();                       // publish L1
    ktile(L[1]);
    bar();                       // all waves done reading L1
    if (kt + 3 < NT) stage(L[1], (kt + 3) * 32);
  }

  // C/D: col = lane&15, row = (lane>>4)*4 + reg
  if constexpr (MODE == 0 || MODE == 1 || MODE == 3) {
    const float* gc = (MODE == 3) ? (gcon + (size_t)(blockIdx.x * 2 + wm) * 256) : nullptr;
#pragma unroll
    for (int fm = 0; fm < FM; ++fm)
#pragma unroll
      for (int fn = 0; fn < 4; ++fn) {
        const int col = wn * 64 + fn * 16 + l15;
        float bb = bias[col];
        if constexpr (MODE == 3) bb += gc[col];
#pragma unroll
        for (int r = 0; r < 4; ++r) {
          const int row = mbase + wrow + fm * 16 + lkb * 4 + r;
          float v = leaky(acc[fm][fn][r] + bb);
          const size_t off = (size_t)row * ldo + colOff + col;
          if constexpr (MODE == 1) v += b2f(prevh[off - 128]) + b2f(prevl[off - 128]);
          us hi, lo; split2(v, hi, lo);
          outh[off] = hi;
          outl[off] = lo;
        }
      }
  } else if constexpr (MODE == 2) {
    // WM==2: wave wm covers rows of slice blockIdx.x*2+wm entirely; cols disjoint by wn.
#pragma unroll
    for (int fn = 0; fn < 4; ++fn) {
      float m = acc[0][fn][0];
#pragma unroll
      for (int fm = 0; fm < FM; ++fm)
#pragma unroll
        for (int r = 0; r < 4; ++r) m = fmaxf(m, acc[fm][fn][r]);
      m = fmaxf(m, __shfl_xor(m, 16));
      m = fmaxf(m, __shfl_xor(m, 32));
      if (lane < 16) {
        const int col = wn * 64 + fn * 16 + l15;
        outf[(size_t)(blockIdx.x * 2 + wm) * 256 + col] = m + bias[col];
      }
    }
  } else {  // MODE 4: p2, BN=64, WN=1
#pragma unroll
    for (int fm = 0; fm < FM; ++fm)
#pragma unroll
      for (int fn = 0; fn < 4; ++fn) {
        const int col = fn * 16 + l15;
        const float bb = bias[col];
#pragma unroll
        for (int r = 0; r < 4; ++r) {
          const int row = mbase + wrow + fm * 16 + lkb * 4 + r;
          outf[(size_t)row * 64 + col] = leaky(acc[fm][fn][r] + bb);
        }
      }
  }
}

// gcon[s][o] = sum_{c<256} gmax[s][c] * W_p1[o][c]
__global__ void gcon_kernel(const float* __restrict__ gmax, const float* __restrict__ Wp1,
                            float* __restrict__ gcon) {
  __shared__ float g[256];
  int s = blockIdx.x, o = threadIdx.x;
  g[o] = gmax[(size_t)s * 256 + o];
  __syncthreads();
  float acc = 0.f;
  const float* wr = Wp1 + (size_t)o * 768;
#pragma unroll 8
  for (int c = 0; c < 256; ++c) acc += g[c] * wr[c];
  gcon[(size_t)s * 256 + o] = acc;
}

// out[s][o][v] = b3[o] + sum_{j<64} y2[n][j] * Wp3[o][j],  n = s*128+v
__global__ void p3_kernel(const float* __restrict__ y2, const float* __restrict__ W,
                          const float* __restrict__ b, float* __restrict__ out) {
  __shared__ float w0[64], w1[64];
  int t = threadIdx.x;
  if (t < 64) { w0[t] = W[t]; w1[t] = W[64 + t]; }
  __syncthreads();
  int n = blockIdx.x * 256 + t;
  const float* row = y2 + (size_t)n * 64;
  float a0 = b[0], a1 = b[1];
#pragma unroll
  for (int j = 0; j < 64; j += 4) {
    float4 v = *(const float4*)(row + j);
    a0 += v.x * w0[j] + v.y * w0[j + 1] + v.z * w0[j + 2] + v.w * w0[j + 3];
    a1 += v.x * w1[j] + v.y * w1[j + 1] + v.z * w1[j + 2] + v.w * w1[j + 3];
  }
  int s = n >> 7, vv = n & 127;
  out[((size_t)s * 2 + 0) * 128 + vv] = a0;
  out[((size_t)s * 2 + 1) * 128 + vv] = a1;
}

extern "C" void kernel_launch(void* const* d_in, const int* in_sizes, int n_in,
                              void* d_out, int out_size, void* d_ws, size_t ws_size,
                              hipStream_t stream) {
  const float* x        = (const float*)d_in[0];
  const int*   esrc     = (const int*)d_in[1];
  const int*   edst     = (const int*)d_in[2];
  const float* W_head   = (const float*)d_in[3];
  const float* b_head   = (const float*)d_in[4];
  const float* W_res[3] = {(const float*)d_in[5], (const float*)d_in[7], (const float*)d_in[9]};
  const float* b_res[3] = {(const float*)d_in[6], (const float*)d_in[8], (const float*)d_in[10]};
  const float* W_fusion = (const float*)d_in[11];
  const float* b_fusion = (const float*)d_in[12];
  const float* W_p1     = (const float*)d_in[13];
  const float* b_p1     = (const float*)d_in[14];
  const float* W_p2     = (const float*)d_in[15];
  const float* b_p2     = (const float*)d_in[16];
  const float* W_p3     = (const float*)d_in[17];
  const float* b_p3     = (const float*)d_in[18];
  float* outp = (float*)d_out;

  char* w = (char*)d_ws;
  size_t off = 0;
  auto alloc = [&](size_t bytes) { char* p = w + off; off += (bytes + 255) & ~(size_t)255; return p; };

  us* states_h = (us*)alloc((size_t)NN * 512 * 2);
  us* states_l = (us*)alloc((size_t)NN * 512 * 2);
  char* regionA = alloc((size_t)NN * 128 * 2 * 4);   // h0h|h0l|aggh|aggl, later y1h|y1l
  us* h0h  = (us*)regionA;
  us* h0l  = (us*)(regionA + (size_t)NN * 128 * 2);
  us* aggh = (us*)(regionA + (size_t)NN * 128 * 4);
  us* aggl = (us*)(regionA + (size_t)NN * 128 * 6);
  us* y1h  = (us*)regionA;
  us* y1l  = (us*)(regionA + (size_t)NN * 256 * 2);
  float* y2 = (float*)states_h;                       // states dead after p1

  float* gmax   = (float*)alloc(512 * 256 * 4);
  float* gcon   = (float*)alloc(512 * 256 * 4);
  float* rs_out = (float*)alloc((size_t)NN * 4);
  float* rs_in  = (float*)alloc((size_t)NN * 4);
  us* cWh[4]; us* cWl[4];
  for (int l = 0; l < 4; ++l) { cWh[l] = (us*)alloc(128 * 128 * 2); cWl[l] = (us*)alloc(128 * 128 * 2); }
  us* fWh  = (us*)alloc(256 * 512 * 2);
  us* fWl  = (us*)alloc(256 * 512 * 2);
  us* p1Wh = (us*)alloc(256 * 512 * 2);
  us* p1Wl = (us*)alloc(256 * 512 * 2);
  us* p2Wh = (us*)alloc(64 * 256 * 2);
  us* p2Wl = (us*)alloc(64 * 256 * 2);
  int* cnt_out = (int*)alloc((size_t)NN * 4);
  int* cnt_in  = (int*)alloc((size_t)NN * 4);
  int* cursor  = (int*)alloc((size_t)NN * 4);
  int* row_ptr = (int*)alloc(((size_t)NN + 1) * 4);
  int* csr     = (int*)alloc((size_t)NE * 4);

  zero_ints<<<(3 * NN + 255) / 256, 256, 0, stream>>>(cnt_out, 3 * NN);
  deg_count<<<NE / 256, 256, 0, stream>>>(esrc, edst, cnt_out, cnt_in);
  rs_kernel<<<NN / 256, 256, 0, stream>>>(cnt_out, cnt_in, rs_out, rs_in);
  scan_kernel<<<1, 1024, 0, stream>>>(cnt_in, row_ptr);
  csr_fill<<<NE / 256, 256, 0, stream>>>(esrc, edst, row_ptr, cursor, csr);

  transpose_x<<<1024, 256, 0, stream>>>(x, h0h, h0l);
  const float* cW[4] = {W_head, W_res[0], W_res[1], W_res[2]};
  for (int l = 0; l < 4; ++l)
    wsplit_t<<<64, 256, 0, stream>>>(cW[l], cWh[l], cWl[l], 128, 128, 128);
  wsplit<<<512, 256, 0, stream>>>(W_fusion, fWh, fWl, 256, 512, 512, 0);
  wsplit<<<512, 256, 0, stream>>>(W_p1, p1Wh, p1Wl, 256, 512, 768, 256);
  wsplit<<<64, 256, 0, stream>>>(W_p2, p2Wh, p2Wl, 64, 256, 256, 0);

  const float* cB[4] = {b_head, b_res[0], b_res[1], b_res[2]};
  // layer 1 (head)
  aggregate<<<NN / 4, 256, 0, stream>>>(h0h, h0l, 128, row_ptr, csr, rs_out, rs_in, aggh, aggl);
  mgemm8<128, 128, 4, 2, 0><<<256, 512, 0, stream>>>(aggh, aggl, 128, cWh[0], cWl[0], cB[0],
                                                     nullptr, states_h, states_l, 512, 0,
                                                     nullptr, nullptr, nullptr);
  // layers 2..4 (residual)
  for (int l = 1; l <= 3; ++l) {
    aggregate<<<NN / 4, 256, 0, stream>>>(states_h + (size_t)(l - 1) * 128,
                                          states_l + (size_t)(l - 1) * 128, 512,
                                          row_ptr, csr, rs_out, rs_in, aggh, aggl);
    mgemm8<128, 128, 4, 2, 1><<<256, 512, 0, stream>>>(aggh, aggl, 128, cWh[l], cWl[l], cB[l],
                                                       nullptr, states_h, states_l, 512, l * 128,
                                                       states_h, states_l, nullptr);
  }
  // fusion conv + per-slice max -> gmax
  mgemm8<512, 256, 2, 4, 2><<<256, 512, 0, stream>>>(states_h, states_l, 512, fWh, fWl, b_fusion,
                                                     gmax, nullptr, nullptr, 0, 0,
                                                     nullptr, nullptr, nullptr);
  gcon_kernel<<<512, 256, 0, stream>>>(gmax, W_p1, gcon);
  // p1 -> y1 planes
  mgemm8<512, 256, 2, 4, 3><<<256, 512, 0, stream>>>(states_h, states_l, 512, p1Wh, p1Wl, b_p1,
                                                     nullptr, y1h, y1l, 256, 0,
                                                     nullptr, nullptr, gcon);
  // p2 -> y2 fp32 [NN][64]
  mgemm8<256, 64, 8, 2, 4><<<256, 512, 0, stream>>>(y1h, y1l, 256, p2Wh, p2Wl, b_p2,
                                                    y2, nullptr, nullptr, 0, 0,
                                                    nullptr, nullptr, nullptr);
  // p3
  p3_kernel<<<NN / 256, 256, 0, stream>>>(y2, W_p3, b_p3, outp);
}